// Round 1
// baseline (2853.140 us; speedup 1.0000x reference)
//
#include <hip/hip_runtime.h>

#define SEQL 1024
#define DMODEL 512
#define DINNER 1024
#define NROWS 8192

__device__ __forceinline__ float sigmoid_f(float x){ return 1.f/(1.f+expf(-x)); }
__device__ __forceinline__ float silu_f(float x){ return x/(1.f+expf(-x)); }
__device__ __forceinline__ float softplus_f(float x){ return fmaxf(x,0.f)+log1pf(expf(-fabsf(x))); }
__device__ __forceinline__ float gelu_f(float x){
  float u = 0.7978845608028654f*(x+0.044715f*x*x*x);
  return 0.5f*x*(1.f+tanhf(u));
}

// ---------------- LayerNorm (D=512), optional add-in and residual-out ----------
__global__ __launch_bounds__(128) void ln_k(const float* a, const float* b, float* resid,
                                            const float* g, const float* beta, float* out)
{
  int row = blockIdx.x;
  int t = threadIdx.x;
  size_t off = (size_t)row*DMODEL + t*4;
  float4 v = *(const float4*)(a + off);
  if (b) {
    float4 w = *(const float4*)(b + off);
    v.x += w.x; v.y += w.y; v.z += w.z; v.w += w.w;
  }
  if (resid) *(float4*)(resid + off) = v;
  float s = v.x+v.y+v.z+v.w;
  float q = v.x*v.x+v.y*v.y+v.z*v.z+v.w*v.w;
  #pragma unroll
  for (int o=1;o<64;o<<=1){ s += __shfl_xor(s,o); q += __shfl_xor(q,o); }
  __shared__ float ss[2], qq[2];
  int w = t>>6;
  if ((t&63)==0){ ss[w]=s; qq[w]=q; }
  __syncthreads();
  s = ss[0]+ss[1]; q = qq[0]+qq[1];
  float mean = s*(1.f/512.f);
  float var  = q*(1.f/512.f) - mean*mean;
  float rstd = rsqrtf(var + 1e-5f);
  int c = t*4;
  float4 gg = *(const float4*)(g+c);
  float4 bb = *(const float4*)(beta+c);
  float4 o4;
  o4.x = (v.x-mean)*rstd*gg.x + bb.x;
  o4.y = (v.y-mean)*rstd*gg.y + bb.y;
  o4.z = (v.z-mean)*rstd*gg.z + bb.z;
  o4.w = (v.w-mean)*rstd*gg.w + bb.w;
  *(float4*)(out + off) = o4;
}

// ---------------- Generic tiled fp32 GEMM: C[M,N] = A[M,K] @ B, + epilogue ------
// EPI: 0 none, 1 +bias, 2 softplus(x+bias), 3 gelu(x+bias), 4 *scale,
//      5 x+bias+p0[idx], 6 gate fusion
// BMODE: 0 plain, 1 scores (batched NT over b,h), 2 attnV (batched NN), 3 stitched A|A2 (K=1024)
// BT: B is [N,K] row-major (dot along K) when true, else [K,N]
template<int EPI, int BMODE, bool BT>
__global__ __launch_bounds__(256) void gemm_k(
    const float* A, int lda, const float* B, int ldb,
    float* C, int ldc, int M, int N, int K,
    const float* bias, const float* p0, const float* p1, const float* p2,
    const float* A2, float scale)
{
  __shared__ float As[16][68];
  __shared__ float Bs[16][68];
  const int tid = threadIdx.x;
  const int bx = blockIdx.x, by = blockIdx.y, bz = blockIdx.z;
  if (BMODE==1) {
    int zb = bz>>3, zh = bz&7;
    A += (size_t)zb*SEQL*DMODEL + zh*64;
    B += (size_t)zb*SEQL*DMODEL + zh*64;
    C += (size_t)bz*SEQL*SEQL;
  } else if (BMODE==2) {
    int zb = bz>>3, zh = bz&7;
    A += (size_t)bz*SEQL*SEQL;
    B += (size_t)zb*SEQL*DMODEL + zh*64;
    C += (size_t)zb*SEQL*DMODEL + zh*64;
  }
  const int row0 = by*64, col0 = bx*64;
  const int ty = tid>>4, tx = tid&15;
  const int ar = tid>>2,  akq = tid&3;
  const int bkr = tid>>4, bn4 = tid&15;
  const int btn = tid>>2, btkq = tid&3;
  float acc[4][4] = {};

  for (int k0=0; k0<K; k0+=16) {
    {
      const float* src;
      if (BMODE==3) {
        int kk = k0 + akq*4;
        src = (kk < 512) ? (A  + (size_t)(row0+ar)*512 + kk)
                         : (A2 + (size_t)(row0+ar)*512 + (kk-512));
      } else {
        src = A + (size_t)(row0+ar)*lda + k0 + akq*4;
      }
      float4 v = *(const float4*)src;
      As[akq*4+0][ar]=v.x; As[akq*4+1][ar]=v.y; As[akq*4+2][ar]=v.z; As[akq*4+3][ar]=v.w;
    }
    if (!BT) {
      int col = col0 + bn4*4;
      float4 v = (col < N) ? *(const float4*)(B + (size_t)(k0+bkr)*ldb + col)
                           : make_float4(0.f,0.f,0.f,0.f);
      *(float4*)&Bs[bkr][bn4*4] = v;
    } else {
      int col = col0 + btn;
      float4 v = (col < N) ? *(const float4*)(B + (size_t)col*ldb + k0 + btkq*4)
                           : make_float4(0.f,0.f,0.f,0.f);
      Bs[btkq*4+0][btn]=v.x; Bs[btkq*4+1][btn]=v.y; Bs[btkq*4+2][btn]=v.z; Bs[btkq*4+3][btn]=v.w;
    }
    __syncthreads();
    #pragma unroll
    for (int kk=0; kk<16; ++kk) {
      float4 a4 = *(const float4*)&As[kk][ty*4];
      float4 b4 = *(const float4*)&Bs[kk][tx*4];
      float a[4] = {a4.x,a4.y,a4.z,a4.w};
      float b[4] = {b4.x,b4.y,b4.z,b4.w};
      #pragma unroll
      for (int i=0;i<4;++i)
        #pragma unroll
        for (int j=0;j<4;++j)
          acc[i][j] = fmaf(a[i], b[j], acc[i][j]);
    }
    __syncthreads();
  }

  #pragma unroll
  for (int i=0;i<4;++i) {
    int row = row0 + ty*4 + i;
    #pragma unroll
    for (int j=0;j<4;++j) {
      int col = col0 + tx*4 + j;
      if (col >= N) continue;
      size_t idx = (size_t)row*ldc + col;
      float v = acc[i][j];
      if (EPI==1) v += bias[col];
      else if (EPI==2) v = softplus_f(v + bias[col]);
      else if (EPI==3) v = gelu_f(v + bias[col]);
      else if (EPI==4) v *= scale;
      else if (EPI==5) v = v + bias[col] + p0[idx];
      else if (EPI==6) {
        float g = sigmoid_f(v + bias[col]);
        float m = p0[idx], at = p1[idx];
        v = p2[idx] + at + g*m + (1.f-g)*at;
      }
      C[idx] = v;
    }
  }
}

// ---------------- causal depthwise conv (D_CONV=4) + SiLU ----------------------
__global__ __launch_bounds__(256) void conv_k(const float* xr, const float* cw,
                                              const float* cb, float* xc)
{
  int t = blockIdx.x*256 + threadIdx.x;
  int d = (t & 255)*4;
  int row = t >> 8;
  int l = row & (SEQL-1);
  const float* xmb = xr + (size_t)(row - l)*2048 + d;  // batch base (xm half of xr)
  float wv[4][4];
  #pragma unroll
  for (int dd=0; dd<4; ++dd){
    float4 w = *(const float4*)(cw + (size_t)(d+dd)*4);
    wv[dd][0]=w.x; wv[dd][1]=w.y; wv[dd][2]=w.z; wv[dd][3]=w.w;
  }
  float4 acc = *(const float4*)(cb + d);
  #pragma unroll
  for (int k=0;k<4;++k){
    int ls = l + k - 3;
    if (ls >= 0) {
      float4 xv = *(const float4*)(xmb + (size_t)ls*2048);
      acc.x += wv[0][k]*xv.x;
      acc.y += wv[1][k]*xv.y;
      acc.z += wv[2][k]*xv.z;
      acc.w += wv[3][k]*xv.w;
    }
  }
  acc.x = silu_f(acc.x); acc.y = silu_f(acc.y);
  acc.z = silu_f(acc.z); acc.w = silu_f(acc.w);
  *(float4*)(xc + (size_t)row*DINNER + d) = acc;
}

// ---------------- selective scan -----------------------------------------------
// lane layout: s = tid&15 (state), d-group = tid>>4. y written in-place over delta,
// fused with +u*Dp and *silu(res).
__global__ __launch_bounds__(256) void scan_k(const float* xc, float* deltaY,
                                              const float* bc, const float* xr,
                                              const float* A_log, const float* Dp)
{
  int b = blockIdx.y;
  int s = threadIdx.x & 15;
  int d = blockIdx.x*16 + (threadIdx.x >> 4);
  float A = -expf(A_log[s]);
  float dcoef = Dp[d];
  float h = 0.f;
  size_t base = (size_t)b*SEQL;
  const float* pu   = xc    + base*DINNER + d;
  float*       pdy  = deltaY+ base*DINNER + d;
  const float* pbc  = bc    + base*32;
  const float* pres = xr    + base*2048 + 1024 + d;
  for (int l=0; l<SEQL; ++l) {
    float dt = pdy[(size_t)l*DINNER];
    float u  = pu [(size_t)l*DINNER];
    float Bv = pbc[l*32 + s];
    float Cv = pbc[l*32 + 16 + s];
    float dA = expf(dt * A);
    h = h*dA + (dt*Bv)*u;
    float p = h*Cv;
    p += __shfl_xor(p,1); p += __shfl_xor(p,2);
    p += __shfl_xor(p,4); p += __shfl_xor(p,8);
    if (s == 0) {
      float y = p + u*dcoef;
      float r = pres[(size_t)l*2048];
      y *= silu_f(r);
      pdy[(size_t)l*DINNER] = y;
    }
  }
}

// ---------------- row softmax over 1024 cols, in place --------------------------
__global__ __launch_bounds__(256) void softmax_k(float* w)
{
  size_t row = blockIdx.x;
  float* p = w + row*SEQL + threadIdx.x*4;
  float4 v = *(const float4*)p;
  float m = fmaxf(fmaxf(v.x,v.y), fmaxf(v.z,v.w));
  #pragma unroll
  for (int o=1;o<64;o<<=1) m = fmaxf(m, __shfl_xor(m,o));
  __shared__ float sm[4], ssum[4];
  int wv = threadIdx.x>>6;
  if ((threadIdx.x&63)==0) sm[wv]=m;
  __syncthreads();
  m = fmaxf(fmaxf(sm[0],sm[1]), fmaxf(sm[2],sm[3]));
  v.x = expf(v.x-m); v.y = expf(v.y-m); v.z = expf(v.z-m); v.w = expf(v.w-m);
  float s = v.x+v.y+v.z+v.w;
  #pragma unroll
  for (int o=1;o<64;o<<=1) s += __shfl_xor(s,o);
  if ((threadIdx.x&63)==0) ssum[wv]=s;
  __syncthreads();
  s = ssum[0]+ssum[1]+ssum[2]+ssum[3];
  float inv = 1.f/s;
  v.x*=inv; v.y*=inv; v.z*=inv; v.w*=inv;
  *(float4*)p = v;
}

extern "C" void kernel_launch(void* const* d_in, const int* in_sizes, int n_in,
                              void* d_out, int out_size, void* d_ws, size_t ws_size,
                              hipStream_t stream)
{
  const float* x          = (const float*)d_in[0];
  const float* in_proj_w  = (const float*)d_in[1];
  const float* conv_w     = (const float*)d_in[2];
  const float* conv_b     = (const float*)d_in[3];
  const float* x_proj_w   = (const float*)d_in[4];
  const float* dt_proj_w  = (const float*)d_in[5];
  const float* dt_proj_b  = (const float*)d_in[6];
  const float* A_log      = (const float*)d_in[7];
  const float* Dvec       = (const float*)d_in[8];
  const float* out_proj_w = (const float*)d_in[9];
  const float* wq_w = (const float*)d_in[10]; const float* wq_b = (const float*)d_in[11];
  const float* wk_w = (const float*)d_in[12]; const float* wk_b = (const float*)d_in[13];
  const float* wv_w = (const float*)d_in[14]; const float* wv_b = (const float*)d_in[15];
  const float* wo_w = (const float*)d_in[16]; const float* wo_b = (const float*)d_in[17];
  const float* attn_ln_g = (const float*)d_in[18]; const float* attn_ln_b = (const float*)d_in[19];
  const float* ffn_w1 = (const float*)d_in[20]; const float* ffn_b1 = (const float*)d_in[21];
  const float* ffn_w2 = (const float*)d_in[22]; const float* ffn_b2 = (const float*)d_in[23];
  const float* norm1_g = (const float*)d_in[24]; const float* norm1_b = (const float*)d_in[25];
  const float* norm2_g = (const float*)d_in[26]; const float* norm2_b = (const float*)d_in[27];
  const float* norm3_g = (const float*)d_in[28]; const float* norm3_b = (const float*)d_in[29];
  const float* gate_w  = (const float*)d_in[30]; const float* gate_b  = (const float*)d_in[31];

  float* ws  = (float*)d_ws;
  float* XR  = ws;                   // 8192*2048 = 16,777,216   (xr; later Q|K|V; later ffn hidden)
  float* XC  = XR  + 16777216;       // 8192*1024 = 8,388,608    (xc; later attnV-out | wo-out)
  float* DY  = XC  + 8388608;        // 8192*1024                (delta -> y in place)
  float* BCb = DY  + 8388608;        // 8192*32   = 262,144
  float* XN1 = BCb + 262144;         // 8192*512  = 4,194,304    (xn1)
  float* MB  = XN1 + 4194304;        //                          (mamba_out; later xn3)
  float* X1  = MB  + 4194304;        //                          (x1 -> x3 in place)
  float* XN2 = X1  + 4194304;        //                          (xn2)
  float* ATT = XN2 + 4194304;        //                          (attn_out)

  float* Q    = XR;
  float* Kp   = XR + 4194304;
  float* V    = XR + 8388608;
  float* Hb   = XC;                  // attn_w @ V
  float* WOUT = XC + 4194304;        // (attn_w @ V) @ wo + b
  float* FH   = XR;                  // ffn hidden (8192*2048)
  float* XOUT = (float*)d_out;
  float* AW   = (float*)d_out + 4194304;  // attn_w [8,8,1024,1024]

  const float* nul = nullptr;

  // 1) xn1 = LN(x)
  ln_k<<<NROWS, 128, 0, stream>>>(x, nullptr, nullptr, norm1_g, norm1_b, XN1);
  // 2) xr = xn1 @ in_proj_w   [8192,2048]
  gemm_k<0,0,false><<<dim3(32,128), 256, 0, stream>>>(XN1,512, in_proj_w,2048, XR,2048,
        NROWS,2048,512, nul,nul,nul,nul,nul,1.f);
  // 3) xc = silu(conv(xm) + cb)
  conv_k<<<NROWS, 256, 0, stream>>>(XR, conv_w, conv_b, XC);
  // 4) BC = xc @ x_proj_w     [8192,32]
  gemm_k<0,0,false><<<dim3(1,128), 256, 0, stream>>>(XC,1024, x_proj_w,32, BCb,32,
        NROWS,32,1024, nul,nul,nul,nul,nul,1.f);
  // 5) delta = softplus(xc @ dt_proj_w + b)
  gemm_k<2,0,false><<<dim3(16,128), 256, 0, stream>>>(XC,1024, dt_proj_w,1024, DY,1024,
        NROWS,1024,1024, dt_proj_b,nul,nul,nul,nul,1.f);
  // 6) selective scan (+u*D, *silu(res)) -> y in DY
  scan_k<<<dim3(64,8), 256, 0, stream>>>(XC, DY, BCb, XR, A_log, Dvec);
  // 7) mamba_out = y @ out_proj_w
  gemm_k<0,0,false><<<dim3(8,128), 256, 0, stream>>>(DY,1024, out_proj_w,512, MB,512,
        NROWS,512,1024, nul,nul,nul,nul,nul,1.f);
  // 8) x1 = x + mamba_out ; xn2 = LN(x1)
  ln_k<<<NROWS, 128, 0, stream>>>(x, MB, X1, norm2_g, norm2_b, XN2);
  // 9) Q,K,V
  gemm_k<1,0,false><<<dim3(8,128), 256, 0, stream>>>(XN2,512, wq_w,512, Q,512,
        NROWS,512,512, wq_b,nul,nul,nul,nul,1.f);
  gemm_k<1,0,false><<<dim3(8,128), 256, 0, stream>>>(XN2,512, wk_w,512, Kp,512,
        NROWS,512,512, wk_b,nul,nul,nul,nul,1.f);
  gemm_k<1,0,false><<<dim3(8,128), 256, 0, stream>>>(XN2,512, wv_w,512, V,512,
        NROWS,512,512, wv_b,nul,nul,nul,nul,1.f);
  // 10) scores = Q K^T / 8  -> AW
  gemm_k<4,1,true><<<dim3(16,16,64), 256, 0, stream>>>(Q,512, Kp,512, AW,1024,
        SEQL,SEQL,64, nul,nul,nul,nul,nul,0.125f);
  // 11) attn_w = softmax(scores) in place
  softmax_k<<<65536, 256, 0, stream>>>(AW);
  // 12) Hb = attn_w @ V
  gemm_k<0,2,false><<<dim3(1,16,64), 256, 0, stream>>>(AW,1024, V,512, Hb,512,
        SEQL,64,SEQL, nul,nul,nul,nul,nul,1.f);
  // 13) WOUT = Hb @ wo + b
  gemm_k<1,0,false><<<dim3(8,128), 256, 0, stream>>>(Hb,512, wo_w,512, WOUT,512,
        NROWS,512,512, wo_b,nul,nul,nul,nul,1.f);
  // 14) attn_out = LN(WOUT + xn2)
  ln_k<<<NROWS, 128, 0, stream>>>(WOUT, XN2, nullptr, attn_ln_g, attn_ln_b, ATT);
  // 15) gate: x3 = x1 + att + g*m + (1-g)*att,  g = sigmoid([m|att] @ gate_w + b)
  gemm_k<6,3,false><<<dim3(8,128), 256, 0, stream>>>(MB,512, gate_w,512, X1,512,
        NROWS,512,1024, gate_b, MB, ATT, X1, ATT, 1.f);
  // 16) xn3 = LN(x3)   (into MB, mamba_out dead)
  ln_k<<<NROWS, 128, 0, stream>>>(X1, nullptr, nullptr, norm3_g, norm3_b, MB);
  // 17) fh = gelu(xn3 @ ffn_w1 + b1)
  gemm_k<3,0,false><<<dim3(32,128), 256, 0, stream>>>(MB,512, ffn_w1,2048, FH,2048,
        NROWS,2048,512, ffn_b1,nul,nul,nul,nul,1.f);
  // 18) out = x3 + fh @ ffn_w2 + b2  -> d_out
  gemm_k<5,0,false><<<dim3(8,128), 256, 0, stream>>>(FH,2048, ffn_w2,512, XOUT,512,
        NROWS,512,2048, ffn_b2, X1,nul,nul,nul,1.f);
}

// Round 2
// 1229.962 us; speedup vs baseline: 2.3197x; 2.3197x over previous
//
#include <hip/hip_runtime.h>

#define SEQL 1024
#define DMODEL 512
#define DINNER 1024
#define NROWS 8192

typedef unsigned short u16;
typedef unsigned int u32;
using bf16x8 = __attribute__((ext_vector_type(8))) short;
using f32x4  = __attribute__((ext_vector_type(4))) float;
using u16x4  = __attribute__((ext_vector_type(4))) unsigned short;

__device__ __forceinline__ float sigmoid_f(float x){ return 1.f/(1.f+expf(-x)); }
__device__ __forceinline__ float silu_f(float x){ return x/(1.f+expf(-x)); }
__device__ __forceinline__ float softplus_f(float x){ return fmaxf(x,0.f)+log1pf(expf(-fabsf(x))); }
__device__ __forceinline__ float gelu_f(float x){
  float u = 0.7978845608028654f*(x+0.044715f*x*x*x);
  return 0.5f*x*(1.f+tanhf(u));
}
__device__ __forceinline__ u16 f2bf(float f){
  u32 u = __builtin_bit_cast(u32, f);
  return (u16)((u + 0x7FFFu + ((u>>16)&1u)) >> 16);
}
__device__ __forceinline__ float bf2f(u16 h){
  return __builtin_bit_cast(float, (u32)h << 16);
}

// ---------------- weight transpose+cvt: [K,N] fp32 -> [N,K] bf16 ---------------
struct WtDesc { const float* src; u16* dst; int K; int N; int t0; };
struct WtArgs { WtDesc d[11]; };

__global__ __launch_bounds__(256) void wt_k(WtArgs a)
{
  __shared__ float t[64][65];
  int bid = blockIdx.x;
  int i = 0;
  #pragma unroll
  for (int j=1;j<11;++j) if (bid >= a.d[j].t0) i = j;
  const float* src = a.d[i].src; u16* dst = a.d[i].dst;
  int K = a.d[i].K, N = a.d[i].N;
  int ntN = (N+63)>>6;
  int loc = bid - a.d[i].t0;
  int k0 = (loc / ntN)*64, n0 = (loc % ntN)*64;
  int tr = threadIdx.x>>4, tc = threadIdx.x&15;
  #pragma unroll
  for (int p=0;p<4;++p) {
    int r = p*16 + tr; int c = tc*4;
    if (n0 + c < N) {
      float4 v = *(const float4*)(src + (size_t)(k0+r)*N + n0 + c);
      t[r][c]=v.x; t[r][c+1]=v.y; t[r][c+2]=v.z; t[r][c+3]=v.w;
    }
  }
  __syncthreads();
  #pragma unroll
  for (int p=0;p<4;++p) {
    int n = p*16 + tr; int k = tc*4;
    if (n0 + n < N) {
      u16x4 o = { f2bf(t[k][n]), f2bf(t[k+1][n]), f2bf(t[k+2][n]), f2bf(t[k+3][n]) };
      *(u16x4*)(dst + (size_t)(n0+n)*K + k0 + k) = o;
    }
  }
}

// ---------------- LayerNorm (D=512), optional add-in, resid-out, f32/bf16 outs --
__global__ __launch_bounds__(128) void ln_k(const float* a, const float* b, float* resid,
                                            const float* g, const float* beta,
                                            float* outf, u16* outb)
{
  int row = blockIdx.x;
  int t = threadIdx.x;
  size_t off = (size_t)row*DMODEL + t*4;
  float4 v = *(const float4*)(a + off);
  if (b) {
    float4 w = *(const float4*)(b + off);
    v.x += w.x; v.y += w.y; v.z += w.z; v.w += w.w;
  }
  if (resid) *(float4*)(resid + off) = v;
  float s = v.x+v.y+v.z+v.w;
  float q = v.x*v.x+v.y*v.y+v.z*v.z+v.w*v.w;
  #pragma unroll
  for (int o=1;o<64;o<<=1){ s += __shfl_xor(s,o); q += __shfl_xor(q,o); }
  __shared__ float ss[2], qq[2];
  int w = t>>6;
  if ((t&63)==0){ ss[w]=s; qq[w]=q; }
  __syncthreads();
  s = ss[0]+ss[1]; q = qq[0]+qq[1];
  float mean = s*(1.f/512.f);
  float var  = q*(1.f/512.f) - mean*mean;
  float rstd = rsqrtf(var + 1e-5f);
  int c = t*4;
  float4 gg = *(const float4*)(g+c);
  float4 bb = *(const float4*)(beta+c);
  float4 o4;
  o4.x = (v.x-mean)*rstd*gg.x + bb.x;
  o4.y = (v.y-mean)*rstd*gg.y + bb.y;
  o4.z = (v.z-mean)*rstd*gg.z + bb.z;
  o4.w = (v.w-mean)*rstd*gg.w + bb.w;
  if (outf) *(float4*)(outf + off) = o4;
  if (outb) {
    u16x4 ob = { f2bf(o4.x), f2bf(o4.y), f2bf(o4.z), f2bf(o4.w) };
    *(u16x4*)(outb + off) = ob;
  }
}

// ---------------- bf16 MFMA GEMM, 128x128 tile, BK=32 --------------------------
// C[M,N] = A[M,K] @ B ; B supplied pre-transposed bf16 [N,K] (row n = col n of B)
// EPI: 0 f32, 1 f32+bias, 2 softplus(x+bias) f32, 3 gelu(x+bias) bf16, 4 x*scale f32,
//      5 x+bias+p0 f32, 6 gate fusion f32, 7 bf16, 8 bf16+bias, 9 f32 + aux bf16,
//      10 bias + transposed bf16 write to aux (V-mode)
// BMODE: 0 plain, 1 scores (batch b*8+h over Q,K), 2 attnV (A=AW f32 batch), 3 stitched A|A2
// AF32: A operand is fp32, convert during staging
template<int EPI, int BMODE, bool AF32>
__global__ __launch_bounds__(256) void mm_k(
    const void* Av, int lda, const u16* Bb, int ldb,
    void* Cv, int ldc, int M, int N, int K,
    const float* bias, const float* p0, const float* p1, const float* p2,
    const void* A2v, u16* aux, float scale)
{
  __shared__ u16 As[128][32];
  __shared__ u16 Bs[128][32];
  const int tid = threadIdx.x;
  const int bx = blockIdx.x, by = blockIdx.y, bz = blockIdx.z;
  const u16* Ab = (const u16*)Av;
  const float* Af = (const float*)Av;
  const u16* A2b = (const u16*)A2v;
  float* Cf = (float*)Cv;
  u16* Cb = (u16*)Cv;
  int bb = 0;
  if (BMODE==1) {
    bb = bz>>3; int hh = bz&7;
    Ab += (size_t)bb*SEQL*DMODEL + hh*64;
    Bb += (size_t)bb*SEQL*DMODEL + hh*64;
    Cf += (size_t)bz*SEQL*SEQL;
  } else if (BMODE==2) {
    bb = bz>>3; int hh = bz&7;
    Af += (size_t)bz*SEQL*SEQL;
    Bb += (size_t)bb*DMODEL*SEQL + (size_t)(hh*64)*SEQL;
    Cb += (size_t)bb*SEQL*DMODEL + hh*64;
  }
  const int row0 = by*128, col0 = bx*128;
  const int sr = tid>>2, sc = tid&3;
  const int wv = tid>>6, lane = tid&63;
  const int wr = wv>>1, wc = wv&1;
  const int lr = lane&15, lk = (lane>>4)*8;
  const int lq = lane>>4;

  f32x4 acc[4][4];
  #pragma unroll
  for (int i=0;i<4;++i)
    #pragma unroll
    for (int j=0;j<4;++j)
      acc[i][j] = (f32x4){0.f,0.f,0.f,0.f};

  for (int k0=0; k0<K; k0+=32) {
    #pragma unroll
    for (int h=0; h<2; ++h) {
      int row = sr + h*64;
      u16* dst = &As[row][sc*8];
      if (AF32) {
        const float* src = Af + (size_t)(row0+row)*lda + k0 + sc*8;
        float4 u0 = *(const float4*)src;
        float4 u1 = *(const float4*)(src+4);
        uint4 pk;
        pk.x = (u32)f2bf(u0.x) | ((u32)f2bf(u0.y)<<16);
        pk.y = (u32)f2bf(u0.z) | ((u32)f2bf(u0.w)<<16);
        pk.z = (u32)f2bf(u1.x) | ((u32)f2bf(u1.y)<<16);
        pk.w = (u32)f2bf(u1.z) | ((u32)f2bf(u1.w)<<16);
        *(uint4*)dst = pk;
      } else if (BMODE==3) {
        int kk = k0 + sc*8;
        const u16* src = (kk < 512) ? Ab + (size_t)(row0+row)*512 + kk
                                    : A2b + (size_t)(row0+row)*512 + (kk-512);
        *(uint4*)dst = *(const uint4*)src;
      } else {
        const u16* src = Ab + (size_t)(row0+row)*lda + k0 + sc*8;
        *(uint4*)dst = *(const uint4*)src;
      }
    }
    #pragma unroll
    for (int h=0; h<2; ++h) {
      int rowb = sr + h*64;
      int n = col0 + rowb;
      uint4 v = {0u,0u,0u,0u};
      if (n < N) v = *(const uint4*)(Bb + (size_t)n*ldb + k0 + sc*8);
      *(uint4*)&Bs[rowb][sc*8] = v;
    }
    __syncthreads();
    bf16x8 fa[4], fb[4];
    #pragma unroll
    for (int i=0;i<4;++i) fa[i] = *(const bf16x8*)&As[wr*64 + i*16 + lr][lk];
    #pragma unroll
    for (int j=0;j<4;++j) fb[j] = *(const bf16x8*)&Bs[wc*64 + j*16 + lr][lk];
    #pragma unroll
    for (int i=0;i<4;++i)
      #pragma unroll
      for (int j=0;j<4;++j)
        acc[i][j] = __builtin_amdgcn_mfma_f32_16x16x32_bf16(fa[i], fb[j], acc[i][j], 0,0,0);
    __syncthreads();
  }

  #pragma unroll
  for (int i=0;i<4;++i) {
    #pragma unroll
    for (int j=0;j<4;++j) {
      int col = col0 + wc*64 + j*16 + lr;
      if (col >= N) continue;
      int rowbase = row0 + wr*64 + i*16 + lq*4;
      f32x4 v4 = acc[i][j];
      if (EPI==10) {
        int b2 = rowbase >> 10;
        int l2 = rowbase & 1023;
        float bv = bias[col];
        u16x4 pk = { f2bf(v4[0]+bv), f2bf(v4[1]+bv), f2bf(v4[2]+bv), f2bf(v4[3]+bv) };
        *(u16x4*)(aux + (size_t)b2*DMODEL*SEQL + (size_t)col*SEQL + l2) = pk;
        continue;
      }
      #pragma unroll
      for (int r=0;r<4;++r) {
        int row = rowbase + r;
        size_t idx = (size_t)row*ldc + col;
        float v = v4[r];
        if (EPI==0) Cf[idx] = v;
        else if (EPI==1) Cf[idx] = v + bias[col];
        else if (EPI==2) Cf[idx] = softplus_f(v + bias[col]);
        else if (EPI==3) Cb[idx] = f2bf(gelu_f(v + bias[col]));
        else if (EPI==4) Cf[idx] = v*scale;
        else if (EPI==5) Cf[idx] = v + bias[col] + p0[idx];
        else if (EPI==6) {
          float g = sigmoid_f(v + bias[col]);
          float m = p0[idx], at = p1[idx];
          Cf[idx] = p2[idx] + at + g*m + (1.f-g)*at;
        }
        else if (EPI==7) Cb[idx] = f2bf(v);
        else if (EPI==8) Cb[idx] = f2bf(v + bias[col]);
        else if (EPI==9) { Cf[idx] = v; aux[idx] = f2bf(v); }
      }
    }
  }
}

// ---------------- causal depthwise conv (D_CONV=4) + SiLU, bf16 in, dual out ---
__global__ __launch_bounds__(256) void conv_k(const u16* xrb, const float* cw,
                                              const float* cb, float* xc, u16* xcb)
{
  int t = blockIdx.x*256 + threadIdx.x;
  int d = (t & 255)*4;
  int row = t >> 8;
  int l = row & (SEQL-1);
  const u16* xmb = xrb + (size_t)(row - l)*2048 + d;
  float wv[4][4];
  #pragma unroll
  for (int dd=0; dd<4; ++dd){
    float4 w = *(const float4*)(cw + (size_t)(d+dd)*4);
    wv[dd][0]=w.x; wv[dd][1]=w.y; wv[dd][2]=w.z; wv[dd][3]=w.w;
  }
  float4 acc = *(const float4*)(cb + d);
  #pragma unroll
  for (int k=0;k<4;++k){
    int ls = l + k - 3;
    if (ls >= 0) {
      u16x4 xv = *(const u16x4*)(xmb + (size_t)ls*2048);
      acc.x += wv[0][k]*bf2f(xv[0]);
      acc.y += wv[1][k]*bf2f(xv[1]);
      acc.z += wv[2][k]*bf2f(xv[2]);
      acc.w += wv[3][k]*bf2f(xv[3]);
    }
  }
  acc.x = silu_f(acc.x); acc.y = silu_f(acc.y);
  acc.z = silu_f(acc.z); acc.w = silu_f(acc.w);
  size_t off = (size_t)row*DINNER + d;
  *(float4*)(xc + off) = acc;
  u16x4 ob = { f2bf(acc.x), f2bf(acc.y), f2bf(acc.z), f2bf(acc.w) };
  *(u16x4*)(xcb + off) = ob;
}

// ---------------- selective scan (prefetch-1), fused +u*D, *silu(res) ----------
__global__ __launch_bounds__(256) void scan_k(const float* xc, const float* dtv,
                                              const float* bc, const u16* xrb,
                                              const float* A_log, const float* Dp,
                                              u16* yb)
{
  int b = blockIdx.y;
  int s = threadIdx.x & 15;
  int d = blockIdx.x*16 + (threadIdx.x >> 4);
  float A = -expf(A_log[s]);
  float dcoef = Dp[d];
  float h = 0.f;
  size_t base = (size_t)b*SEQL;
  const float* pu   = xc  + base*DINNER + d;
  const float* pdt  = dtv + base*DINNER + d;
  const float* pbc  = bc  + base*32;
  const u16*   pres = xrb + base*2048 + 1024 + d;
  u16*         py   = yb  + base*DINNER + d;
  float dt = pdt[0], u = pu[0], Bv = pbc[s], Cv = pbc[16+s];
  u16 rr = pres[0];
  for (int l=0; l<SEQL; ++l) {
    float dtn=dt, un=u, Bn=Bv, Cn=Cv; u16 rn=rr;
    if (l < SEQL-1) {
      dtn = pdt[(size_t)(l+1)*DINNER];
      un  = pu [(size_t)(l+1)*DINNER];
      Bn  = pbc[(l+1)*32 + s];
      Cn  = pbc[(l+1)*32 + 16 + s];
      rn  = pres[(size_t)(l+1)*2048];
    }
    float dA = expf(dt*A);
    h = h*dA + (dt*Bv)*u;
    float p = h*Cv;
    p += __shfl_xor(p,1); p += __shfl_xor(p,2);
    p += __shfl_xor(p,4); p += __shfl_xor(p,8);
    if (s == 0) {
      float y = p + u*dcoef;
      y *= silu_f(bf2f(rr));
      py[(size_t)l*DINNER] = f2bf(y);
    }
    dt=dtn; u=un; Bv=Bn; Cv=Cn; rr=rn;
  }
}

// ---------------- row softmax over 1024 cols, in place --------------------------
__global__ __launch_bounds__(256) void softmax_k(float* w)
{
  size_t row = blockIdx.x;
  float* p = w + row*SEQL + threadIdx.x*4;
  float4 v = *(const float4*)p;
  float m = fmaxf(fmaxf(v.x,v.y), fmaxf(v.z,v.w));
  #pragma unroll
  for (int o=1;o<64;o<<=1) m = fmaxf(m, __shfl_xor(m,o));
  __shared__ float sm[4], ssum[4];
  int wv = threadIdx.x>>6;
  if ((threadIdx.x&63)==0) sm[wv]=m;
  __syncthreads();
  m = fmaxf(fmaxf(sm[0],sm[1]), fmaxf(sm[2],sm[3]));
  v.x = expf(v.x-m); v.y = expf(v.y-m); v.z = expf(v.z-m); v.w = expf(v.w-m);
  float s = v.x+v.y+v.z+v.w;
  #pragma unroll
  for (int o=1;o<64;o<<=1) s += __shfl_xor(s,o);
  if ((threadIdx.x&63)==0) ssum[wv]=s;
  __syncthreads();
  s = ssum[0]+ssum[1]+ssum[2]+ssum[3];
  float inv = 1.f/s;
  v.x*=inv; v.y*=inv; v.z*=inv; v.w*=inv;
  *(float4*)p = v;
}

extern "C" void kernel_launch(void* const* d_in, const int* in_sizes, int n_in,
                              void* d_out, int out_size, void* d_ws, size_t ws_size,
                              hipStream_t stream)
{
  const float* x          = (const float*)d_in[0];
  const float* in_proj_w  = (const float*)d_in[1];
  const float* conv_w     = (const float*)d_in[2];
  const float* conv_b     = (const float*)d_in[3];
  const float* x_proj_w   = (const float*)d_in[4];
  const float* dt_proj_w  = (const float*)d_in[5];
  const float* dt_proj_b  = (const float*)d_in[6];
  const float* A_log      = (const float*)d_in[7];
  const float* Dvec       = (const float*)d_in[8];
  const float* out_proj_w = (const float*)d_in[9];
  const float* wq_w = (const float*)d_in[10]; const float* wq_b = (const float*)d_in[11];
  const float* wk_w = (const float*)d_in[12]; const float* wk_b = (const float*)d_in[13];
  const float* wv_w = (const float*)d_in[14]; const float* wv_b = (const float*)d_in[15];
  const float* wo_w = (const float*)d_in[16]; const float* wo_b = (const float*)d_in[17];
  const float* attn_ln_g = (const float*)d_in[18]; const float* attn_ln_b = (const float*)d_in[19];
  const float* ffn_w1 = (const float*)d_in[20]; const float* ffn_b1 = (const float*)d_in[21];
  const float* ffn_w2 = (const float*)d_in[22]; const float* ffn_b2 = (const float*)d_in[23];
  const float* norm1_g = (const float*)d_in[24]; const float* norm1_b = (const float*)d_in[25];
  const float* norm2_g = (const float*)d_in[26]; const float* norm2_b = (const float*)d_in[27];
  const float* norm3_g = (const float*)d_in[28]; const float* norm3_b = (const float*)d_in[29];
  const float* gate_w  = (const float*)d_in[30]; const float* gate_b  = (const float*)d_in[31];

  // ---- workspace layout ----
  float* ws  = (float*)d_ws;
  float* XC  = ws;                  // 8388608 f32 (u for scan); reused as WOUT after scan
  float* DY  = XC + 8388608;        // 8388608 f32 (delta); reused as ATT after scan
  float* BC  = DY + 8388608;        // 262144  f32
  float* X1  = BC + 262144;         // 4194304 f32 (x1 -> x3 in place)
  float* XN2 = X1 + 4194304;        // 4194304 f32
  float* MB  = XN2+ 4194304;        // 4194304 f32
  float* WOUT = XC;
  float* ATT  = DY;
  u16* WT0 = (u16*)(MB + 4194304);  // 6324224 halves of transposed weights
  u16* XRb = WT0 + 6324224;         // 16777216 halves (xr bf16); reused Q|K|VT|Hb; then FH
  u16* NB  = XRb + 16777216;        // 4194304 halves (xn1b -> xn2b -> xn3b)
  u16* XCb = NB  + 4194304;         // 8388608 halves (xc bf16); reused MBb+ATTb
  u16* Yb  = XCb + 8388608;         // 8388608 halves (scan y bf16)

  u16* Qb   = XRb;
  u16* Kb   = XRb + 4194304;
  u16* VTb  = XRb + 8388608;
  u16* Hbb  = XRb + 12582912;
  u16* FHb  = XRb;                  // after Q/K/VT/Hb dead
  u16* MBb  = XCb;
  u16* ATTb = XCb + 4194304;

  u16* inprojT = WT0;               // [2048,512]
  u16* xprojT  = inprojT + 1048576; // [32,1024]
  u16* dtT     = xprojT  + 32768;   // [1024,1024]
  u16* outT    = dtT     + 1048576; // [512,1024]
  u16* wqT     = outT    + 524288;  // [512,512]
  u16* wkT     = wqT     + 262144;
  u16* wvT     = wkT     + 262144;
  u16* woT     = wvT     + 262144;
  u16* ffn1T   = woT     + 262144;  // [2048,512]
  u16* ffn2T   = ffn1T   + 1048576; // [512,2048]
  u16* gateT   = ffn2T   + 1048576; // [512,1024]

  float* XOUT = (float*)d_out;
  float* AW   = (float*)d_out + 4194304;

  const float* nulf = nullptr;
  u16* nulh = nullptr;

  // 0) transpose + cvt all weights to bf16 [N,K]
  WtArgs wa;
  wa.d[0]  = { in_proj_w, inprojT, 512, 2048, 0 };
  wa.d[1]  = { x_proj_w,  xprojT, 1024,   32, 256 };
  wa.d[2]  = { dt_proj_w, dtT,    1024, 1024, 272 };
  wa.d[3]  = { out_proj_w,outT,   1024,  512, 528 };
  wa.d[4]  = { wq_w,      wqT,     512,  512, 656 };
  wa.d[5]  = { wk_w,      wkT,     512,  512, 720 };
  wa.d[6]  = { wv_w,      wvT,     512,  512, 784 };
  wa.d[7]  = { wo_w,      woT,     512,  512, 848 };
  wa.d[8]  = { ffn_w1,    ffn1T,   512, 2048, 912 };
  wa.d[9]  = { ffn_w2,    ffn2T,  2048,  512, 1168 };
  wa.d[10] = { gate_w,    gateT,  1024,  512, 1424 };
  wt_k<<<1552, 256, 0, stream>>>(wa);

  // 1) xn1b = LN(x) (bf16 only)
  ln_k<<<NROWS, 128, 0, stream>>>(x, nullptr, nullptr, norm1_g, norm1_b, nullptr, NB);
  // 2) xrb = xn1 @ in_proj (bf16 out)
  mm_k<7,0,false><<<dim3(16,64), 256, 0, stream>>>(NB,512, inprojT,512, XRb,2048,
        NROWS,2048,512, nulf,nulf,nulf,nulf,nullptr,nulh,1.f);
  // 3) xc = silu(conv(xm)+cb), dual out
  conv_k<<<NROWS, 256, 0, stream>>>(XRb, conv_w, conv_b, XC, XCb);
  // 4) BC = xc @ x_proj (f32)
  mm_k<0,0,false><<<dim3(1,64), 256, 0, stream>>>(XCb,1024, xprojT,1024, BC,32,
        NROWS,32,1024, nulf,nulf,nulf,nulf,nullptr,nulh,1.f);
  // 5) delta = softplus(xc @ dt_proj + b) (f32)
  mm_k<2,0,false><<<dim3(8,64), 256, 0, stream>>>(XCb,1024, dtT,1024, DY,1024,
        NROWS,1024,1024, dt_proj_b,nulf,nulf,nulf,nullptr,nulh,1.f);
  // 6) selective scan -> yb (bf16)
  scan_k<<<dim3(64,8), 256, 0, stream>>>(XC, DY, BC, XRb, A_log, Dvec, Yb);
  // 7) mamba_out = y @ out_proj (f32 MB + bf16 MBb)
  mm_k<9,0,false><<<dim3(4,64), 256, 0, stream>>>(Yb,1024, outT,1024, MB,512,
        NROWS,512,1024, nulf,nulf,nulf,nulf,nullptr,MBb,1.f);
  // 8) x1 = x + mamba_out ; xn2 = LN(x1) (f32 + bf16)
  ln_k<<<NROWS, 128, 0, stream>>>(x, MB, X1, norm2_g, norm2_b, XN2, NB);
  // 9) Q,K (bf16), V (transposed bf16)
  mm_k<8,0,false><<<dim3(4,64), 256, 0, stream>>>(NB,512, wqT,512, Qb,512,
        NROWS,512,512, wq_b,nulf,nulf,nulf,nullptr,nulh,1.f);
  mm_k<8,0,false><<<dim3(4,64), 256, 0, stream>>>(NB,512, wkT,512, Kb,512,
        NROWS,512,512, wk_b,nulf,nulf,nulf,nullptr,nulh,1.f);
  mm_k<10,0,false><<<dim3(4,64), 256, 0, stream>>>(NB,512, wvT,512, nullptr,512,
        NROWS,512,512, wv_b,nulf,nulf,nulf,nullptr,VTb,1.f);
  // 10) scores = Q K^T / 8 -> AW (f32, d_out)
  mm_k<4,1,false><<<dim3(8,8,64), 256, 0, stream>>>(Qb,512, Kb,512, AW,1024,
        SEQL,SEQL,64, nulf,nulf,nulf,nulf,nullptr,nulh,0.125f);
  // 11) softmax in place
  softmax_k<<<65536, 256, 0, stream>>>(AW);
  // 12) Hb = attn_w @ V (stage-convert A, bf16 out)
  mm_k<7,2,true><<<dim3(1,8,64), 256, 0, stream>>>(AW,1024, VTb,1024, Hbb,512,
        SEQL,64,SEQL, nulf,nulf,nulf,nulf,nullptr,nulh,1.f);
  // 13) WOUT = Hb @ wo + b (f32)
  mm_k<1,0,false><<<dim3(4,64), 256, 0, stream>>>(Hbb,512, woT,512, WOUT,512,
        NROWS,512,512, wo_b,nulf,nulf,nulf,nullptr,nulh,1.f);
  // 14) attn_out = LN(WOUT + xn2) (f32 + bf16)
  ln_k<<<NROWS, 128, 0, stream>>>(WOUT, XN2, nullptr, attn_ln_g, attn_ln_b, ATT, ATTb);
  // 15) gate fusion -> X1 (in place x3)
  mm_k<6,3,false><<<dim3(4,64), 256, 0, stream>>>(MBb,512, gateT,1024, X1,512,
        NROWS,512,1024, gate_b, MB, ATT, X1, ATTb, nulh,1.f);
  // 16) xn3b = LN(x3) (bf16 only)
  ln_k<<<NROWS, 128, 0, stream>>>(X1, nullptr, nullptr, norm3_g, norm3_b, nullptr, NB);
  // 17) fh = gelu(xn3 @ ffn1 + b1) (bf16)
  mm_k<3,0,false><<<dim3(16,64), 256, 0, stream>>>(NB,512, ffn1T,512, FHb,2048,
        NROWS,2048,512, ffn_b1,nulf,nulf,nulf,nullptr,nulh,1.f);
  // 18) out = x3 + fh @ ffn2 + b2 -> d_out
  mm_k<5,0,false><<<dim3(4,64), 256, 0, stream>>>(FHb,2048, ffn2T,2048, XOUT,512,
        NROWS,512,2048, ffn_b2, X1,nulf,nulf,nullptr,nulh,1.f);
}

// Round 3
// 990.636 us; speedup vs baseline: 2.8801x; 1.2416x over previous
//
#include <hip/hip_runtime.h>

#define SEQL 1024
#define DMODEL 512
#define DINNER 1024
#define NROWS 8192
#define PFD 8

typedef unsigned short u16;
typedef unsigned int u32;
using bf16x8 = __attribute__((ext_vector_type(8))) short;
using f32x4  = __attribute__((ext_vector_type(4))) float;
using u16x4  = __attribute__((ext_vector_type(4))) unsigned short;

__device__ __forceinline__ float rcp_fast(float x){ return __builtin_amdgcn_rcpf(x); }
__device__ __forceinline__ float exp_fast(float x){ return __expf(x); }
__device__ __forceinline__ float sigmoid_f(float x){ return rcp_fast(1.f+exp_fast(-x)); }
__device__ __forceinline__ float silu_f(float x){ return x*rcp_fast(1.f+exp_fast(-x)); }
__device__ __forceinline__ float softplus_f(float x){ return fmaxf(x,0.f)+__logf(1.f+exp_fast(-fabsf(x))); }
__device__ __forceinline__ float gelu_f(float x){
  float u2 = 1.5957691216057308f*(x+0.044715f*x*x*x);  // 2*sqrt(2/pi)*(...)
  float t = 1.f - 2.f*rcp_fast(1.f+exp_fast(u2));      // tanh(u2/2)
  return 0.5f*x*(1.f+t);
}
__device__ __forceinline__ u16 f2bf(float f){
  u32 u = __builtin_bit_cast(u32, f);
  return (u16)((u + 0x7FFFu + ((u>>16)&1u)) >> 16);
}
__device__ __forceinline__ float bf2f(u16 h){
  return __builtin_bit_cast(float, (u32)h << 16);
}

// ---------------- weight transpose+cvt: [K,N] fp32 -> [N,K] bf16 ---------------
struct WtDesc { const float* src; u16* dst; int K; int N; int t0; };
struct WtArgs { WtDesc d[11]; };

__global__ __launch_bounds__(256) void wt_k(WtArgs a)
{
  __shared__ float t[64][65];
  int bid = blockIdx.x;
  int i = 0;
  #pragma unroll
  for (int j=1;j<11;++j) if (bid >= a.d[j].t0) i = j;
  const float* src = a.d[i].src; u16* dst = a.d[i].dst;
  int K = a.d[i].K, N = a.d[i].N;
  int ntN = (N+63)>>6;
  int loc = bid - a.d[i].t0;
  int k0 = (loc / ntN)*64, n0 = (loc % ntN)*64;
  int tr = threadIdx.x>>4, tc = threadIdx.x&15;
  #pragma unroll
  for (int p=0;p<4;++p) {
    int r = p*16 + tr; int c = tc*4;
    if (n0 + c < N) {
      float4 v = *(const float4*)(src + (size_t)(k0+r)*N + n0 + c);
      t[r][c]=v.x; t[r][c+1]=v.y; t[r][c+2]=v.z; t[r][c+3]=v.w;
    }
  }
  __syncthreads();
  #pragma unroll
  for (int p=0;p<4;++p) {
    int n = p*16 + tr; int k = tc*4;
    if (n0 + n < N) {
      u16x4 o = { f2bf(t[k][n]), f2bf(t[k+1][n]), f2bf(t[k+2][n]), f2bf(t[k+3][n]) };
      *(u16x4*)(dst + (size_t)(n0+n)*K + k0 + k) = o;
    }
  }
}

// ---------------- bias concat for QKV -----------------------------------------
__global__ __launch_bounds__(256) void pack3_k(const float* a, const float* b,
                                               const float* c, float* o)
{
  int t = blockIdx.x*256 + threadIdx.x;
  if (t < 512) o[t] = a[t];
  else if (t < 1024) o[t] = b[t-512];
  else if (t < 1536) o[t] = c[t-1024];
}

// ---------------- LayerNorm (D=512), optional add-in, resid-out, f32/bf16 outs --
__global__ __launch_bounds__(128) void ln_k(const float* a, const float* b, float* resid,
                                            const float* g, const float* beta,
                                            float* outf, u16* outb)
{
  int row = blockIdx.x;
  int t = threadIdx.x;
  size_t off = (size_t)row*DMODEL + t*4;
  float4 v = *(const float4*)(a + off);
  if (b) {
    float4 w = *(const float4*)(b + off);
    v.x += w.x; v.y += w.y; v.z += w.z; v.w += w.w;
  }
  if (resid) *(float4*)(resid + off) = v;
  float s = v.x+v.y+v.z+v.w;
  float q = v.x*v.x+v.y*v.y+v.z*v.z+v.w*v.w;
  #pragma unroll
  for (int o=1;o<64;o<<=1){ s += __shfl_xor(s,o); q += __shfl_xor(q,o); }
  __shared__ float ss[2], qq[2];
  int w = t>>6;
  if ((t&63)==0){ ss[w]=s; qq[w]=q; }
  __syncthreads();
  s = ss[0]+ss[1]; q = qq[0]+qq[1];
  float mean = s*(1.f/512.f);
  float var  = q*(1.f/512.f) - mean*mean;
  float rstd = rsqrtf(var + 1e-5f);
  int c = t*4;
  float4 gg = *(const float4*)(g+c);
  float4 bb = *(const float4*)(beta+c);
  float4 o4;
  o4.x = (v.x-mean)*rstd*gg.x + bb.x;
  o4.y = (v.y-mean)*rstd*gg.y + bb.y;
  o4.z = (v.z-mean)*rstd*gg.z + bb.z;
  o4.w = (v.w-mean)*rstd*gg.w + bb.w;
  if (outf) *(float4*)(outf + off) = o4;
  if (outb) {
    u16x4 ob = { f2bf(o4.x), f2bf(o4.y), f2bf(o4.z), f2bf(o4.w) };
    *(u16x4*)(outb + off) = ob;
  }
}

// ---------------- bf16 MFMA GEMM, 128x128 tile, BK=32 --------------------------
// EPI: 0 f32, 1 f32+bias, 2 softplus(x+bias) f32, 3 gelu(x+bias) bf16, 4 x*scale f32,
//      5 x+bias+p0 f32, 6 gate fusion f32, 7 bf16, 9 f32 + aux bf16,
//      10 bias + transposed bf16 write to aux (V-mode),
//      11 QKV fused (cols 0-1023 -> Q/K bf16 + bias; 1024-1535 -> V transposed to aux),
//      12 BC|delta fused (cols 0-31 -> Cf raw; 32-1055 -> softplus+bias -> xf)
// BMODE: 0 plain, 1 scores (batch b*8+h over Q,K), 2 attnV (A=AW f32 batch), 3 stitched A|A2
// AF32: A operand is fp32, convert during staging
template<int EPI, int BMODE, bool AF32>
__global__ __launch_bounds__(256) void mm_k(
    const void* Av, int lda, const u16* Bb, int ldb,
    void* Cv, int ldc, int M, int N, int K,
    const float* bias, const float* p0, const float* p1, const float* p2,
    const void* A2v, u16* aux, float* xf, float scale)
{
  __shared__ u16 As[128][32];
  __shared__ u16 Bs[128][32];
  const int tid = threadIdx.x;
  const int bx = blockIdx.x, by = blockIdx.y, bz = blockIdx.z;
  const u16* Ab = (const u16*)Av;
  const float* Af = (const float*)Av;
  const u16* A2b = (const u16*)A2v;
  float* Cf = (float*)Cv;
  u16* Cb = (u16*)Cv;
  int bb = 0;
  if (BMODE==1) {
    bb = bz>>3; int hh = bz&7;
    Ab += (size_t)bb*SEQL*DMODEL + hh*64;
    Bb += (size_t)bb*SEQL*DMODEL + hh*64;
    Cf += (size_t)bz*SEQL*SEQL;
  } else if (BMODE==2) {
    bb = bz>>3; int hh = bz&7;
    Af += (size_t)bz*SEQL*SEQL;
    Bb += (size_t)bb*DMODEL*SEQL + (size_t)(hh*64)*SEQL;
    Cb += (size_t)bb*SEQL*DMODEL + hh*64;
  }
  const int row0 = by*128, col0 = bx*128;
  const int sr = tid>>2, sc = tid&3;
  const int wv = tid>>6, lane = tid&63;
  const int wr = wv>>1, wc = wv&1;
  const int lr = lane&15, lk = (lane>>4)*8;
  const int lq = lane>>4;

  f32x4 acc[4][4];
  #pragma unroll
  for (int i=0;i<4;++i)
    #pragma unroll
    for (int j=0;j<4;++j)
      acc[i][j] = (f32x4){0.f,0.f,0.f,0.f};

  for (int k0=0; k0<K; k0+=32) {
    #pragma unroll
    for (int h=0; h<2; ++h) {
      int row = sr + h*64;
      u16* dst = &As[row][sc*8];
      if (AF32) {
        const float* src = Af + (size_t)(row0+row)*lda + k0 + sc*8;
        float4 u0 = *(const float4*)src;
        float4 u1 = *(const float4*)(src+4);
        uint4 pk;
        pk.x = (u32)f2bf(u0.x) | ((u32)f2bf(u0.y)<<16);
        pk.y = (u32)f2bf(u0.z) | ((u32)f2bf(u0.w)<<16);
        pk.z = (u32)f2bf(u1.x) | ((u32)f2bf(u1.y)<<16);
        pk.w = (u32)f2bf(u1.z) | ((u32)f2bf(u1.w)<<16);
        *(uint4*)dst = pk;
      } else if (BMODE==3) {
        int kk = k0 + sc*8;
        const u16* src = (kk < 512) ? Ab + (size_t)(row0+row)*512 + kk
                                    : A2b + (size_t)(row0+row)*512 + (kk-512);
        *(uint4*)dst = *(const uint4*)src;
      } else {
        const u16* src = Ab + (size_t)(row0+row)*lda + k0 + sc*8;
        *(uint4*)dst = *(const uint4*)src;
      }
    }
    #pragma unroll
    for (int h=0; h<2; ++h) {
      int rowb = sr + h*64;
      int n = col0 + rowb;
      uint4 v = {0u,0u,0u,0u};
      if (n < N) v = *(const uint4*)(Bb + (size_t)n*ldb + k0 + sc*8);
      *(uint4*)&Bs[rowb][sc*8] = v;
    }
    __syncthreads();
    bf16x8 fa[4], fb[4];
    #pragma unroll
    for (int i=0;i<4;++i) fa[i] = *(const bf16x8*)&As[wr*64 + i*16 + lr][lk];
    #pragma unroll
    for (int j=0;j<4;++j) fb[j] = *(const bf16x8*)&Bs[wc*64 + j*16 + lr][lk];
    #pragma unroll
    for (int i=0;i<4;++i)
      #pragma unroll
      for (int j=0;j<4;++j)
        acc[i][j] = __builtin_amdgcn_mfma_f32_16x16x32_bf16(fa[i], fb[j], acc[i][j], 0,0,0);
    __syncthreads();
  }

  #pragma unroll
  for (int i=0;i<4;++i) {
    #pragma unroll
    for (int j=0;j<4;++j) {
      int col = col0 + wc*64 + j*16 + lr;
      if (col >= N) continue;
      int rowbase = row0 + wr*64 + i*16 + lq*4;
      f32x4 v4 = acc[i][j];
      if (EPI==10 || (EPI==11 && col >= 1024)) {
        int c2 = (EPI==11) ? col-1024 : col;
        int b2 = rowbase >> 10;
        int l2 = rowbase & 1023;
        float bv = bias[col];
        u16x4 pk = { f2bf(v4[0]+bv), f2bf(v4[1]+bv), f2bf(v4[2]+bv), f2bf(v4[3]+bv) };
        *(u16x4*)(aux + (size_t)b2*DMODEL*SEQL + (size_t)c2*SEQL + l2) = pk;
        continue;
      }
      #pragma unroll
      for (int r=0;r<4;++r) {
        int row = rowbase + r;
        size_t idx = (size_t)row*ldc + col;
        float v = v4[r];
        if (EPI==0) Cf[idx] = v;
        else if (EPI==1) Cf[idx] = v + bias[col];
        else if (EPI==2) Cf[idx] = softplus_f(v + bias[col]);
        else if (EPI==3) Cb[idx] = f2bf(gelu_f(v + bias[col]));
        else if (EPI==4) Cf[idx] = v*scale;
        else if (EPI==5) Cf[idx] = v + bias[col] + p0[idx];
        else if (EPI==6) {
          float g = sigmoid_f(v + bias[col]);
          float m = p0[idx], at = p1[idx];
          Cf[idx] = p2[idx] + at + g*m + (1.f-g)*at;
        }
        else if (EPI==7) Cb[idx] = f2bf(v);
        else if (EPI==9) { Cf[idx] = v; aux[idx] = f2bf(v); }
        else if (EPI==11) {
          size_t i2 = (size_t)(col>>9)*4194304 + (size_t)row*512 + (col&511);
          Cb[i2] = f2bf(v + bias[col]);
        }
        else if (EPI==12) {
          if (col < 32) Cf[(size_t)row*32 + col] = v;
          else xf[(size_t)row*1024 + (col-32)] = softplus_f(v + bias[col-32]);
        }
      }
    }
  }
}

// ---------------- causal depthwise conv (D_CONV=4) + SiLU, bf16 in, dual out ---
__global__ __launch_bounds__(256) void conv_k(const u16* xrb, const float* cw,
                                              const float* cb, float* xc, u16* xcb)
{
  int t = blockIdx.x*256 + threadIdx.x;
  int d = (t & 255)*4;
  int row = t >> 8;
  int l = row & (SEQL-1);
  const u16* xmb = xrb + (size_t)(row - l)*2048 + d;
  float wv[4][4];
  #pragma unroll
  for (int dd=0; dd<4; ++dd){
    float4 w = *(const float4*)(cw + (size_t)(d+dd)*4);
    wv[dd][0]=w.x; wv[dd][1]=w.y; wv[dd][2]=w.z; wv[dd][3]=w.w;
  }
  float4 acc = *(const float4*)(cb + d);
  #pragma unroll
  for (int k=0;k<4;++k){
    int ls = l + k - 3;
    if (ls >= 0) {
      u16x4 xv = *(const u16x4*)(xmb + (size_t)ls*2048);
      acc.x += wv[0][k]*bf2f(xv[0]);
      acc.y += wv[1][k]*bf2f(xv[1]);
      acc.z += wv[2][k]*bf2f(xv[2]);
      acc.w += wv[3][k]*bf2f(xv[3]);
    }
  }
  acc.x = silu_f(acc.x); acc.y = silu_f(acc.y);
  acc.z = silu_f(acc.z); acc.w = silu_f(acc.w);
  size_t off = (size_t)row*DINNER + d;
  *(float4*)(xc + off) = acc;
  u16x4 ob = { f2bf(acc.x), f2bf(acc.y), f2bf(acc.z), f2bf(acc.w) };
  *(u16x4*)(xcb + off) = ob;
}

// ---------------- selective scan, prefetch-8 pipeline ---------------------------
__global__ __launch_bounds__(256) void scan_k(const float* xc, const float* dtv,
                                              const float* bc, const u16* xrb,
                                              const float* A_log, const float* Dp,
                                              u16* yb)
{
  int b = blockIdx.y;
  int s = threadIdx.x & 15;
  int d = blockIdx.x*16 + (threadIdx.x >> 4);
  float A = -expf(A_log[s]);
  float dcoef = Dp[d];
  float h = 0.f;
  size_t base = (size_t)b*SEQL;
  const float* pdt  = dtv + base*DINNER + d;
  const float* pu   = xc  + base*DINNER + d;
  const float* pbc  = bc  + base*32 + s;
  const u16*   pres = xrb + base*2048 + 1024 + d;
  u16*         py   = yb  + base*DINNER + d;

  float dtb[PFD], ub[PFD], Bp[PFD], Cp[PFD]; u16 rb[PFD];
  #pragma unroll
  for (int j=0;j<PFD;++j){
    dtb[j] = pdt[(size_t)j*DINNER];
    ub[j]  = pu [(size_t)j*DINNER];
    Bp[j]  = pbc[j*32];
    Cp[j]  = pbc[j*32+16];
    rb[j]  = pres[(size_t)j*2048];
  }
  const float* pdt_f = pdt + (size_t)PFD*DINNER;
  const float* pu_f  = pu  + (size_t)PFD*DINNER;
  const float* pbc_f = pbc + PFD*32;
  const u16*   pres_f= pres+ (size_t)PFD*2048;

  for (int l=0; l<SEQL-PFD; l+=PFD) {
    #pragma unroll
    for (int j=0;j<PFD;++j) {
      float dt=dtb[j], u=ub[j], Bv=Bp[j], Cv=Cp[j]; u16 rr=rb[j];
      dtb[j]=*pdt_f; ub[j]=*pu_f; Bp[j]=pbc_f[0]; Cp[j]=pbc_f[16]; rb[j]=*pres_f;
      pdt_f += DINNER; pu_f += DINNER; pbc_f += 32; pres_f += 2048;
      float dA = exp_fast(dt*A);
      h = fmaf(h, dA, dt*Bv*u);
      float p = h*Cv;
      p += __shfl_xor(p,1); p += __shfl_xor(p,2);
      p += __shfl_xor(p,4); p += __shfl_xor(p,8);
      if (s == 0) {
        float r = bf2f(rr);
        float y = fmaf(u, dcoef, p);
        y *= r * rcp_fast(1.f + exp_fast(-r));
        *py = f2bf(y);
      }
      py += DINNER;
    }
  }
  #pragma unroll
  for (int j=0;j<PFD;++j) {
    float dt=dtb[j], u=ub[j], Bv=Bp[j], Cv=Cp[j]; u16 rr=rb[j];
    float dA = exp_fast(dt*A);
    h = fmaf(h, dA, dt*Bv*u);
    float p = h*Cv;
    p += __shfl_xor(p,1); p += __shfl_xor(p,2);
    p += __shfl_xor(p,4); p += __shfl_xor(p,8);
    if (s == 0) {
      float r = bf2f(rr);
      float y = fmaf(u, dcoef, p);
      y *= r * rcp_fast(1.f + exp_fast(-r));
      *py = f2bf(y);
    }
    py += DINNER;
  }
}

// ---------------- row softmax over 1024 cols, in place --------------------------
__global__ __launch_bounds__(256) void softmax_k(float* w)
{
  size_t row = blockIdx.x;
  float* p = w + row*SEQL + threadIdx.x*4;
  float4 v = *(const float4*)p;
  float m = fmaxf(fmaxf(v.x,v.y), fmaxf(v.z,v.w));
  #pragma unroll
  for (int o=1;o<64;o<<=1) m = fmaxf(m, __shfl_xor(m,o));
  __shared__ float sm[4], ssum[4];
  int wv = threadIdx.x>>6;
  if ((threadIdx.x&63)==0) sm[wv]=m;
  __syncthreads();
  m = fmaxf(fmaxf(sm[0],sm[1]), fmaxf(sm[2],sm[3]));
  v.x = exp_fast(v.x-m); v.y = exp_fast(v.y-m);
  v.z = exp_fast(v.z-m); v.w = exp_fast(v.w-m);
  float s = v.x+v.y+v.z+v.w;
  #pragma unroll
  for (int o=1;o<64;o<<=1) s += __shfl_xor(s,o);
  if ((threadIdx.x&63)==0) ssum[wv]=s;
  __syncthreads();
  s = ssum[0]+ssum[1]+ssum[2]+ssum[3];
  float inv = rcp_fast(s);
  v.x*=inv; v.y*=inv; v.z*=inv; v.w*=inv;
  *(float4*)p = v;
}

extern "C" void kernel_launch(void* const* d_in, const int* in_sizes, int n_in,
                              void* d_out, int out_size, void* d_ws, size_t ws_size,
                              hipStream_t stream)
{
  const float* x          = (const float*)d_in[0];
  const float* in_proj_w  = (const float*)d_in[1];
  const float* conv_w     = (const float*)d_in[2];
  const float* conv_b     = (const float*)d_in[3];
  const float* x_proj_w   = (const float*)d_in[4];
  const float* dt_proj_w  = (const float*)d_in[5];
  const float* dt_proj_b  = (const float*)d_in[6];
  const float* A_log      = (const float*)d_in[7];
  const float* Dvec       = (const float*)d_in[8];
  const float* out_proj_w = (const float*)d_in[9];
  const float* wq_w = (const float*)d_in[10]; const float* wq_b = (const float*)d_in[11];
  const float* wk_w = (const float*)d_in[12]; const float* wk_b = (const float*)d_in[13];
  const float* wv_w = (const float*)d_in[14]; const float* wv_b = (const float*)d_in[15];
  const float* wo_w = (const float*)d_in[16]; const float* wo_b = (const float*)d_in[17];
  const float* attn_ln_g = (const float*)d_in[18]; const float* attn_ln_b = (const float*)d_in[19];
  const float* ffn_w1 = (const float*)d_in[20]; const float* ffn_b1 = (const float*)d_in[21];
  const float* ffn_w2 = (const float*)d_in[22]; const float* ffn_b2 = (const float*)d_in[23];
  const float* norm1_g = (const float*)d_in[24]; const float* norm1_b = (const float*)d_in[25];
  const float* norm2_g = (const float*)d_in[26]; const float* norm2_b = (const float*)d_in[27];
  const float* norm3_g = (const float*)d_in[28]; const float* norm3_b = (const float*)d_in[29];
  const float* gate_w  = (const float*)d_in[30]; const float* gate_b  = (const float*)d_in[31];

  // ---- workspace layout ----
  float* ws  = (float*)d_ws;
  float* XC  = ws;                  // 8388608 f32 (u); reused WOUT
  float* DY  = XC + 8388608;        // 8388608 f32 (delta); reused ATT
  float* BC  = DY + 8388608;        // 262144  f32
  float* X1  = BC + 262144;         // 4194304 f32 (x1 -> x3)
  float* XN2 = X1 + 4194304;        // 4194304 f32
  float* MB  = XN2+ 4194304;        // 4194304 f32
  float* WOUT = XC;
  float* ATT  = DY;
  u16* WT0 = (u16*)(MB + 4194304);  // 6324224 halves transposed weights
  u16* XRb = WT0 + 6324224;         // 16777216 halves (xr); reused Q|K|VT|Hb; then FH
  u16* NB  = XRb + 16777216;        // 4194304 halves (xn1b -> xn2b -> xn3b)
  u16* XCb = NB  + 4194304;         // 8388608 halves (xc); reused MBb+ATTb
  u16* Yb  = XCb + 8388608;         // 8388608 halves (scan y)
  float* QKVB = (float*)(Yb + 8388608); // 1536 f32 packed qkv bias

  u16* Qb   = XRb;
  u16* Kb   = XRb + 4194304;
  u16* VTb  = XRb + 8388608;
  u16* Hbb  = XRb + 12582912;
  u16* FHb  = XRb;
  u16* MBb  = XCb;
  u16* ATTb = XCb + 4194304;

  u16* inprojT = WT0;               // [2048,512]
  u16* xprojT  = inprojT + 1048576; // [32,1024]   (contiguous with dtT -> stacked 1056)
  u16* dtT     = xprojT  + 32768;   // [1024,1024]
  u16* outT    = dtT     + 1048576; // [512,1024]
  u16* wqT     = outT    + 524288;  // [512,512]   (wq|wk|wv contiguous -> stacked 1536)
  u16* wkT     = wqT     + 262144;
  u16* wvT     = wkT     + 262144;
  u16* woT     = wvT     + 262144;
  u16* ffn1T   = woT     + 262144;  // [2048,512]
  u16* ffn2T   = ffn1T   + 1048576; // [512,2048]
  u16* gateT   = ffn2T   + 1048576; // [512,1024]

  float* XOUT = (float*)d_out;
  float* AW   = (float*)d_out + 4194304;

  const float* nulf = nullptr;
  u16* nulh = nullptr;
  float* nulx = nullptr;

  // 0) transpose + cvt all weights; pack qkv bias
  WtArgs wa;
  wa.d[0]  = { in_proj_w, inprojT, 512, 2048, 0 };
  wa.d[1]  = { x_proj_w,  xprojT, 1024,   32, 256 };
  wa.d[2]  = { dt_proj_w, dtT,    1024, 1024, 272 };
  wa.d[3]  = { out_proj_w,outT,   1024,  512, 528 };
  wa.d[4]  = { wq_w,      wqT,     512,  512, 656 };
  wa.d[5]  = { wk_w,      wkT,     512,  512, 720 };
  wa.d[6]  = { wv_w,      wvT,     512,  512, 784 };
  wa.d[7]  = { wo_w,      woT,     512,  512, 848 };
  wa.d[8]  = { ffn_w1,    ffn1T,   512, 2048, 912 };
  wa.d[9]  = { ffn_w2,    ffn2T,  2048,  512, 1168 };
  wa.d[10] = { gate_w,    gateT,  1024,  512, 1424 };
  wt_k<<<1552, 256, 0, stream>>>(wa);
  pack3_k<<<6, 256, 0, stream>>>(wq_b, wk_b, wv_b, QKVB);

  // 1) xn1b = LN(x)
  ln_k<<<NROWS, 128, 0, stream>>>(x, nullptr, nullptr, norm1_g, norm1_b, nullptr, NB);
  // 2) xrb = xn1 @ in_proj (bf16)
  mm_k<7,0,false><<<dim3(16,64), 256, 0, stream>>>(NB,512, inprojT,512, XRb,2048,
        NROWS,2048,512, nulf,nulf,nulf,nulf,nullptr,nulh,nulx,1.f);
  // 3) xc = silu(conv(xm)+cb), dual out
  conv_k<<<NROWS, 256, 0, stream>>>(XRb, conv_w, conv_b, XC, XCb);
  // 4+5) BC | delta fused: N=1056 over stacked [xprojT|dtT]
  mm_k<12,0,false><<<dim3(9,64), 256, 0, stream>>>(XCb,1024, xprojT,1024, BC,32,
        NROWS,1056,1024, dt_proj_b,nulf,nulf,nulf,nullptr,nulh,DY,1.f);
  // 6) selective scan -> Yb
  scan_k<<<dim3(64,8), 256, 0, stream>>>(XC, DY, BC, XRb, A_log, Dvec, Yb);
  // 7) mamba_out = y @ out_proj (f32 MB + bf16 MBb)
  mm_k<9,0,false><<<dim3(4,64), 256, 0, stream>>>(Yb,1024, outT,1024, MB,512,
        NROWS,512,1024, nulf,nulf,nulf,nulf,nullptr,MBb,nulx,1.f);
  // 8) x1 = x + mamba_out ; xn2 = LN(x1)
  ln_k<<<NROWS, 128, 0, stream>>>(x, MB, X1, norm2_g, norm2_b, XN2, NB);
  // 9) QKV fused: N=1536 over stacked [wqT|wkT|wvT]
  mm_k<11,0,false><<<dim3(12,64), 256, 0, stream>>>(NB,512, wqT,512, Qb,512,
        NROWS,1536,512, QKVB,nulf,nulf,nulf,nullptr,VTb,nulx,1.f);
  // 10) scores = Q K^T / 8 -> AW
  mm_k<4,1,false><<<dim3(8,8,64), 256, 0, stream>>>(Qb,512, Kb,512, AW,1024,
        SEQL,SEQL,64, nulf,nulf,nulf,nulf,nullptr,nulh,nulx,0.125f);
  // 11) softmax in place
  softmax_k<<<65536, 256, 0, stream>>>(AW);
  // 12) Hb = attn_w @ V (stage-convert A)
  mm_k<7,2,true><<<dim3(1,8,64), 256, 0, stream>>>(AW,1024, VTb,1024, Hbb,512,
        SEQL,64,SEQL, nulf,nulf,nulf,nulf,nullptr,nulh,nulx,1.f);
  // 13) WOUT = Hb @ wo + b
  mm_k<1,0,false><<<dim3(4,64), 256, 0, stream>>>(Hbb,512, woT,512, WOUT,512,
        NROWS,512,512, wo_b,nulf,nulf,nulf,nullptr,nulh,nulx,1.f);
  // 14) attn_out = LN(WOUT + xn2)
  ln_k<<<NROWS, 128, 0, stream>>>(WOUT, XN2, nullptr, attn_ln_g, attn_ln_b, ATT, ATTb);
  // 15) gate fusion -> X1
  mm_k<6,3,false><<<dim3(4,64), 256, 0, stream>>>(MBb,512, gateT,1024, X1,512,
        NROWS,512,1024, gate_b, MB, ATT, X1, ATTb, nulh,nulx,1.f);
  // 16) xn3b = LN(x3)
  ln_k<<<NROWS, 128, 0, stream>>>(X1, nullptr, nullptr, norm3_g, norm3_b, nullptr, NB);
  // 17) fh = gelu(xn3 @ ffn1 + b1)
  mm_k<3,0,false><<<dim3(16,64), 256, 0, stream>>>(NB,512, ffn1T,512, FHb,2048,
        NROWS,2048,512, ffn_b1,nulf,nulf,nulf,nullptr,nulh,nulx,1.f);
  // 18) out = x3 + fh @ ffn2 + b2 -> d_out
  mm_k<5,0,false><<<dim3(4,64), 256, 0, stream>>>(FHb,2048, ffn2T,2048, XOUT,512,
        NROWS,512,2048, ffn_b2, X1,nulf,nulf,nullptr,nulh,nulx,1.f);
}

// Round 4
// 821.760 us; speedup vs baseline: 3.4720x; 1.2055x over previous
//
#include <hip/hip_runtime.h>

#define SEQL 1024
#define DMODEL 512
#define DINNER 1024
#define NROWS 8192
#define SEG 64
#define NSEG 16
#define LOG2E 1.4426950408889634f

typedef unsigned short u16;
typedef unsigned int u32;
using bf16x8 = __attribute__((ext_vector_type(8))) short;
using f32x4  = __attribute__((ext_vector_type(4))) float;
using u16x4  = __attribute__((ext_vector_type(4))) unsigned short;

__device__ __forceinline__ float rcp_fast(float x){ return __builtin_amdgcn_rcpf(x); }
__device__ __forceinline__ float exp_fast(float x){ return __expf(x); }
#if __has_builtin(__builtin_amdgcn_exp2f)
__device__ __forceinline__ float exp2_fast(float x){ return __builtin_amdgcn_exp2f(x); }
#else
__device__ __forceinline__ float exp2_fast(float x){ return __expf(x*0.6931471805599453f); }
#endif
__device__ __forceinline__ float sigmoid_f(float x){ return rcp_fast(1.f+exp_fast(-x)); }
__device__ __forceinline__ float softplus_f(float x){ return fmaxf(x,0.f)+__logf(1.f+exp_fast(-fabsf(x))); }
__device__ __forceinline__ float gelu_f(float x){
  float u2 = 1.5957691216057308f*(x+0.044715f*x*x*x);
  float t = 1.f - 2.f*rcp_fast(1.f+exp_fast(u2));
  return 0.5f*x*(1.f+t);
}
__device__ __forceinline__ u16 f2bf(float f){
  u32 u = __builtin_bit_cast(u32, f);
  return (u16)((u + 0x7FFFu + ((u>>16)&1u)) >> 16);
}
__device__ __forceinline__ float bf2f(u16 h){
  return __builtin_bit_cast(float, (u32)h << 16);
}

// ---------------- weight transpose+cvt: [K,N] fp32 -> [N,K] bf16 ---------------
struct WtDesc { const float* src; u16* dst; int K; int N; int t0; };
struct WtArgs { WtDesc d[11]; };

__global__ __launch_bounds__(256) void wt_k(WtArgs a)
{
  __shared__ float t[64][65];
  int bid = blockIdx.x;
  int i = 0;
  #pragma unroll
  for (int j=1;j<11;++j) if (bid >= a.d[j].t0) i = j;
  const float* src = a.d[i].src; u16* dst = a.d[i].dst;
  int K = a.d[i].K, N = a.d[i].N;
  int ntN = (N+63)>>6;
  int loc = bid - a.d[i].t0;
  int k0 = (loc / ntN)*64, n0 = (loc % ntN)*64;
  int tr = threadIdx.x>>4, tc = threadIdx.x&15;
  #pragma unroll
  for (int p=0;p<4;++p) {
    int r = p*16 + tr; int c = tc*4;
    if (n0 + c < N) {
      float4 v = *(const float4*)(src + (size_t)(k0+r)*N + n0 + c);
      t[r][c]=v.x; t[r][c+1]=v.y; t[r][c+2]=v.z; t[r][c+3]=v.w;
    }
  }
  __syncthreads();
  #pragma unroll
  for (int p=0;p<4;++p) {
    int n = p*16 + tr; int k = tc*4;
    if (n0 + n < N) {
      u16x4 o = { f2bf(t[k][n]), f2bf(t[k+1][n]), f2bf(t[k+2][n]), f2bf(t[k+3][n]) };
      *(u16x4*)(dst + (size_t)(n0+n)*K + k0 + k) = o;
    }
  }
}

// ---------------- bias concat for QKV -----------------------------------------
__global__ __launch_bounds__(256) void pack3_k(const float* a, const float* b,
                                               const float* c, float* o)
{
  int t = blockIdx.x*256 + threadIdx.x;
  if (t < 512) o[t] = a[t];
  else if (t < 1024) o[t] = b[t-512];
  else if (t < 1536) o[t] = c[t-1024];
}

// ---------------- LayerNorm (D=512), optional add-in, resid-out, f32/bf16 outs --
__global__ __launch_bounds__(128) void ln_k(const float* a, const float* b, float* resid,
                                            const float* g, const float* beta,
                                            float* outf, u16* outb)
{
  int row = blockIdx.x;
  int t = threadIdx.x;
  size_t off = (size_t)row*DMODEL + t*4;
  float4 v = *(const float4*)(a + off);
  if (b) {
    float4 w = *(const float4*)(b + off);
    v.x += w.x; v.y += w.y; v.z += w.z; v.w += w.w;
  }
  if (resid) *(float4*)(resid + off) = v;
  float s = v.x+v.y+v.z+v.w;
  float q = v.x*v.x+v.y*v.y+v.z*v.z+v.w*v.w;
  #pragma unroll
  for (int o=1;o<64;o<<=1){ s += __shfl_xor(s,o); q += __shfl_xor(q,o); }
  __shared__ float ss[2], qq[2];
  int w = t>>6;
  if ((t&63)==0){ ss[w]=s; qq[w]=q; }
  __syncthreads();
  s = ss[0]+ss[1]; q = qq[0]+qq[1];
  float mean = s*(1.f/512.f);
  float var  = q*(1.f/512.f) - mean*mean;
  float rstd = rsqrtf(var + 1e-5f);
  int c = t*4;
  float4 gg = *(const float4*)(g+c);
  float4 bb = *(const float4*)(beta+c);
  float4 o4;
  o4.x = (v.x-mean)*rstd*gg.x + bb.x;
  o4.y = (v.y-mean)*rstd*gg.y + bb.y;
  o4.z = (v.z-mean)*rstd*gg.z + bb.z;
  o4.w = (v.w-mean)*rstd*gg.w + bb.w;
  if (outf) *(float4*)(outf + off) = o4;
  if (outb) {
    u16x4 ob = { f2bf(o4.x), f2bf(o4.y), f2bf(o4.z), f2bf(o4.w) };
    *(u16x4*)(outb + off) = ob;
  }
}

// ---------------- bf16 MFMA GEMM, 128x128 tile, BK=32 --------------------------
// EPI: 0 f32, 1 f32+bias, 2 softplus(x+bias) f32, 3 gelu(x+bias) bf16, 4 x*scale f32,
//      5 x+bias+p0 f32, 6 gate fusion f32, 7 bf16, 9 f32 + aux bf16,
//      10 bias + transposed bf16 write to aux (V-mode),
//      11 QKV fused (cols 0-1023 -> Q/K bf16 + bias; 1024-1535 -> V transposed to aux),
//      12 BC|delta fused (cols 0-31 -> Cf raw f32; 32-1055 -> softplus+bias -> bf16 aux)
// BMODE: 0 plain, 1 scores (batch b*8+h over Q,K), 2 attnV (A=AW f32 batch), 3 stitched A|A2
// AF32: A operand is fp32, convert during staging
template<int EPI, int BMODE, bool AF32>
__global__ __launch_bounds__(256) void mm_k(
    const void* Av, int lda, const u16* Bb, int ldb,
    void* Cv, int ldc, int M, int N, int K,
    const float* bias, const float* p0, const float* p1, const float* p2,
    const void* A2v, u16* aux, float scale)
{
  __shared__ u16 As[128][32];
  __shared__ u16 Bs[128][32];
  const int tid = threadIdx.x;
  const int bx = blockIdx.x, by = blockIdx.y, bz = blockIdx.z;
  const u16* Ab = (const u16*)Av;
  const float* Af = (const float*)Av;
  const u16* A2b = (const u16*)A2v;
  float* Cf = (float*)Cv;
  u16* Cb = (u16*)Cv;
  int bb = 0;
  if (BMODE==1) {
    bb = bz>>3; int hh = bz&7;
    Ab += (size_t)bb*SEQL*DMODEL + hh*64;
    Bb += (size_t)bb*SEQL*DMODEL + hh*64;
    Cf += (size_t)bz*SEQL*SEQL;
  } else if (BMODE==2) {
    bb = bz>>3; int hh = bz&7;
    Af += (size_t)bz*SEQL*SEQL;
    Bb += (size_t)bb*DMODEL*SEQL + (size_t)(hh*64)*SEQL;
    Cb += (size_t)bb*SEQL*DMODEL + hh*64;
  }
  const int row0 = by*128, col0 = bx*128;
  const int sr = tid>>2, sc = tid&3;
  const int wv = tid>>6, lane = tid&63;
  const int wr = wv>>1, wc = wv&1;
  const int lr = lane&15, lk = (lane>>4)*8;
  const int lq = lane>>4;

  f32x4 acc[4][4];
  #pragma unroll
  for (int i=0;i<4;++i)
    #pragma unroll
    for (int j=0;j<4;++j)
      acc[i][j] = (f32x4){0.f,0.f,0.f,0.f};

  for (int k0=0; k0<K; k0+=32) {
    #pragma unroll
    for (int h=0; h<2; ++h) {
      int row = sr + h*64;
      u16* dst = &As[row][sc*8];
      if (AF32) {
        const float* src = Af + (size_t)(row0+row)*lda + k0 + sc*8;
        float4 u0 = *(const float4*)src;
        float4 u1 = *(const float4*)(src+4);
        uint4 pk;
        pk.x = (u32)f2bf(u0.x) | ((u32)f2bf(u0.y)<<16);
        pk.y = (u32)f2bf(u0.z) | ((u32)f2bf(u0.w)<<16);
        pk.z = (u32)f2bf(u1.x) | ((u32)f2bf(u1.y)<<16);
        pk.w = (u32)f2bf(u1.z) | ((u32)f2bf(u1.w)<<16);
        *(uint4*)dst = pk;
      } else if (BMODE==3) {
        int kk = k0 + sc*8;
        const u16* src = (kk < 512) ? Ab + (size_t)(row0+row)*512 + kk
                                    : A2b + (size_t)(row0+row)*512 + (kk-512);
        *(uint4*)dst = *(const uint4*)src;
      } else {
        const u16* src = Ab + (size_t)(row0+row)*lda + k0 + sc*8;
        *(uint4*)dst = *(const uint4*)src;
      }
    }
    #pragma unroll
    for (int h=0; h<2; ++h) {
      int rowb = sr + h*64;
      int n = col0 + rowb;
      uint4 v = {0u,0u,0u,0u};
      if (n < N) v = *(const uint4*)(Bb + (size_t)n*ldb + k0 + sc*8);
      *(uint4*)&Bs[rowb][sc*8] = v;
    }
    __syncthreads();
    bf16x8 fa[4], fb[4];
    #pragma unroll
    for (int i=0;i<4;++i) fa[i] = *(const bf16x8*)&As[wr*64 + i*16 + lr][lk];
    #pragma unroll
    for (int j=0;j<4;++j) fb[j] = *(const bf16x8*)&Bs[wc*64 + j*16 + lr][lk];
    #pragma unroll
    for (int i=0;i<4;++i)
      #pragma unroll
      for (int j=0;j<4;++j)
        acc[i][j] = __builtin_amdgcn_mfma_f32_16x16x32_bf16(fa[i], fb[j], acc[i][j], 0,0,0);
    __syncthreads();
  }

  #pragma unroll
  for (int i=0;i<4;++i) {
    #pragma unroll
    for (int j=0;j<4;++j) {
      int col = col0 + wc*64 + j*16 + lr;
      if (col >= N) continue;
      int rowbase = row0 + wr*64 + i*16 + lq*4;
      f32x4 v4 = acc[i][j];
      if (EPI==10 || (EPI==11 && col >= 1024)) {
        int c2 = (EPI==11) ? col-1024 : col;
        int b2 = rowbase >> 10;
        int l2 = rowbase & 1023;
        float bv = bias[col];
        u16x4 pk = { f2bf(v4[0]+bv), f2bf(v4[1]+bv), f2bf(v4[2]+bv), f2bf(v4[3]+bv) };
        *(u16x4*)(aux + (size_t)b2*DMODEL*SEQL + (size_t)c2*SEQL + l2) = pk;
        continue;
      }
      #pragma unroll
      for (int r=0;r<4;++r) {
        int row = rowbase + r;
        size_t idx = (size_t)row*ldc + col;
        float v = v4[r];
        if (EPI==0) Cf[idx] = v;
        else if (EPI==1) Cf[idx] = v + bias[col];
        else if (EPI==2) Cf[idx] = softplus_f(v + bias[col]);
        else if (EPI==3) Cb[idx] = f2bf(gelu_f(v + bias[col]));
        else if (EPI==4) Cf[idx] = v*scale;
        else if (EPI==5) Cf[idx] = v + bias[col] + p0[idx];
        else if (EPI==6) {
          float g = sigmoid_f(v + bias[col]);
          float m = p0[idx], at = p1[idx];
          Cf[idx] = p2[idx] + at + g*m + (1.f-g)*at;
        }
        else if (EPI==7) Cb[idx] = f2bf(v);
        else if (EPI==9) { Cf[idx] = v; aux[idx] = f2bf(v); }
        else if (EPI==11) {
          size_t i2 = (size_t)(col>>9)*4194304 + (size_t)row*512 + (col&511);
          Cb[i2] = f2bf(v + bias[col]);
        }
        else if (EPI==12) {
          if (col < 32) Cf[(size_t)row*32 + col] = v;
          else aux[(size_t)row*1024 + (col-32)] = f2bf(softplus_f(v + bias[col-32]));
        }
      }
    }
  }
}

// ---------------- causal depthwise conv (D_CONV=4) + SiLU, bf16 in/out ---------
__global__ __launch_bounds__(256) void conv_k(const u16* xrb, const float* cw,
                                              const float* cb, u16* xcb)
{
  int t = blockIdx.x*256 + threadIdx.x;
  int d = (t & 255)*4;
  int row = t >> 8;
  int l = row & (SEQL-1);
  const u16* xmb = xrb + (size_t)(row - l)*2048 + d;
  float wv[4][4];
  #pragma unroll
  for (int dd=0; dd<4; ++dd){
    float4 w = *(const float4*)(cw + (size_t)(d+dd)*4);
    wv[dd][0]=w.x; wv[dd][1]=w.y; wv[dd][2]=w.z; wv[dd][3]=w.w;
  }
  float4 acc = *(const float4*)(cb + d);
  #pragma unroll
  for (int k=0;k<4;++k){
    int ls = l + k - 3;
    if (ls >= 0) {
      u16x4 xv = *(const u16x4*)(xmb + (size_t)ls*2048);
      acc.x += wv[0][k]*bf2f(xv[0]);
      acc.y += wv[1][k]*bf2f(xv[1]);
      acc.z += wv[2][k]*bf2f(xv[2]);
      acc.w += wv[3][k]*bf2f(xv[3]);
    }
  }
  float sx = acc.x*rcp_fast(1.f+exp_fast(-acc.x));
  float sy = acc.y*rcp_fast(1.f+exp_fast(-acc.y));
  float sz = acc.z*rcp_fast(1.f+exp_fast(-acc.z));
  float sw = acc.w*rcp_fast(1.f+exp_fast(-acc.w));
  size_t off = (size_t)row*DINNER + d;
  u16x4 ob = { f2bf(sx), f2bf(sy), f2bf(sz), f2bf(sw) };
  *(u16x4*)(xcb + off) = ob;
}

// ---------------- selective scan, chunked two-pass -----------------------------
// lane = one d channel; 16 state chains in registers; B/C staged in LDS.
// scan1: per segment (64 steps) compute P[s]=prod dA, q[s]=h_end from h0=0.
// Pq layout: [b][seg][32][1024] (rows 0-15 = P, 16-31 = q), indexed by d.
__global__ __launch_bounds__(256) void scan1_k(const u16* dtb, const u16* ub,
                                               const float* bc, const float* A_log,
                                               float* Pq)
{
  const int tid = threadIdx.x;
  const int d   = blockIdx.x*256 + tid;
  const int seg = blockIdx.y;
  const int b   = blockIdx.z;
  const int l0  = seg*SEG;

  __shared__ float BCs[SEG*32];
  {
    const float4* src = (const float4*)(bc + ((size_t)b*SEQL + l0)*32);
    float4* dst = (float4*)BCs;
    dst[tid]     = src[tid];
    dst[tid+256] = src[tid+256];
  }
  float As2[16];
  #pragma unroll
  for (int s=0;s<16;++s) As2[s] = -expf(A_log[s]) * LOG2E;
  __syncthreads();

  float h[16], P[16];
  #pragma unroll
  for (int s=0;s<16;++s){ h[s]=0.f; P[s]=1.f; }

  size_t base = ((size_t)b*SEQL + l0)*DINNER + d;
  const u16* pdt = dtb + base;
  const u16* pu  = ub  + base;

  u16 dpf[8], upf[8];
  #pragma unroll
  for (int j=0;j<8;++j){ dpf[j]=pdt[(size_t)j*DINNER]; upf[j]=pu[(size_t)j*DINNER]; }
  const u16* pdt_f = pdt + (size_t)8*DINNER;
  const u16* pu_f  = pu  + (size_t)8*DINNER;

  for (int l=0; l<SEG; l+=8) {
    bool pf = (l+8 < SEG);
    #pragma unroll
    for (int j=0;j<8;++j) {
      float dt = bf2f(dpf[j]), u = bf2f(upf[j]);
      if (pf) { dpf[j] = *pdt_f; upf[j] = *pu_f; }
      pdt_f += DINNER; pu_f += DINNER;
      float dtu = dt*u;
      const float* Bs = &BCs[(l+j)*32];
      #pragma unroll
      for (int s=0;s<16;++s) {
        float dA = exp2_fast(dt*As2[s]);
        P[s] *= dA;
        h[s] = fmaf(h[s], dA, dtu*Bs[s]);
      }
    }
  }
  float* out = Pq + (((size_t)b*NSEG + seg)*32)*1024 + d;
  #pragma unroll
  for (int s=0;s<16;++s) {
    out[(size_t)s*1024]      = P[s];
    out[(size_t)(16+s)*1024] = h[s];
  }
}

// scan2: combine prefix (h = P*h + q over preceding segments), rerun segment, emit y
__global__ __launch_bounds__(256) void scan2_k(const u16* dtb, const u16* ub,
                                               const float* bc, const u16* xrb,
                                               const float* A_log, const float* Dp,
                                               const float* Pq, u16* yb)
{
  const int tid = threadIdx.x;
  const int d   = blockIdx.x*256 + tid;
  const int seg = blockIdx.y;
  const int b   = blockIdx.z;
  const int l0  = seg*SEG;

  __shared__ float BCs[SEG*32];
  {
    const float4* src = (const float4*)(bc + ((size_t)b*SEQL + l0)*32);
    float4* dst = (float4*)BCs;
    dst[tid]     = src[tid];
    dst[tid+256] = src[tid+256];
  }
  float As2[16];
  #pragma unroll
  for (int s=0;s<16;++s) As2[s] = -expf(A_log[s]) * LOG2E;
  float dcoef = Dp[d];
  __syncthreads();

  float h[16];
  #pragma unroll
  for (int s=0;s<16;++s) h[s]=0.f;

  const float* pp = Pq + ((size_t)b*NSEG)*32*1024 + d;
  for (int sg=0; sg<seg; ++sg) {
    const float* q = pp + (size_t)sg*32*1024;
    #pragma unroll
    for (int s=0;s<16;++s)
      h[s] = fmaf(h[s], q[(size_t)s*1024], q[(size_t)(16+s)*1024]);
  }

  size_t rbase = (size_t)b*SEQL + l0;
  const u16* pdt = dtb + rbase*DINNER + d;
  const u16* pu  = ub  + rbase*DINNER + d;
  const u16* pr  = xrb + rbase*2048 + 1024 + d;
  u16*       py  = yb  + rbase*DINNER + d;

  u16 dpf[8], upf[8], rpf[8];
  #pragma unroll
  for (int j=0;j<8;++j){
    dpf[j]=pdt[(size_t)j*DINNER]; upf[j]=pu[(size_t)j*DINNER]; rpf[j]=pr[(size_t)j*2048];
  }
  const u16* pdt_f = pdt + (size_t)8*DINNER;
  const u16* pu_f  = pu  + (size_t)8*DINNER;
  const u16* pr_f  = pr  + (size_t)8*2048;

  for (int l=0; l<SEG; l+=8) {
    bool pf = (l+8 < SEG);
    #pragma unroll
    for (int j=0;j<8;++j) {
      float dt = bf2f(dpf[j]), u = bf2f(upf[j]), rv = bf2f(rpf[j]);
      if (pf) { dpf[j] = *pdt_f; upf[j] = *pu_f; rpf[j] = *pr_f; }
      pdt_f += DINNER; pu_f += DINNER; pr_f += 2048;
      float dtu = dt*u;
      float acc = 0.f;
      const float* Bs = &BCs[(l+j)*32];
      #pragma unroll
      for (int s=0;s<16;++s) {
        float dA = exp2_fast(dt*As2[s]);
        h[s] = fmaf(h[s], dA, dtu*Bs[s]);
        acc  = fmaf(h[s], Bs[16+s], acc);
      }
      float y = fmaf(u, dcoef, acc);
      y *= rv * rcp_fast(1.f + exp2_fast(rv*(-LOG2E)));
      *py = f2bf(y);
      py += DINNER;
    }
  }
}

// ---------------- row softmax over 1024 cols, in place --------------------------
__global__ __launch_bounds__(256) void softmax_k(float* w)
{
  size_t row = blockIdx.x;
  float* p = w + row*SEQL + threadIdx.x*4;
  float4 v = *(const float4*)p;
  float m = fmaxf(fmaxf(v.x,v.y), fmaxf(v.z,v.w));
  #pragma unroll
  for (int o=1;o<64;o<<=1) m = fmaxf(m, __shfl_xor(m,o));
  __shared__ float sm[4], ssum[4];
  int wv = threadIdx.x>>6;
  if ((threadIdx.x&63)==0) sm[wv]=m;
  __syncthreads();
  m = fmaxf(fmaxf(sm[0],sm[1]), fmaxf(sm[2],sm[3]));
  v.x = exp_fast(v.x-m); v.y = exp_fast(v.y-m);
  v.z = exp_fast(v.z-m); v.w = exp_fast(v.w-m);
  float s = v.x+v.y+v.z+v.w;
  #pragma unroll
  for (int o=1;o<64;o<<=1) s += __shfl_xor(s,o);
  if ((threadIdx.x&63)==0) ssum[wv]=s;
  __syncthreads();
  s = ssum[0]+ssum[1]+ssum[2]+ssum[3];
  float inv = rcp_fast(s);
  v.x*=inv; v.y*=inv; v.z*=inv; v.w*=inv;
  *(float4*)p = v;
}

extern "C" void kernel_launch(void* const* d_in, const int* in_sizes, int n_in,
                              void* d_out, int out_size, void* d_ws, size_t ws_size,
                              hipStream_t stream)
{
  const float* x          = (const float*)d_in[0];
  const float* in_proj_w  = (const float*)d_in[1];
  const float* conv_w     = (const float*)d_in[2];
  const float* conv_b     = (const float*)d_in[3];
  const float* x_proj_w   = (const float*)d_in[4];
  const float* dt_proj_w  = (const float*)d_in[5];
  const float* dt_proj_b  = (const float*)d_in[6];
  const float* A_log      = (const float*)d_in[7];
  const float* Dvec       = (const float*)d_in[8];
  const float* out_proj_w = (const float*)d_in[9];
  const float* wq_w = (const float*)d_in[10]; const float* wq_b = (const float*)d_in[11];
  const float* wk_w = (const float*)d_in[12]; const float* wk_b = (const float*)d_in[13];
  const float* wv_w = (const float*)d_in[14]; const float* wv_b = (const float*)d_in[15];
  const float* wo_w = (const float*)d_in[16]; const float* wo_b = (const float*)d_in[17];
  const float* attn_ln_g = (const float*)d_in[18]; const float* attn_ln_b = (const float*)d_in[19];
  const float* ffn_w1 = (const float*)d_in[20]; const float* ffn_b1 = (const float*)d_in[21];
  const float* ffn_w2 = (const float*)d_in[22]; const float* ffn_b2 = (const float*)d_in[23];
  const float* norm1_g = (const float*)d_in[24]; const float* norm1_b = (const float*)d_in[25];
  const float* norm2_g = (const float*)d_in[26]; const float* norm2_b = (const float*)d_in[27];
  const float* norm3_g = (const float*)d_in[28]; const float* norm3_b = (const float*)d_in[29];
  const float* gate_w  = (const float*)d_in[30]; const float* gate_b  = (const float*)d_in[31];

  // ---- workspace layout ----
  float* ws  = (float*)d_ws;
  float* BC   = ws;                 // 262144 f32
  float* X1   = BC  + 262144;       // 4194304 f32 (x1 -> x3)
  float* XN2  = X1  + 4194304;      // 4194304 f32
  float* MB   = XN2 + 4194304;      // 4194304 f32
  float* WOUT = MB  + 4194304;      // 4194304 f32
  float* ATT  = WOUT+ 4194304;      // 4194304 f32
  float* Pq   = ATT + 4194304;      // 4194304 f32  [8][16][32][1024]
  u16* WT0 = (u16*)(Pq + 4194304);  // 6324224 u16 transposed weights
  u16* XRb = WT0 + 6324224;         // 16777216 u16 (xr); reused Q|K|VT|Hb; then FH
  u16* NB  = XRb + 16777216;        // 4194304 u16 (xn1b -> xn2b -> xn3b)
  u16* XCb = NB  + 4194304;         // 8388608 u16 (xc = u, bf16)
  u16* DTb = XCb + 8388608;         // 8388608 u16 (delta bf16)
  u16* Yb  = DTb + 8388608;         // 8388608 u16 (scan y bf16)
  float* QKVB = (float*)(Yb + 8388608); // 1536 f32

  u16* Qb   = XRb;
  u16* Kb   = XRb + 4194304;
  u16* VTb  = XRb + 8388608;
  u16* Hbb  = XRb + 12582912;
  u16* FHb  = XRb;
  u16* MBb  = XCb;
  u16* ATTb = XCb + 4194304;

  u16* inprojT = WT0;               // [2048,512]
  u16* xprojT  = inprojT + 1048576; // [32,1024]   (stacked with dtT -> 1056 rows)
  u16* dtT     = xprojT  + 32768;   // [1024,1024]
  u16* outT    = dtT     + 1048576; // [512,1024]
  u16* wqT     = outT    + 524288;  // [512,512]   (wq|wk|wv stacked -> 1536 rows)
  u16* wkT     = wqT     + 262144;
  u16* wvT     = wkT     + 262144;
  u16* woT     = wvT     + 262144;
  u16* ffn1T   = woT     + 262144;  // [2048,512]
  u16* ffn2T   = ffn1T   + 1048576; // [512,2048]
  u16* gateT   = ffn2T   + 1048576; // [512,1024]

  float* XOUT = (float*)d_out;
  float* AW   = (float*)d_out + 4194304;

  const float* nulf = nullptr;
  u16* nulh = nullptr;

  // 0) transpose + cvt weights; pack qkv bias
  WtArgs wa;
  wa.d[0]  = { in_proj_w, inprojT, 512, 2048, 0 };
  wa.d[1]  = { x_proj_w,  xprojT, 1024,   32, 256 };
  wa.d[2]  = { dt_proj_w, dtT,    1024, 1024, 272 };
  wa.d[3]  = { out_proj_w,outT,   1024,  512, 528 };
  wa.d[4]  = { wq_w,      wqT,     512,  512, 656 };
  wa.d[5]  = { wk_w,      wkT,     512,  512, 720 };
  wa.d[6]  = { wv_w,      wvT,     512,  512, 784 };
  wa.d[7]  = { wo_w,      woT,     512,  512, 848 };
  wa.d[8]  = { ffn_w1,    ffn1T,   512, 2048, 912 };
  wa.d[9]  = { ffn_w2,    ffn2T,  2048,  512, 1168 };
  wa.d[10] = { gate_w,    gateT,  1024,  512, 1424 };
  wt_k<<<1552, 256, 0, stream>>>(wa);
  pack3_k<<<6, 256, 0, stream>>>(wq_b, wk_b, wv_b, QKVB);

  // 1) xn1b = LN(x)
  ln_k<<<NROWS, 128, 0, stream>>>(x, nullptr, nullptr, norm1_g, norm1_b, nullptr, NB);
  // 2) xrb = xn1 @ in_proj (bf16)
  mm_k<7,0,false><<<dim3(16,64), 256, 0, stream>>>(NB,512, inprojT,512, XRb,2048,
        NROWS,2048,512, nulf,nulf,nulf,nulf,nullptr,nulh,1.f);
  // 3) xc = silu(conv(xm)+cb) (bf16)
  conv_k<<<NROWS, 256, 0, stream>>>(XRb, conv_w, conv_b, XCb);
  // 4+5) BC (f32) | delta (bf16) fused: N=1056 over stacked [xprojT|dtT]
  mm_k<12,0,false><<<dim3(9,64), 256, 0, stream>>>(XCb,1024, xprojT,1024, BC,32,
        NROWS,1056,1024, dt_proj_b,nulf,nulf,nulf,nullptr,DTb,1.f);
  // 6) chunked scan: pass 1 (P,q per segment), pass 2 (emit y)
  scan1_k<<<dim3(4,NSEG-1,8), 256, 0, stream>>>(DTb, XCb, BC, A_log, Pq);
  scan2_k<<<dim3(4,NSEG,8),   256, 0, stream>>>(DTb, XCb, BC, XRb, A_log, Dvec, Pq, Yb);
  // 7) mamba_out = y @ out_proj (f32 MB + bf16 MBb)
  mm_k<9,0,false><<<dim3(4,64), 256, 0, stream>>>(Yb,1024, outT,1024, MB,512,
        NROWS,512,1024, nulf,nulf,nulf,nulf,nullptr,MBb,1.f);
  // 8) x1 = x + mamba_out ; xn2 = LN(x1)
  ln_k<<<NROWS, 128, 0, stream>>>(x, MB, X1, norm2_g, norm2_b, XN2, NB);
  // 9) QKV fused: N=1536 over stacked [wqT|wkT|wvT]
  mm_k<11,0,false><<<dim3(12,64), 256, 0, stream>>>(NB,512, wqT,512, Qb,512,
        NROWS,1536,512, QKVB,nulf,nulf,nulf,nullptr,VTb,1.f);
  // 10) scores = Q K^T / 8 -> AW
  mm_k<4,1,false><<<dim3(8,8,64), 256, 0, stream>>>(Qb,512, Kb,512, AW,1024,
        SEQL,SEQL,64, nulf,nulf,nulf,nulf,nullptr,nulh,0.125f);
  // 11) softmax in place
  softmax_k<<<65536, 256, 0, stream>>>(AW);
  // 12) Hb = attn_w @ V (stage-convert A)
  mm_k<7,2,true><<<dim3(1,8,64), 256, 0, stream>>>(AW,1024, VTb,1024, Hbb,512,
        SEQL,64,SEQL, nulf,nulf,nulf,nulf,nullptr,nulh,1.f);
  // 13) WOUT = Hb @ wo + b
  mm_k<1,0,false><<<dim3(4,64), 256, 0, stream>>>(Hbb,512, woT,512, WOUT,512,
        NROWS,512,512, wo_b,nulf,nulf,nulf,nullptr,nulh,1.f);
  // 14) attn_out = LN(WOUT + xn2)
  ln_k<<<NROWS, 128, 0, stream>>>(WOUT, XN2, nullptr, attn_ln_g, attn_ln_b, ATT, ATTb);
  // 15) gate fusion -> X1 (x3 in place)
  mm_k<6,3,false><<<dim3(4,64), 256, 0, stream>>>(MBb,512, gateT,1024, X1,512,
        NROWS,512,1024, gate_b, MB, ATT, X1, ATTb, nulh,1.f);
  // 16) xn3b = LN(x3)
  ln_k<<<NROWS, 128, 0, stream>>>(X1, nullptr, nullptr, norm3_g, norm3_b, nullptr, NB);
  // 17) fh = gelu(xn3 @ ffn1 + b1) (bf16)
  mm_k<3,0,false><<<dim3(16,64), 256, 0, stream>>>(NB,512, ffn1T,512, FHb,2048,
        NROWS,2048,512, ffn_b1,nulf,nulf,nulf,nullptr,nulh,1.f);
  // 18) out = x3 + fh @ ffn2 + b2 -> d_out
  mm_k<5,0,false><<<dim3(4,64), 256, 0, stream>>>(FHb,2048, ffn2T,2048, XOUT,512,
        NROWS,512,2048, ffn_b2, X1,nulf,nulf,nullptr,nulh,1.f);
}

// Round 5
// 671.023 us; speedup vs baseline: 4.2519x; 1.2246x over previous
//
#include <hip/hip_runtime.h>

#define SEQL 1024
#define DMODEL 512
#define DINNER 1024
#define NROWS 8192
#define SEG 64
#define NSEG 16
#define LOG2E 1.4426950408889634f

typedef unsigned short u16;
typedef unsigned int u32;
using bf16x8 = __attribute__((ext_vector_type(8))) short;
using f32x4  = __attribute__((ext_vector_type(4))) float;
using u16x4  = __attribute__((ext_vector_type(4))) unsigned short;

__device__ __forceinline__ float rcp_fast(float x){ return __builtin_amdgcn_rcpf(x); }
__device__ __forceinline__ float exp_fast(float x){ return __expf(x); }
#if __has_builtin(__builtin_amdgcn_exp2f)
__device__ __forceinline__ float exp2_fast(float x){ return __builtin_amdgcn_exp2f(x); }
#else
__device__ __forceinline__ float exp2_fast(float x){ return __expf(x*0.6931471805599453f); }
#endif
__device__ __forceinline__ float sigmoid_f(float x){ return rcp_fast(1.f+exp_fast(-x)); }
__device__ __forceinline__ float softplus_f(float x){ return fmaxf(x,0.f)+__logf(1.f+exp_fast(-fabsf(x))); }
__device__ __forceinline__ float gelu_f(float x){
  float u2 = 1.5957691216057308f*(x+0.044715f*x*x*x);
  float t = 1.f - 2.f*rcp_fast(1.f+exp_fast(u2));
  return 0.5f*x*(1.f+t);
}
__device__ __forceinline__ u16 f2bf(float f){
  u32 u = __builtin_bit_cast(u32, f);
  return (u16)((u + 0x7FFFu + ((u>>16)&1u)) >> 16);
}
__device__ __forceinline__ float bf2f(u16 h){
  return __builtin_bit_cast(float, (u32)h << 16);
}

// async global -> LDS, 16B per lane (LDS dest must be linear in lane order)
typedef __attribute__((address_space(1))) const void g_void;
typedef __attribute__((address_space(3))) void l_void;
__device__ __forceinline__ void gl_lds16(const void* g, void* l){
  __builtin_amdgcn_global_load_lds((g_void*)g, (l_void*)l, 16, 0, 0);
}

// ---------------- weight transpose+cvt: [K,N] fp32 -> [N,K] bf16 ---------------
struct WtDesc { const float* src; u16* dst; int K; int N; int t0; };
struct WtArgs { WtDesc d[11]; };

__global__ __launch_bounds__(256) void wt_k(WtArgs a)
{
  __shared__ float t[64][65];
  int bid = blockIdx.x;
  int i = 0;
  #pragma unroll
  for (int j=1;j<11;++j) if (bid >= a.d[j].t0) i = j;
  const float* src = a.d[i].src; u16* dst = a.d[i].dst;
  int K = a.d[i].K, N = a.d[i].N;
  int ntN = (N+63)>>6;
  int loc = bid - a.d[i].t0;
  int k0 = (loc / ntN)*64, n0 = (loc % ntN)*64;
  int tr = threadIdx.x>>4, tc = threadIdx.x&15;
  #pragma unroll
  for (int p=0;p<4;++p) {
    int r = p*16 + tr; int c = tc*4;
    if (n0 + c < N) {
      float4 v = *(const float4*)(src + (size_t)(k0+r)*N + n0 + c);
      t[r][c]=v.x; t[r][c+1]=v.y; t[r][c+2]=v.z; t[r][c+3]=v.w;
    }
  }
  __syncthreads();
  #pragma unroll
  for (int p=0;p<4;++p) {
    int n = p*16 + tr; int k = tc*4;
    if (n0 + n < N) {
      u16x4 o = { f2bf(t[k][n]), f2bf(t[k+1][n]), f2bf(t[k+2][n]), f2bf(t[k+3][n]) };
      *(u16x4*)(dst + (size_t)(n0+n)*K + k0 + k) = o;
    }
  }
}

// ---------------- bias concat for QKV -----------------------------------------
__global__ __launch_bounds__(256) void pack3_k(const float* a, const float* b,
                                               const float* c, float* o)
{
  int t = blockIdx.x*256 + threadIdx.x;
  if (t < 512) o[t] = a[t];
  else if (t < 1024) o[t] = b[t-512];
  else if (t < 1536) o[t] = c[t-1024];
}

// ---------------- LayerNorm (D=512), optional add-in, resid-out, f32/bf16 outs --
__global__ __launch_bounds__(128) void ln_k(const float* a, const float* b, float* resid,
                                            const float* g, const float* beta,
                                            float* outf, u16* outb)
{
  int row = blockIdx.x;
  int t = threadIdx.x;
  size_t off = (size_t)row*DMODEL + t*4;
  float4 v = *(const float4*)(a + off);
  if (b) {
    float4 w = *(const float4*)(b + off);
    v.x += w.x; v.y += w.y; v.z += w.z; v.w += w.w;
  }
  if (resid) *(float4*)(resid + off) = v;
  float s = v.x+v.y+v.z+v.w;
  float q = v.x*v.x+v.y*v.y+v.z*v.z+v.w*v.w;
  #pragma unroll
  for (int o=1;o<64;o<<=1){ s += __shfl_xor(s,o); q += __shfl_xor(q,o); }
  __shared__ float ss[2], qq[2];
  int w = t>>6;
  if ((t&63)==0){ ss[w]=s; qq[w]=q; }
  __syncthreads();
  s = ss[0]+ss[1]; q = qq[0]+qq[1];
  float mean = s*(1.f/512.f);
  float var  = q*(1.f/512.f) - mean*mean;
  float rstd = rsqrtf(var + 1e-5f);
  int c = t*4;
  float4 gg = *(const float4*)(g+c);
  float4 bb = *(const float4*)(beta+c);
  float4 o4;
  o4.x = (v.x-mean)*rstd*gg.x + bb.x;
  o4.y = (v.y-mean)*rstd*gg.y + bb.y;
  o4.z = (v.z-mean)*rstd*gg.z + bb.z;
  o4.w = (v.w-mean)*rstd*gg.w + bb.w;
  if (outf) *(float4*)(outf + off) = o4;
  if (outb) {
    u16x4 ob = { f2bf(o4.x), f2bf(o4.y), f2bf(o4.z), f2bf(o4.w) };
    *(u16x4*)(outb + off) = ob;
  }
}

// ---------------- bf16 MFMA GEMM, 128x128 tile, BK=32, global_load_lds staging --
// EPI: 1 f32+bias, 3 gelu(x+bias) bf16, 5 x+bias+p0 f32, 6 gate fusion f32,
//      7 bf16, 9 f32 + aux bf16,
//      11 QKV fused (cols 0-1023 -> Q/K bf16 + bias; 1024-1535 -> V transposed to aux),
//      12 BC|delta fused (cols 0-31 -> Cf raw f32; 32-1055 -> softplus+bias -> bf16 aux)
// BMODE: 0 plain, 3 stitched A|A2 (K=1024)
template<int EPI, int BMODE>
__global__ __launch_bounds__(256) void mm_k(
    const u16* Ab, int lda, const u16* Bb, int ldb,
    void* Cv, int ldc, int M, int N, int K,
    const float* bias, const float* p0, const float* p1, const float* p2,
    const u16* A2b, u16* aux)
{
  __shared__ u16 As[128][32];
  __shared__ u16 Bs[128][32];
  const int tid = threadIdx.x;
  const int bx = blockIdx.x, by = blockIdx.y;
  float* Cf = (float*)Cv;
  u16* Cb = (u16*)Cv;
  const int row0 = by*128, col0 = bx*128;
  const int sr = tid>>2, sc = tid&3;
  const int wv = tid>>6, lane = tid&63;
  const int wr = wv>>1, wc = wv&1;
  const int lr = lane&15, lk = (lane>>4)*8;
  const int lq = lane>>4;

  f32x4 acc[4][4];
  #pragma unroll
  for (int i=0;i<4;++i)
    #pragma unroll
    for (int j=0;j<4;++j)
      acc[i][j] = (f32x4){0.f,0.f,0.f,0.f};

  for (int k0=0; k0<K; k0+=32) {
    #pragma unroll
    for (int h=0; h<2; ++h) {
      int row = sr + h*64;
      const u16* src;
      if (BMODE==3) {
        int kk = k0 + sc*8;
        src = (kk < 512) ? Ab + (size_t)(row0+row)*512 + kk
                         : A2b + (size_t)(row0+row)*512 + (kk-512);
      } else {
        src = Ab + (size_t)(row0+row)*lda + k0 + sc*8;
      }
      gl_lds16(src, &As[row][sc*8]);
    }
    #pragma unroll
    for (int h=0; h<2; ++h) {
      int rowb = sr + h*64;
      gl_lds16(Bb + (size_t)(col0+rowb)*ldb + k0 + sc*8, &Bs[rowb][sc*8]);
    }
    __syncthreads();
    bf16x8 fa[4], fb[4];
    #pragma unroll
    for (int i=0;i<4;++i) fa[i] = *(const bf16x8*)&As[wr*64 + i*16 + lr][lk];
    #pragma unroll
    for (int j=0;j<4;++j) fb[j] = *(const bf16x8*)&Bs[wc*64 + j*16 + lr][lk];
    #pragma unroll
    for (int i=0;i<4;++i)
      #pragma unroll
      for (int j=0;j<4;++j)
        acc[i][j] = __builtin_amdgcn_mfma_f32_16x16x32_bf16(fa[i], fb[j], acc[i][j], 0,0,0);
    __syncthreads();
  }

  #pragma unroll
  for (int i=0;i<4;++i) {
    #pragma unroll
    for (int j=0;j<4;++j) {
      int col = col0 + wc*64 + j*16 + lr;
      if (col >= N) continue;
      int rowbase = row0 + wr*64 + i*16 + lq*4;
      f32x4 v4 = acc[i][j];
      if (EPI==11 && col >= 1024) {
        int c2 = col-1024;
        int b2 = rowbase >> 10;
        int l2 = rowbase & 1023;
        float bv = bias[col];
        u16x4 pk = { f2bf(v4[0]+bv), f2bf(v4[1]+bv), f2bf(v4[2]+bv), f2bf(v4[3]+bv) };
        *(u16x4*)(aux + (size_t)b2*DMODEL*SEQL + (size_t)c2*SEQL + l2) = pk;
        continue;
      }
      #pragma unroll
      for (int r=0;r<4;++r) {
        int row = rowbase + r;
        size_t idx = (size_t)row*ldc + col;
        float v = v4[r];
        if (EPI==1) Cf[idx] = v + bias[col];
        else if (EPI==3) Cb[idx] = f2bf(gelu_f(v + bias[col]));
        else if (EPI==5) Cf[idx] = v + bias[col] + p0[idx];
        else if (EPI==6) {
          float g = sigmoid_f(v + bias[col]);
          float m = p0[idx], at = p1[idx];
          Cf[idx] = p2[idx] + at + g*m + (1.f-g)*at;
        }
        else if (EPI==7) Cb[idx] = f2bf(v);
        else if (EPI==9) { Cf[idx] = v; aux[idx] = f2bf(v); }
        else if (EPI==11) {
          size_t i2 = (size_t)(col>>9)*4194304 + (size_t)row*512 + (col&511);
          Cb[i2] = f2bf(v + bias[col]);
        }
        else if (EPI==12) {
          if (col < 32) Cf[(size_t)row*32 + col] = v;
          else aux[(size_t)row*1024 + (col-32)] = f2bf(softplus_f(v + bias[col-32]));
        }
      }
    }
  }
}

// ---------------- fused attention: S=QK^T/8, softmax (+AW out), O=PV ------------
// grid (qt=64, bh=64), 256 thr (4 waves). q-tile 16 rows; wave w owns cols w*256..+256
__global__ __launch_bounds__(256) void attn_k(const u16* Qb, const u16* Kb,
                                              const u16* VTb, float* AW, u16* Hbb)
{
  __shared__ u16 Qs[16][72];
  __shared__ u16 Ps[16][1032];
  __shared__ float part[4][16][64];
  __shared__ float smax[4][16];
  __shared__ float ssum[4][16];

  const int tid = threadIdx.x;
  const int w = tid>>6, lane = tid&63;
  const int qt = blockIdx.x, bh = blockIdx.y;
  const int b = bh>>3, h = bh&7;
  const int q0 = qt*16;
  const int lr = lane&15, lg = lane>>4;

  // stage Q tile (16 x 64)
  {
    int r = tid>>4, c = (tid&15)*4;
    const u16* src = Qb + ((size_t)(b*1024 + q0 + r))*512 + h*64 + c;
    *(u16x4*)&Qs[r][c] = *(const u16x4*)src;
  }
  __syncthreads();

  // phase 1: S chunk [16 x 256] per wave
  f32x4 acc[16];
  #pragma unroll
  for (int j=0;j<16;++j) acc[j] = (f32x4){0.f,0.f,0.f,0.f};
  bf16x8 fa0 = *(const bf16x8*)&Qs[lr][lg*8];
  bf16x8 fa1 = *(const bf16x8*)&Qs[lr][32+lg*8];
  const u16* Kbase = Kb + ((size_t)(b*1024 + w*256))*512 + h*64;
  #pragma unroll
  for (int j=0;j<16;++j){
    const u16* krow = Kbase + (size_t)(j*16 + lr)*512 + lg*8;
    bf16x8 fb0 = *(const bf16x8*)krow;
    bf16x8 fb1 = *(const bf16x8*)(krow+32);
    acc[j] = __builtin_amdgcn_mfma_f32_16x16x32_bf16(fa0, fb0, acc[j], 0,0,0);
    acc[j] = __builtin_amdgcn_mfma_f32_16x16x32_bf16(fa1, fb1, acc[j], 0,0,0);
  }

  // phase 2: softmax stats (rows rw..rw+3 held by this lane)
  const int rw = lg*4;
  float m0=-1e30f,m1=-1e30f,m2=-1e30f,m3=-1e30f;
  #pragma unroll
  for (int j=0;j<16;++j){
    m0=fmaxf(m0,acc[j][0]); m1=fmaxf(m1,acc[j][1]);
    m2=fmaxf(m2,acc[j][2]); m3=fmaxf(m3,acc[j][3]);
  }
  #pragma unroll
  for (int o=1;o<16;o<<=1){
    m0=fmaxf(m0,__shfl_xor(m0,o)); m1=fmaxf(m1,__shfl_xor(m1,o));
    m2=fmaxf(m2,__shfl_xor(m2,o)); m3=fmaxf(m3,__shfl_xor(m3,o));
  }
  if (lr==0){ smax[w][rw]=m0; smax[w][rw+1]=m1; smax[w][rw+2]=m2; smax[w][rw+3]=m3; }
  __syncthreads();
  float M0 = fmaxf(fmaxf(smax[0][rw  ],smax[1][rw  ]),fmaxf(smax[2][rw  ],smax[3][rw  ]));
  float M1 = fmaxf(fmaxf(smax[0][rw+1],smax[1][rw+1]),fmaxf(smax[2][rw+1],smax[3][rw+1]));
  float M2 = fmaxf(fmaxf(smax[0][rw+2],smax[1][rw+2]),fmaxf(smax[2][rw+2],smax[3][rw+2]));
  float M3 = fmaxf(fmaxf(smax[0][rw+3],smax[1][rw+3]),fmaxf(smax[2][rw+3],smax[3][rw+3]));
  const float cs = 0.125f*LOG2E;
  float s0=0.f,s1=0.f,s2=0.f,s3=0.f;
  #pragma unroll
  for (int j=0;j<16;++j){
    acc[j][0]=exp2_fast((acc[j][0]-M0)*cs); s0+=acc[j][0];
    acc[j][1]=exp2_fast((acc[j][1]-M1)*cs); s1+=acc[j][1];
    acc[j][2]=exp2_fast((acc[j][2]-M2)*cs); s2+=acc[j][2];
    acc[j][3]=exp2_fast((acc[j][3]-M3)*cs); s3+=acc[j][3];
  }
  #pragma unroll
  for (int o=1;o<16;o<<=1){
    s0+=__shfl_xor(s0,o); s1+=__shfl_xor(s1,o);
    s2+=__shfl_xor(s2,o); s3+=__shfl_xor(s3,o);
  }
  if (lr==0){ ssum[w][rw]=s0; ssum[w][rw+1]=s1; ssum[w][rw+2]=s2; ssum[w][rw+3]=s3; }
  __syncthreads();
  float i0 = rcp_fast(ssum[0][rw  ]+ssum[1][rw  ]+ssum[2][rw  ]+ssum[3][rw  ]);
  float i1 = rcp_fast(ssum[0][rw+1]+ssum[1][rw+1]+ssum[2][rw+1]+ssum[3][rw+1]);
  float i2 = rcp_fast(ssum[0][rw+2]+ssum[1][rw+2]+ssum[2][rw+2]+ssum[3][rw+2]);
  float i3 = rcp_fast(ssum[0][rw+3]+ssum[1][rw+3]+ssum[2][rw+3]+ssum[3][rw+3]);

  // write attn_w (f32, d_out) and P (bf16, LDS)
  float* awr = AW + (size_t)bh*1048576 + (size_t)q0*1024 + (size_t)w*256;
  #pragma unroll
  for (int j=0;j<16;++j){
    int col = j*16 + lr;
    float v0=acc[j][0]*i0, v1=acc[j][1]*i1, v2=acc[j][2]*i2, v3=acc[j][3]*i3;
    awr[(size_t)(rw  )*1024 + col] = v0;
    awr[(size_t)(rw+1)*1024 + col] = v1;
    awr[(size_t)(rw+2)*1024 + col] = v2;
    awr[(size_t)(rw+3)*1024 + col] = v3;
    Ps[rw  ][w*256+col] = f2bf(v0);
    Ps[rw+1][w*256+col] = f2bf(v1);
    Ps[rw+2][w*256+col] = f2bf(v2);
    Ps[rw+3][w*256+col] = f2bf(v3);
  }
  __syncthreads();

  // phase 3: PV, k-chunk [w*256, w*256+256)
  f32x4 av[4];
  #pragma unroll
  for (int j2=0;j2<4;++j2) av[j2] = (f32x4){0.f,0.f,0.f,0.f};
  const u16* Vbase = VTb + (size_t)b*524288 + (size_t)(h*64)*1024 + w*256;
  #pragma unroll
  for (int ks=0; ks<8; ++ks){
    bf16x8 pa = *(const bf16x8*)&Ps[lr][w*256 + ks*32 + lg*8];
    #pragma unroll
    for (int j2=0;j2<4;++j2){
      bf16x8 fb = *(const bf16x8*)(Vbase + (size_t)(j2*16+lr)*1024 + ks*32 + lg*8);
      av[j2] = __builtin_amdgcn_mfma_f32_16x16x32_bf16(pa, fb, av[j2], 0,0,0);
    }
  }
  #pragma unroll
  for (int j2=0;j2<4;++j2){
    part[w][rw  ][j2*16+lr] = av[j2][0];
    part[w][rw+1][j2*16+lr] = av[j2][1];
    part[w][rw+2][j2*16+lr] = av[j2][2];
    part[w][rw+3][j2*16+lr] = av[j2][3];
  }
  __syncthreads();
  {
    int q = tid>>4, dd = (tid&15)*4;
    float4 o0 = *(float4*)&part[0][q][dd];
    float4 o1 = *(float4*)&part[1][q][dd];
    float4 o2 = *(float4*)&part[2][q][dd];
    float4 o3 = *(float4*)&part[3][q][dd];
    float ox = o0.x+o1.x+o2.x+o3.x;
    float oy = o0.y+o1.y+o2.y+o3.y;
    float oz = o0.z+o1.z+o2.z+o3.z;
    float ow = o0.w+o1.w+o2.w+o3.w;
    u16x4 ob = { f2bf(ox), f2bf(oy), f2bf(oz), f2bf(ow) };
    *(u16x4*)(Hbb + ((size_t)(b*1024+q0+q))*512 + h*64 + dd) = ob;
  }
}

// ---------------- causal depthwise conv (D_CONV=4) + SiLU, bf16 in/out ---------
__global__ __launch_bounds__(256) void conv_k(const u16* xrb, const float* cw,
                                              const float* cb, u16* xcb)
{
  int t = blockIdx.x*256 + threadIdx.x;
  int d = (t & 255)*4;
  int row = t >> 8;
  int l = row & (SEQL-1);
  const u16* xmb = xrb + (size_t)(row - l)*2048 + d;
  float wv[4][4];
  #pragma unroll
  for (int dd=0; dd<4; ++dd){
    float4 w = *(const float4*)(cw + (size_t)(d+dd)*4);
    wv[dd][0]=w.x; wv[dd][1]=w.y; wv[dd][2]=w.z; wv[dd][3]=w.w;
  }
  float4 acc = *(const float4*)(cb + d);
  #pragma unroll
  for (int k=0;k<4;++k){
    int ls = l + k - 3;
    if (ls >= 0) {
      u16x4 xv = *(const u16x4*)(xmb + (size_t)ls*2048);
      acc.x += wv[0][k]*bf2f(xv[0]);
      acc.y += wv[1][k]*bf2f(xv[1]);
      acc.z += wv[2][k]*bf2f(xv[2]);
      acc.w += wv[3][k]*bf2f(xv[3]);
    }
  }
  float sx = acc.x*rcp_fast(1.f+exp_fast(-acc.x));
  float sy = acc.y*rcp_fast(1.f+exp_fast(-acc.y));
  float sz = acc.z*rcp_fast(1.f+exp_fast(-acc.z));
  float sw = acc.w*rcp_fast(1.f+exp_fast(-acc.w));
  size_t off = (size_t)row*DINNER + d;
  u16x4 ob = { f2bf(sx), f2bf(sy), f2bf(sz), f2bf(sw) };
  *(u16x4*)(xcb + off) = ob;
}

// ---------------- selective scan, chunked two-pass -----------------------------
__global__ __launch_bounds__(256) void scan1_k(const u16* dtb, const u16* ub,
                                               const float* bc, const float* A_log,
                                               float* Pq)
{
  const int tid = threadIdx.x;
  const int d   = blockIdx.x*256 + tid;
  const int seg = blockIdx.y;
  const int b   = blockIdx.z;
  const int l0  = seg*SEG;

  __shared__ float BCs[SEG*32];
  {
    const float4* src = (const float4*)(bc + ((size_t)b*SEQL + l0)*32);
    float4* dst = (float4*)BCs;
    dst[tid]     = src[tid];
    dst[tid+256] = src[tid+256];
  }
  float As2[16];
  #pragma unroll
  for (int s=0;s<16;++s) As2[s] = -expf(A_log[s]) * LOG2E;
  __syncthreads();

  float h[16], P[16];
  #pragma unroll
  for (int s=0;s<16;++s){ h[s]=0.f; P[s]=1.f; }

  size_t base = ((size_t)b*SEQL + l0)*DINNER + d;
  const u16* pdt = dtb + base;
  const u16* pu  = ub  + base;

  u16 dpf[8], upf[8];
  #pragma unroll
  for (int j=0;j<8;++j){ dpf[j]=pdt[(size_t)j*DINNER]; upf[j]=pu[(size_t)j*DINNER]; }
  const u16* pdt_f = pdt + (size_t)8*DINNER;
  const u16* pu_f  = pu  + (size_t)8*DINNER;

  for (int l=0; l<SEG; l+=8) {
    bool pf = (l+8 < SEG);
    #pragma unroll
    for (int j=0;j<8;++j) {
      float dt = bf2f(dpf[j]), u = bf2f(upf[j]);
      if (pf) { dpf[j] = *pdt_f; upf[j] = *pu_f; }
      pdt_f += DINNER; pu_f += DINNER;
      float dtu = dt*u;
      const float* Bs = &BCs[(l+j)*32];
      #pragma unroll
      for (int s=0;s<16;++s) {
        float dA = exp2_fast(dt*As2[s]);
        P[s] *= dA;
        h[s] = fmaf(h[s], dA, dtu*Bs[s]);
      }
    }
  }
  float* out = Pq + (((size_t)b*NSEG + seg)*32)*1024 + d;
  #pragma unroll
  for (int s=0;s<16;++s) {
    out[(size_t)s*1024]      = P[s];
    out[(size_t)(16+s)*1024] = h[s];
  }
}

__global__ __launch_bounds__(256) void scan2_k(const u16* dtb, const u16* ub,
                                               const float* bc, const u16* xrb,
                                               const float* A_log, const float* Dp,
                                               const float* Pq, u16* yb)
{
  const int tid = threadIdx.x;
  const int d   = blockIdx.x*256 + tid;
  const int seg = blockIdx.y;
  const int b   = blockIdx.z;
  const int l0  = seg*SEG;

  __shared__ float BCs[SEG*32];
  {
    const float4* src = (const float4*)(bc + ((size_t)b*SEQL + l0)*32);
    float4* dst = (float4*)BCs;
    dst[tid]     = src[tid];
    dst[tid+256] = src[tid+256];
  }
  float As2[16];
  #pragma unroll
  for (int s=0;s<16;++s) As2[s] = -expf(A_log[s]) * LOG2E;
  float dcoef = Dp[d];
  __syncthreads();

  float h[16];
  #pragma unroll
  for (int s=0;s<16;++s) h[s]=0.f;

  const float* pp = Pq + ((size_t)b*NSEG)*32*1024 + d;
  for (int sg=0; sg<seg; ++sg) {
    const float* q = pp + (size_t)sg*32*1024;
    #pragma unroll
    for (int s=0;s<16;++s)
      h[s] = fmaf(h[s], q[(size_t)s*1024], q[(size_t)(16+s)*1024]);
  }

  size_t rbase = (size_t)b*SEQL + l0;
  const u16* pdt = dtb + rbase*DINNER + d;
  const u16* pu  = ub  + rbase*DINNER + d;
  const u16* pr  = xrb + rbase*2048 + 1024 + d;
  u16*       py  = yb  + rbase*DINNER + d;

  u16 dpf[8], upf[8], rpf[8];
  #pragma unroll
  for (int j=0;j<8;++j){
    dpf[j]=pdt[(size_t)j*DINNER]; upf[j]=pu[(size_t)j*DINNER]; rpf[j]=pr[(size_t)j*2048];
  }
  const u16* pdt_f = pdt + (size_t)8*DINNER;
  const u16* pu_f  = pu  + (size_t)8*DINNER;
  const u16* pr_f  = pr  + (size_t)8*2048;

  for (int l=0; l<SEG; l+=8) {
    bool pf = (l+8 < SEG);
    #pragma unroll
    for (int j=0;j<8;++j) {
      float dt = bf2f(dpf[j]), u = bf2f(upf[j]), rv = bf2f(rpf[j]);
      if (pf) { dpf[j] = *pdt_f; upf[j] = *pu_f; rpf[j] = *pr_f; }
      pdt_f += DINNER; pu_f += DINNER; pr_f += 2048;
      float dtu = dt*u;
      float acc = 0.f;
      const float* Bs = &BCs[(l+j)*32];
      #pragma unroll
      for (int s=0;s<16;++s) {
        float dA = exp2_fast(dt*As2[s]);
        h[s] = fmaf(h[s], dA, dtu*Bs[s]);
        acc  = fmaf(h[s], Bs[16+s], acc);
      }
      float y = fmaf(u, dcoef, acc);
      y *= rv * rcp_fast(1.f + exp2_fast(rv*(-LOG2E)));
      *py = f2bf(y);
      py += DINNER;
    }
  }
}

extern "C" void kernel_launch(void* const* d_in, const int* in_sizes, int n_in,
                              void* d_out, int out_size, void* d_ws, size_t ws_size,
                              hipStream_t stream)
{
  const float* x          = (const float*)d_in[0];
  const float* in_proj_w  = (const float*)d_in[1];
  const float* conv_w     = (const float*)d_in[2];
  const float* conv_b     = (const float*)d_in[3];
  const float* x_proj_w   = (const float*)d_in[4];
  const float* dt_proj_w  = (const float*)d_in[5];
  const float* dt_proj_b  = (const float*)d_in[6];
  const float* A_log      = (const float*)d_in[7];
  const float* Dvec       = (const float*)d_in[8];
  const float* out_proj_w = (const float*)d_in[9];
  const float* wq_w = (const float*)d_in[10]; const float* wq_b = (const float*)d_in[11];
  const float* wk_w = (const float*)d_in[12]; const float* wk_b = (const float*)d_in[13];
  const float* wv_w = (const float*)d_in[14]; const float* wv_b = (const float*)d_in[15];
  const float* wo_w = (const float*)d_in[16]; const float* wo_b = (const float*)d_in[17];
  const float* attn_ln_g = (const float*)d_in[18]; const float* attn_ln_b = (const float*)d_in[19];
  const float* ffn_w1 = (const float*)d_in[20]; const float* ffn_b1 = (const float*)d_in[21];
  const float* ffn_w2 = (const float*)d_in[22]; const float* ffn_b2 = (const float*)d_in[23];
  const float* norm1_g = (const float*)d_in[24]; const float* norm1_b = (const float*)d_in[25];
  const float* norm2_g = (const float*)d_in[26]; const float* norm2_b = (const float*)d_in[27];
  const float* norm3_g = (const float*)d_in[28]; const float* norm3_b = (const float*)d_in[29];
  const float* gate_w  = (const float*)d_in[30]; const float* gate_b  = (const float*)d_in[31];

  // ---- workspace layout ----
  float* ws  = (float*)d_ws;
  float* BC   = ws;                 // 262144 f32
  float* X1   = BC  + 262144;       // 4194304 f32 (x1 -> x3)
  float* XN2  = X1  + 4194304;      // 4194304 f32
  float* MB   = XN2 + 4194304;      // 4194304 f32
  float* WOUT = MB  + 4194304;      // 4194304 f32
  float* ATT  = WOUT+ 4194304;      // 4194304 f32
  float* Pq   = ATT + 4194304;      // 4194304 f32  [8][16][32][1024]
  u16* WT0 = (u16*)(Pq + 4194304);  // 6324224 u16 transposed weights
  u16* XRb = WT0 + 6324224;         // 16777216 u16 (xr); reused Q|K|VT|Hb; then FH
  u16* NB  = XRb + 16777216;        // 4194304 u16 (xn1b -> xn2b -> xn3b)
  u16* XCb = NB  + 4194304;         // 8388608 u16 (xc = u, bf16)
  u16* DTb = XCb + 8388608;         // 8388608 u16 (delta bf16)
  u16* Yb  = DTb + 8388608;         // 8388608 u16 (scan y bf16)
  float* QKVB = (float*)(Yb + 8388608); // 1536 f32

  u16* Qb   = XRb;
  u16* Kb   = XRb + 4194304;
  u16* VTb  = XRb + 8388608;
  u16* Hbb  = XRb + 12582912;
  u16* FHb  = XRb;
  u16* MBb  = XCb;
  u16* ATTb = XCb + 4194304;

  u16* inprojT = WT0;               // [2048,512]
  u16* xprojT  = inprojT + 1048576; // [32,1024]   (stacked with dtT -> 1056 rows)
  u16* dtT     = xprojT  + 32768;   // [1024,1024]
  u16* outT    = dtT     + 1048576; // [512,1024]
  u16* wqT     = outT    + 524288;  // [512,512]   (wq|wk|wv stacked -> 1536 rows)
  u16* wkT     = wqT     + 262144;
  u16* wvT     = wkT     + 262144;
  u16* woT     = wvT     + 262144;
  u16* ffn1T   = woT     + 262144;  // [2048,512]
  u16* ffn2T   = ffn1T   + 1048576; // [512,2048]
  u16* gateT   = ffn2T   + 1048576; // [512,1024]

  float* XOUT = (float*)d_out;
  float* AW   = (float*)d_out + 4194304;

  const float* nulf = nullptr;
  u16* nulh = nullptr;

  // 0) transpose + cvt weights; pack qkv bias
  WtArgs wa;
  wa.d[0]  = { in_proj_w, inprojT, 512, 2048, 0 };
  wa.d[1]  = { x_proj_w,  xprojT, 1024,   32, 256 };
  wa.d[2]  = { dt_proj_w, dtT,    1024, 1024, 272 };
  wa.d[3]  = { out_proj_w,outT,   1024,  512, 528 };
  wa.d[4]  = { wq_w,      wqT,     512,  512, 656 };
  wa.d[5]  = { wk_w,      wkT,     512,  512, 720 };
  wa.d[6]  = { wv_w,      wvT,     512,  512, 784 };
  wa.d[7]  = { wo_w,      woT,     512,  512, 848 };
  wa.d[8]  = { ffn_w1,    ffn1T,   512, 2048, 912 };
  wa.d[9]  = { ffn_w2,    ffn2T,  2048,  512, 1168 };
  wa.d[10] = { gate_w,    gateT,  1024,  512, 1424 };
  wt_k<<<1552, 256, 0, stream>>>(wa);
  pack3_k<<<6, 256, 0, stream>>>(wq_b, wk_b, wv_b, QKVB);

  // 1) xn1b = LN(x)
  ln_k<<<NROWS, 128, 0, stream>>>(x, nullptr, nullptr, norm1_g, norm1_b, nullptr, NB);
  // 2) xrb = xn1 @ in_proj (bf16)
  mm_k<7,0><<<dim3(16,64), 256, 0, stream>>>(NB,512, inprojT,512, XRb,2048,
        NROWS,2048,512, nulf,nulf,nulf,nulf,nulh,nulh);
  // 3) xc = silu(conv(xm)+cb) (bf16)
  conv_k<<<NROWS, 256, 0, stream>>>(XRb, conv_w, conv_b, XCb);
  // 4+5) BC (f32) | delta (bf16) fused: N=1056 over stacked [xprojT|dtT]
  mm_k<12,0><<<dim3(9,64), 256, 0, stream>>>(XCb,1024, xprojT,1024, BC,32,
        NROWS,1056,1024, dt_proj_b,nulf,nulf,nulf,nulh,DTb);
  // 6) chunked scan
  scan1_k<<<dim3(4,NSEG-1,8), 256, 0, stream>>>(DTb, XCb, BC, A_log, Pq);
  scan2_k<<<dim3(4,NSEG,8),   256, 0, stream>>>(DTb, XCb, BC, XRb, A_log, Dvec, Pq, Yb);
  // 7) mamba_out = y @ out_proj (f32 MB + bf16 MBb)
  mm_k<9,0><<<dim3(4,64), 256, 0, stream>>>(Yb,1024, outT,1024, MB,512,
        NROWS,512,1024, nulf,nulf,nulf,nulf,nulh,MBb);
  // 8) x1 = x + mamba_out ; xn2 = LN(x1)
  ln_k<<<NROWS, 128, 0, stream>>>(x, MB, X1, norm2_g, norm2_b, XN2, NB);
  // 9) QKV fused: N=1536 over stacked [wqT|wkT|wvT]
  mm_k<11,0><<<dim3(12,64), 256, 0, stream>>>(NB,512, wqT,512, Qb,512,
        NROWS,1536,512, QKVB,nulf,nulf,nulf,nulh,VTb);
  // 10-12) fused attention: AW (d_out) + Hbb
  attn_k<<<dim3(64,64), 256, 0, stream>>>(Qb, Kb, VTb, AW, Hbb);
  // 13) WOUT = Hb @ wo + b
  mm_k<1,0><<<dim3(4,64), 256, 0, stream>>>(Hbb,512, woT,512, WOUT,512,
        NROWS,512,512, wo_b,nulf,nulf,nulf,nulh,nulh);
  // 14) attn_out = LN(WOUT + xn2)
  ln_k<<<NROWS, 128, 0, stream>>>(WOUT, XN2, nullptr, attn_ln_g, attn_ln_b, ATT, ATTb);
  // 15) gate fusion -> X1 (x3 in place)
  mm_k<6,3><<<dim3(4,64), 256, 0, stream>>>(MBb,512, gateT,1024, X1,512,
        NROWS,512,1024, gate_b, MB, ATT, X1, ATTb, nulh);
  // 16) xn3b = LN(x3)
  ln_k<<<NROWS, 128, 0, stream>>>(X1, nullptr, nullptr, norm3_g, norm3_b, nullptr, NB);
  // 17) fh = gelu(xn3 @ ffn1 + b1) (bf16)
  mm_k<3,0><<<dim3(16,64), 256, 0, stream>>>(NB,512, ffn1T,512, FHb,2048,
        NROWS,2048,512, ffn_b1,nulf,nulf,nulf,nulh,nulh);
  // 18) out = x3 + fh @ ffn2 + b2 -> d_out
  mm_k<5,0><<<dim3(4,64), 256, 0, stream>>>(FHb,2048, ffn2T,2048, XOUT,512,
        NROWS,512,2048, ffn_b2, X1,nulf,nulf,nulh,nulh);
}

// Round 6
// 628.463 us; speedup vs baseline: 4.5399x; 1.0677x over previous
//
#include <hip/hip_runtime.h>

#define SEQL 1024
#define DMODEL 512
#define DINNER 1024
#define NROWS 8192
#define SEG 64
#define NSEG 16
#define LOG2E 1.4426950408889634f

typedef unsigned short u16;
typedef unsigned int u32;
using bf16x8 = __attribute__((ext_vector_type(8))) short;
using f32x4  = __attribute__((ext_vector_type(4))) float;
using u16x4  = __attribute__((ext_vector_type(4))) unsigned short;

__device__ __forceinline__ float rcp_fast(float x){ return __builtin_amdgcn_rcpf(x); }
__device__ __forceinline__ float exp_fast(float x){ return __expf(x); }
#if __has_builtin(__builtin_amdgcn_exp2f)
__device__ __forceinline__ float exp2_fast(float x){ return __builtin_amdgcn_exp2f(x); }
#else
__device__ __forceinline__ float exp2_fast(float x){ return __expf(x*0.6931471805599453f); }
#endif
__device__ __forceinline__ float sigmoid_f(float x){ return rcp_fast(1.f+exp_fast(-x)); }
__device__ __forceinline__ float softplus_f(float x){ return fmaxf(x,0.f)+__logf(1.f+exp_fast(-fabsf(x))); }
__device__ __forceinline__ float gelu_f(float x){
  float u2 = 1.5957691216057308f*(x+0.044715f*x*x*x);
  float t = 1.f - 2.f*rcp_fast(1.f+exp_fast(u2));
  return 0.5f*x*(1.f+t);
}
__device__ __forceinline__ u16 f2bf(float f){
  u32 u = __builtin_bit_cast(u32, f);
  return (u16)((u + 0x7FFFu + ((u>>16)&1u)) >> 16);
}
__device__ __forceinline__ float bf2f(u16 h){
  return __builtin_bit_cast(float, (u32)h << 16);
}

// async global -> LDS, 16B per lane (LDS dest must be linear in lane order)
typedef __attribute__((address_space(1))) const void g_void;
typedef __attribute__((address_space(3))) void l_void;
__device__ __forceinline__ void gl_lds16(const void* g, void* l){
  __builtin_amdgcn_global_load_lds((g_void*)g, (l_void*)l, 16, 0, 0);
}

// ---------------- weight transpose+cvt: [K,N] fp32 -> [N,K] bf16 ---------------
struct WtDesc { const float* src; u16* dst; int K; int N; int t0; };
struct WtArgs { WtDesc d[11]; };

__global__ __launch_bounds__(256) void wt_k(WtArgs a)
{
  __shared__ float t[64][65];
  int bid = blockIdx.x;
  int i = 0;
  #pragma unroll
  for (int j=1;j<11;++j) if (bid >= a.d[j].t0) i = j;
  const float* src = a.d[i].src; u16* dst = a.d[i].dst;
  int K = a.d[i].K, N = a.d[i].N;
  int ntN = (N+63)>>6;
  int loc = bid - a.d[i].t0;
  int k0 = (loc / ntN)*64, n0 = (loc % ntN)*64;
  int tr = threadIdx.x>>4, tc = threadIdx.x&15;
  #pragma unroll
  for (int p=0;p<4;++p) {
    int r = p*16 + tr; int c = tc*4;
    if (n0 + c < N) {
      float4 v = *(const float4*)(src + (size_t)(k0+r)*N + n0 + c);
      t[r][c]=v.x; t[r][c+1]=v.y; t[r][c+2]=v.z; t[r][c+3]=v.w;
    }
  }
  __syncthreads();
  #pragma unroll
  for (int p=0;p<4;++p) {
    int n = p*16 + tr; int k = tc*4;
    if (n0 + n < N) {
      u16x4 o = { f2bf(t[k][n]), f2bf(t[k+1][n]), f2bf(t[k+2][n]), f2bf(t[k+3][n]) };
      *(u16x4*)(dst + (size_t)(n0+n)*K + k0 + k) = o;
    }
  }
}

// ---------------- bias concat for QKV -----------------------------------------
__global__ __launch_bounds__(256) void pack3_k(const float* a, const float* b,
                                               const float* c, float* o)
{
  int t = blockIdx.x*256 + threadIdx.x;
  if (t < 512) o[t] = a[t];
  else if (t < 1024) o[t] = b[t-512];
  else if (t < 1536) o[t] = c[t-1024];
}

// ---------------- LayerNorm (D=512), optional add-in, resid-out, f32/bf16 outs --
__global__ __launch_bounds__(128) void ln_k(const float* a, const float* b, float* resid,
                                            const float* g, const float* beta,
                                            float* outf, u16* outb)
{
  int row = blockIdx.x;
  int t = threadIdx.x;
  size_t off = (size_t)row*DMODEL + t*4;
  float4 v = *(const float4*)(a + off);
  if (b) {
    float4 w = *(const float4*)(b + off);
    v.x += w.x; v.y += w.y; v.z += w.z; v.w += w.w;
  }
  if (resid) *(float4*)(resid + off) = v;
  float s = v.x+v.y+v.z+v.w;
  float q = v.x*v.x+v.y*v.y+v.z*v.z+v.w*v.w;
  #pragma unroll
  for (int o=1;o<64;o<<=1){ s += __shfl_xor(s,o); q += __shfl_xor(q,o); }
  __shared__ float ss[2], qq[2];
  int w = t>>6;
  if ((t&63)==0){ ss[w]=s; qq[w]=q; }
  __syncthreads();
  s = ss[0]+ss[1]; q = qq[0]+qq[1];
  float mean = s*(1.f/512.f);
  float var  = q*(1.f/512.f) - mean*mean;
  float rstd = rsqrtf(var + 1e-5f);
  int c = t*4;
  float4 gg = *(const float4*)(g+c);
  float4 bb = *(const float4*)(beta+c);
  float4 o4;
  o4.x = (v.x-mean)*rstd*gg.x + bb.x;
  o4.y = (v.y-mean)*rstd*gg.y + bb.y;
  o4.z = (v.z-mean)*rstd*gg.z + bb.z;
  o4.w = (v.w-mean)*rstd*gg.w + bb.w;
  if (outf) *(float4*)(outf + off) = o4;
  if (outb) {
    u16x4 ob = { f2bf(o4.x), f2bf(o4.y), f2bf(o4.z), f2bf(o4.w) };
    *(u16x4*)(outb + off) = ob;
  }
}

// ---------------- bf16 MFMA GEMM, 128xTN tile, BK=32, global_load_lds staging ---
// EPI: 1 f32+bias, 3 gelu(x+bias) bf16, 5 x+bias+p0 f32, 6 gate fusion f32,
//      7 bf16, 9 f32 + aux bf16,
//      11 QKV fused (cols 0-1023 -> Q/K bf16 + bias; 1024-1535 -> V transposed to aux),
//      12 BC|delta fused (cols 0-31 -> Cf raw f32; 32-1055 -> softplus+bias -> bf16 aux)
// BMODE: 0 plain, 3 stitched A|A2 (K=1024)
// TN: 128 (wave sub-tile 64x64) or 64 (wave sub-tile 64x32, for N=512 GEMMs -> 512 blocks)
template<int EPI, int BMODE, int TN>
__global__ __launch_bounds__(256) void mm_k(
    const u16* Ab, int lda, const u16* Bb, int ldb,
    void* Cv, int ldc, int M, int N, int K,
    const float* bias, const float* p0, const float* p1, const float* p2,
    const u16* A2b, u16* aux)
{
  constexpr int NJ = TN/32;          // j-fragments per wave
  __shared__ u16 As[128][32];
  __shared__ u16 Bs[TN][32];
  const int tid = threadIdx.x;
  const int bx = blockIdx.x, by = blockIdx.y;
  float* Cf = (float*)Cv;
  u16* Cb = (u16*)Cv;
  const int row0 = by*128, col0 = bx*TN;
  const int sr = tid>>2, sc = tid&3;
  const int wv = tid>>6, lane = tid&63;
  const int wr = wv>>1, wc = wv&1;
  const int lr = lane&15, lk = (lane>>4)*8;
  const int lq = lane>>4;

  f32x4 acc[4][NJ];
  #pragma unroll
  for (int i=0;i<4;++i)
    #pragma unroll
    for (int j=0;j<NJ;++j)
      acc[i][j] = (f32x4){0.f,0.f,0.f,0.f};

  for (int k0=0; k0<K; k0+=32) {
    #pragma unroll
    for (int h=0; h<2; ++h) {
      int row = sr + h*64;
      const u16* src;
      if (BMODE==3) {
        int kk = k0 + sc*8;
        src = (kk < 512) ? Ab + (size_t)(row0+row)*512 + kk
                         : A2b + (size_t)(row0+row)*512 + (kk-512);
      } else {
        src = Ab + (size_t)(row0+row)*lda + k0 + sc*8;
      }
      gl_lds16(src, &As[row][sc*8]);
    }
    #pragma unroll
    for (int h=0; h<TN/64; ++h) {
      int rowb = sr + h*64;
      gl_lds16(Bb + (size_t)(col0+rowb)*ldb + k0 + sc*8, &Bs[rowb][sc*8]);
    }
    __syncthreads();
    bf16x8 fa[4], fb[NJ];
    #pragma unroll
    for (int i=0;i<4;++i) fa[i] = *(const bf16x8*)&As[wr*64 + i*16 + lr][lk];
    #pragma unroll
    for (int j=0;j<NJ;++j) fb[j] = *(const bf16x8*)&Bs[wc*(TN/2) + j*16 + lr][lk];
    #pragma unroll
    for (int i=0;i<4;++i)
      #pragma unroll
      for (int j=0;j<NJ;++j)
        acc[i][j] = __builtin_amdgcn_mfma_f32_16x16x32_bf16(fa[i], fb[j], acc[i][j], 0,0,0);
    __syncthreads();
  }

  #pragma unroll
  for (int i=0;i<4;++i) {
    #pragma unroll
    for (int j=0;j<NJ;++j) {
      int col = col0 + wc*(TN/2) + j*16 + lr;
      if (col >= N) continue;
      int rowbase = row0 + wr*64 + i*16 + lq*4;
      f32x4 v4 = acc[i][j];
      if (EPI==11 && col >= 1024) {
        int c2 = col-1024;
        int b2 = rowbase >> 10;
        int l2 = rowbase & 1023;
        float bv = bias[col];
        u16x4 pk = { f2bf(v4[0]+bv), f2bf(v4[1]+bv), f2bf(v4[2]+bv), f2bf(v4[3]+bv) };
        *(u16x4*)(aux + (size_t)b2*DMODEL*SEQL + (size_t)c2*SEQL + l2) = pk;
        continue;
      }
      #pragma unroll
      for (int r=0;r<4;++r) {
        int row = rowbase + r;
        size_t idx = (size_t)row*ldc + col;
        float v = v4[r];
        if (EPI==1) Cf[idx] = v + bias[col];
        else if (EPI==3) Cb[idx] = f2bf(gelu_f(v + bias[col]));
        else if (EPI==5) Cf[idx] = v + bias[col] + p0[idx];
        else if (EPI==6) {
          float g = sigmoid_f(v + bias[col]);
          float m = p0[idx], at = p1[idx];
          Cf[idx] = p2[idx] + at + g*m + (1.f-g)*at;
        }
        else if (EPI==7) Cb[idx] = f2bf(v);
        else if (EPI==9) { Cf[idx] = v; aux[idx] = f2bf(v); }
        else if (EPI==11) {
          size_t i2 = (size_t)(col>>9)*4194304 + (size_t)row*512 + (col&511);
          Cb[i2] = f2bf(v + bias[col]);
        }
        else if (EPI==12) {
          if (col < 32) Cf[(size_t)row*32 + col] = v;
          else aux[(size_t)row*1024 + (col-32)] = f2bf(softplus_f(v + bias[col-32]));
        }
      }
    }
  }
}

// ---------------- fused attention: S=QK^T/8, softmax (+AW out), O=PV ------------
// grid (qt=64, bh=64), 256 thr (4 waves). q-tile 16 rows; wave w owns cols w*256..+256
__global__ __launch_bounds__(256) void attn_k(const u16* Qb, const u16* Kb,
                                              const u16* VTb, float* AW, u16* Hbb)
{
  __shared__ u16 Qs[16][72];
  __shared__ u16 Ps[16][1032];
  __shared__ float part[4][16][64];
  __shared__ float smax[4][16];
  __shared__ float ssum[4][16];

  const int tid = threadIdx.x;
  const int w = tid>>6, lane = tid&63;
  const int qt = blockIdx.x, bh = blockIdx.y;
  const int b = bh>>3, h = bh&7;
  const int q0 = qt*16;
  const int lr = lane&15, lg = lane>>4;

  {
    int r = tid>>4, c = (tid&15)*4;
    const u16* src = Qb + ((size_t)(b*1024 + q0 + r))*512 + h*64 + c;
    *(u16x4*)&Qs[r][c] = *(const u16x4*)src;
  }
  __syncthreads();

  f32x4 acc[16];
  #pragma unroll
  for (int j=0;j<16;++j) acc[j] = (f32x4){0.f,0.f,0.f,0.f};
  bf16x8 fa0 = *(const bf16x8*)&Qs[lr][lg*8];
  bf16x8 fa1 = *(const bf16x8*)&Qs[lr][32+lg*8];
  const u16* Kbase = Kb + ((size_t)(b*1024 + w*256))*512 + h*64;
  #pragma unroll
  for (int j=0;j<16;++j){
    const u16* krow = Kbase + (size_t)(j*16 + lr)*512 + lg*8;
    bf16x8 fb0 = *(const bf16x8*)krow;
    bf16x8 fb1 = *(const bf16x8*)(krow+32);
    acc[j] = __builtin_amdgcn_mfma_f32_16x16x32_bf16(fa0, fb0, acc[j], 0,0,0);
    acc[j] = __builtin_amdgcn_mfma_f32_16x16x32_bf16(fa1, fb1, acc[j], 0,0,0);
  }

  const int rw = lg*4;
  float m0=-1e30f,m1=-1e30f,m2=-1e30f,m3=-1e30f;
  #pragma unroll
  for (int j=0;j<16;++j){
    m0=fmaxf(m0,acc[j][0]); m1=fmaxf(m1,acc[j][1]);
    m2=fmaxf(m2,acc[j][2]); m3=fmaxf(m3,acc[j][3]);
  }
  #pragma unroll
  for (int o=1;o<16;o<<=1){
    m0=fmaxf(m0,__shfl_xor(m0,o)); m1=fmaxf(m1,__shfl_xor(m1,o));
    m2=fmaxf(m2,__shfl_xor(m2,o)); m3=fmaxf(m3,__shfl_xor(m3,o));
  }
  if (lr==0){ smax[w][rw]=m0; smax[w][rw+1]=m1; smax[w][rw+2]=m2; smax[w][rw+3]=m3; }
  __syncthreads();
  float M0 = fmaxf(fmaxf(smax[0][rw  ],smax[1][rw  ]),fmaxf(smax[2][rw  ],smax[3][rw  ]));
  float M1 = fmaxf(fmaxf(smax[0][rw+1],smax[1][rw+1]),fmaxf(smax[2][rw+1],smax[3][rw+1]));
  float M2 = fmaxf(fmaxf(smax[0][rw+2],smax[1][rw+2]),fmaxf(smax[2][rw+2],smax[3][rw+2]));
  float M3 = fmaxf(fmaxf(smax[0][rw+3],smax[1][rw+3]),fmaxf(smax[2][rw+3],smax[3][rw+3]));
  const float cs = 0.125f*LOG2E;
  float s0=0.f,s1=0.f,s2=0.f,s3=0.f;
  #pragma unroll
  for (int j=0;j<16;++j){
    acc[j][0]=exp2_fast((acc[j][0]-M0)*cs); s0+=acc[j][0];
    acc[j][1]=exp2_fast((acc[j][1]-M1)*cs); s1+=acc[j][1];
    acc[j][2]=exp2_fast((acc[j][2]-M2)*cs); s2+=acc[j][2];
    acc[j][3]=exp2_fast((acc[j][3]-M3)*cs); s3+=acc[j][3];
  }
  #pragma unroll
  for (int o=1;o<16;o<<=1){
    s0+=__shfl_xor(s0,o); s1+=__shfl_xor(s1,o);
    s2+=__shfl_xor(s2,o); s3+=__shfl_xor(s3,o);
  }
  if (lr==0){ ssum[w][rw]=s0; ssum[w][rw+1]=s1; ssum[w][rw+2]=s2; ssum[w][rw+3]=s3; }
  __syncthreads();
  float i0 = rcp_fast(ssum[0][rw  ]+ssum[1][rw  ]+ssum[2][rw  ]+ssum[3][rw  ]);
  float i1 = rcp_fast(ssum[0][rw+1]+ssum[1][rw+1]+ssum[2][rw+1]+ssum[3][rw+1]);
  float i2 = rcp_fast(ssum[0][rw+2]+ssum[1][rw+2]+ssum[2][rw+2]+ssum[3][rw+2]);
  float i3 = rcp_fast(ssum[0][rw+3]+ssum[1][rw+3]+ssum[2][rw+3]+ssum[3][rw+3]);

  float* awr = AW + (size_t)bh*1048576 + (size_t)q0*1024 + (size_t)w*256;
  #pragma unroll
  for (int j=0;j<16;++j){
    int col = j*16 + lr;
    float v0=acc[j][0]*i0, v1=acc[j][1]*i1, v2=acc[j][2]*i2, v3=acc[j][3]*i3;
    awr[(size_t)(rw  )*1024 + col] = v0;
    awr[(size_t)(rw+1)*1024 + col] = v1;
    awr[(size_t)(rw+2)*1024 + col] = v2;
    awr[(size_t)(rw+3)*1024 + col] = v3;
    Ps[rw  ][w*256+col] = f2bf(v0);
    Ps[rw+1][w*256+col] = f2bf(v1);
    Ps[rw+2][w*256+col] = f2bf(v2);
    Ps[rw+3][w*256+col] = f2bf(v3);
  }
  __syncthreads();

  f32x4 av[4];
  #pragma unroll
  for (int j2=0;j2<4;++j2) av[j2] = (f32x4){0.f,0.f,0.f,0.f};
  const u16* Vbase = VTb + (size_t)b*524288 + (size_t)(h*64)*1024 + w*256;
  #pragma unroll
  for (int ks=0; ks<8; ++ks){
    bf16x8 pa = *(const bf16x8*)&Ps[lr][w*256 + ks*32 + lg*8];
    #pragma unroll
    for (int j2=0;j2<4;++j2){
      bf16x8 fb = *(const bf16x8*)(Vbase + (size_t)(j2*16+lr)*1024 + ks*32 + lg*8);
      av[j2] = __builtin_amdgcn_mfma_f32_16x16x32_bf16(pa, fb, av[j2], 0,0,0);
    }
  }
  #pragma unroll
  for (int j2=0;j2<4;++j2){
    part[w][rw  ][j2*16+lr] = av[j2][0];
    part[w][rw+1][j2*16+lr] = av[j2][1];
    part[w][rw+2][j2*16+lr] = av[j2][2];
    part[w][rw+3][j2*16+lr] = av[j2][3];
  }
  __syncthreads();
  {
    int q = tid>>4, dd = (tid&15)*4;
    float4 o0 = *(float4*)&part[0][q][dd];
    float4 o1 = *(float4*)&part[1][q][dd];
    float4 o2 = *(float4*)&part[2][q][dd];
    float4 o3 = *(float4*)&part[3][q][dd];
    float ox = o0.x+o1.x+o2.x+o3.x;
    float oy = o0.y+o1.y+o2.y+o3.y;
    float oz = o0.z+o1.z+o2.z+o3.z;
    float ow = o0.w+o1.w+o2.w+o3.w;
    u16x4 ob = { f2bf(ox), f2bf(oy), f2bf(oz), f2bf(ow) };
    *(u16x4*)(Hbb + ((size_t)(b*1024+q0+q))*512 + h*64 + dd) = ob;
  }
}

// ---------------- causal depthwise conv (D_CONV=4) + SiLU, bf16 in/out ---------
__global__ __launch_bounds__(256) void conv_k(const u16* xrb, const float* cw,
                                              const float* cb, u16* xcb)
{
  int t = blockIdx.x*256 + threadIdx.x;
  int d = (t & 255)*4;
  int row = t >> 8;
  int l = row & (SEQL-1);
  const u16* xmb = xrb + (size_t)(row - l)*2048 + d;
  float wv[4][4];
  #pragma unroll
  for (int dd=0; dd<4; ++dd){
    float4 w = *(const float4*)(cw + (size_t)(d+dd)*4);
    wv[dd][0]=w.x; wv[dd][1]=w.y; wv[dd][2]=w.z; wv[dd][3]=w.w;
  }
  float4 acc = *(const float4*)(cb + d);
  #pragma unroll
  for (int k=0;k<4;++k){
    int ls = l + k - 3;
    if (ls >= 0) {
      u16x4 xv = *(const u16x4*)(xmb + (size_t)ls*2048);
      acc.x += wv[0][k]*bf2f(xv[0]);
      acc.y += wv[1][k]*bf2f(xv[1]);
      acc.z += wv[2][k]*bf2f(xv[2]);
      acc.w += wv[3][k]*bf2f(xv[3]);
    }
  }
  float sx = acc.x*rcp_fast(1.f+exp_fast(-acc.x));
  float sy = acc.y*rcp_fast(1.f+exp_fast(-acc.y));
  float sz = acc.z*rcp_fast(1.f+exp_fast(-acc.z));
  float sw = acc.w*rcp_fast(1.f+exp_fast(-acc.w));
  size_t off = (size_t)row*DINNER + d;
  u16x4 ob = { f2bf(sx), f2bf(sy), f2bf(sz), f2bf(sw) };
  *(u16x4*)(xcb + off) = ob;
}

// ---------------- selective scan, chunked two-pass -----------------------------
__global__ __launch_bounds__(256) void scan1_k(const u16* dtb, const u16* ub,
                                               const float* bc, const float* A_log,
                                               float* Pq)
{
  const int tid = threadIdx.x;
  const int d   = blockIdx.x*256 + tid;
  const int seg = blockIdx.y;
  const int b   = blockIdx.z;
  const int l0  = seg*SEG;

  __shared__ float BCs[SEG*32];
  {
    const float4* src = (const float4*)(bc + ((size_t)b*SEQL + l0)*32);
    float4* dst = (float4*)BCs;
    dst[tid]     = src[tid];
    dst[tid+256] = src[tid+256];
  }
  float As2[16];
  #pragma unroll
  for (int s=0;s<16;++s) As2[s] = -expf(A_log[s]) * LOG2E;
  __syncthreads();

  float h[16], P[16];
  #pragma unroll
  for (int s=0;s<16;++s){ h[s]=0.f; P[s]=1.f; }

  size_t base = ((size_t)b*SEQL + l0)*DINNER + d;
  const u16* pdt = dtb + base;
  const u16* pu  = ub  + base;

  u16 dpf[8], upf[8];
  #pragma unroll
  for (int j=0;j<8;++j){ dpf[j]=pdt[(size_t)j*DINNER]; upf[j]=pu[(size_t)j*DINNER]; }
  const u16* pdt_f = pdt + (size_t)8*DINNER;
  const u16* pu_f  = pu  + (size_t)8*DINNER;

  for (int l=0; l<SEG; l+=8) {
    bool pf = (l+8 < SEG);
    #pragma unroll
    for (int j=0;j<8;++j) {
      float dt = bf2f(dpf[j]), u = bf2f(upf[j]);
      if (pf) { dpf[j] = *pdt_f; upf[j] = *pu_f; }
      pdt_f += DINNER; pu_f += DINNER;
      float dtu = dt*u;
      const float* Bs = &BCs[(l+j)*32];
      #pragma unroll
      for (int s=0;s<16;++s) {
        float dA = exp2_fast(dt*As2[s]);
        P[s] *= dA;
        h[s] = fmaf(h[s], dA, dtu*Bs[s]);
      }
    }
  }
  float* out = Pq + (((size_t)b*NSEG + seg)*32)*1024 + d;
  #pragma unroll
  for (int s=0;s<16;++s) {
    out[(size_t)s*1024]      = P[s];
    out[(size_t)(16+s)*1024] = h[s];
  }
}

__global__ __launch_bounds__(256) void scan2_k(const u16* dtb, const u16* ub,
                                               const float* bc, const u16* xrb,
                                               const float* A_log, const float* Dp,
                                               const float* Pq, u16* yb)
{
  const int tid = threadIdx.x;
  const int d   = blockIdx.x*256 + tid;
  const int seg = blockIdx.y;
  const int b   = blockIdx.z;
  const int l0  = seg*SEG;

  __shared__ float BCs[SEG*32];
  {
    const float4* src = (const float4*)(bc + ((size_t)b*SEQL + l0)*32);
    float4* dst = (float4*)BCs;
    dst[tid]     = src[tid];
    dst[tid+256] = src[tid+256];
  }
  float As2[16];
  #pragma unroll
  for (int s=0;s<16;++s) As2[s] = -expf(A_log[s]) * LOG2E;
  float dcoef = Dp[d];
  __syncthreads();

  float h[16];
  #pragma unroll
  for (int s=0;s<16;++s) h[s]=0.f;

  const float* pp = Pq + ((size_t)b*NSEG)*32*1024 + d;
  for (int sg=0; sg<seg; ++sg) {
    const float* q = pp + (size_t)sg*32*1024;
    #pragma unroll
    for (int s=0;s<16;++s)
      h[s] = fmaf(h[s], q[(size_t)s*1024], q[(size_t)(16+s)*1024]);
  }

  size_t rbase = (size_t)b*SEQL + l0;
  const u16* pdt = dtb + rbase*DINNER + d;
  const u16* pu  = ub  + rbase*DINNER + d;
  const u16* pr  = xrb + rbase*2048 + 1024 + d;
  u16*       py  = yb  + rbase*DINNER + d;

  u16 dpf[8], upf[8], rpf[8];
  #pragma unroll
  for (int j=0;j<8;++j){
    dpf[j]=pdt[(size_t)j*DINNER]; upf[j]=pu[(size_t)j*DINNER]; rpf[j]=pr[(size_t)j*2048];
  }
  const u16* pdt_f = pdt + (size_t)8*DINNER;
  const u16* pu_f  = pu  + (size_t)8*DINNER;
  const u16* pr_f  = pr  + (size_t)8*2048;

  for (int l=0; l<SEG; l+=8) {
    bool pf = (l+8 < SEG);
    #pragma unroll
    for (int j=0;j<8;++j) {
      float dt = bf2f(dpf[j]), u = bf2f(upf[j]), rv = bf2f(rpf[j]);
      if (pf) { dpf[j] = *pdt_f; upf[j] = *pu_f; rpf[j] = *pr_f; }
      pdt_f += DINNER; pu_f += DINNER; pr_f += 2048;
      float dtu = dt*u;
      float acc = 0.f;
      const float* Bs = &BCs[(l+j)*32];
      #pragma unroll
      for (int s=0;s<16;++s) {
        float dA = exp2_fast(dt*As2[s]);
        h[s] = fmaf(h[s], dA, dtu*Bs[s]);
        acc  = fmaf(h[s], Bs[16+s], acc);
      }
      float y = fmaf(u, dcoef, acc);
      y *= rv * rcp_fast(1.f + exp2_fast(rv*(-LOG2E)));
      *py = f2bf(y);
      py += DINNER;
    }
  }
}

extern "C" void kernel_launch(void* const* d_in, const int* in_sizes, int n_in,
                              void* d_out, int out_size, void* d_ws, size_t ws_size,
                              hipStream_t stream)
{
  const float* x          = (const float*)d_in[0];
  const float* in_proj_w  = (const float*)d_in[1];
  const float* conv_w     = (const float*)d_in[2];
  const float* conv_b     = (const float*)d_in[3];
  const float* x_proj_w   = (const float*)d_in[4];
  const float* dt_proj_w  = (const float*)d_in[5];
  const float* dt_proj_b  = (const float*)d_in[6];
  const float* A_log      = (const float*)d_in[7];
  const float* Dvec       = (const float*)d_in[8];
  const float* out_proj_w = (const float*)d_in[9];
  const float* wq_w = (const float*)d_in[10]; const float* wq_b = (const float*)d_in[11];
  const float* wk_w = (const float*)d_in[12]; const float* wk_b = (const float*)d_in[13];
  const float* wv_w = (const float*)d_in[14]; const float* wv_b = (const float*)d_in[15];
  const float* wo_w = (const float*)d_in[16]; const float* wo_b = (const float*)d_in[17];
  const float* attn_ln_g = (const float*)d_in[18]; const float* attn_ln_b = (const float*)d_in[19];
  const float* ffn_w1 = (const float*)d_in[20]; const float* ffn_b1 = (const float*)d_in[21];
  const float* ffn_w2 = (const float*)d_in[22]; const float* ffn_b2 = (const float*)d_in[23];
  const float* norm1_g = (const float*)d_in[24]; const float* norm1_b = (const float*)d_in[25];
  const float* norm2_g = (const float*)d_in[26]; const float* norm2_b = (const float*)d_in[27];
  const float* norm3_g = (const float*)d_in[28]; const float* norm3_b = (const float*)d_in[29];
  const float* gate_w  = (const float*)d_in[30]; const float* gate_b  = (const float*)d_in[31];

  // ---- workspace layout ----
  float* ws  = (float*)d_ws;
  float* BC   = ws;                 // 262144 f32
  float* X1   = BC  + 262144;       // 4194304 f32 (x1 -> x3)
  float* XN2  = X1  + 4194304;      // 4194304 f32
  float* MB   = XN2 + 4194304;      // 4194304 f32
  float* WOUT = MB  + 4194304;      // 4194304 f32
  float* ATT  = WOUT+ 4194304;      // 4194304 f32
  float* Pq   = ATT + 4194304;      // 4194304 f32  [8][16][32][1024]
  u16* WT0 = (u16*)(Pq + 4194304);  // 6324224 u16 transposed weights
  u16* XRb = WT0 + 6324224;         // 16777216 u16 (xr); reused Q|K|VT|Hb; then FH
  u16* NB  = XRb + 16777216;        // 4194304 u16 (xn1b -> xn2b -> xn3b)
  u16* XCb = NB  + 4194304;         // 8388608 u16 (xc = u, bf16)
  u16* DTb = XCb + 8388608;         // 8388608 u16 (delta bf16)
  u16* Yb  = DTb + 8388608;         // 8388608 u16 (scan y bf16)
  float* QKVB = (float*)(Yb + 8388608); // 1536 f32

  u16* Qb   = XRb;
  u16* Kb   = XRb + 4194304;
  u16* VTb  = XRb + 8388608;
  u16* Hbb  = XRb + 12582912;
  u16* FHb  = XRb;
  u16* MBb  = XCb;
  u16* ATTb = XCb + 4194304;

  u16* inprojT = WT0;               // [2048,512]
  u16* xprojT  = inprojT + 1048576; // [32,1024]   (stacked with dtT -> 1056 rows)
  u16* dtT     = xprojT  + 32768;   // [1024,1024]
  u16* outT    = dtT     + 1048576; // [512,1024]
  u16* wqT     = outT    + 524288;  // [512,512]   (wq|wk|wv stacked -> 1536 rows)
  u16* wkT     = wqT     + 262144;
  u16* wvT     = wkT     + 262144;
  u16* woT     = wvT     + 262144;
  u16* ffn1T   = woT     + 262144;  // [2048,512]
  u16* ffn2T   = ffn1T   + 1048576; // [512,2048]
  u16* gateT   = ffn2T   + 1048576; // [512,1024]

  float* XOUT = (float*)d_out;
  float* AW   = (float*)d_out + 4194304;

  const float* nulf = nullptr;
  u16* nulh = nullptr;

  // 0) transpose + cvt weights; pack qkv bias
  WtArgs wa;
  wa.d[0]  = { in_proj_w, inprojT, 512, 2048, 0 };
  wa.d[1]  = { x_proj_w,  xprojT, 1024,   32, 256 };
  wa.d[2]  = { dt_proj_w, dtT,    1024, 1024, 272 };
  wa.d[3]  = { out_proj_w,outT,   1024,  512, 528 };
  wa.d[4]  = { wq_w,      wqT,     512,  512, 656 };
  wa.d[5]  = { wk_w,      wkT,     512,  512, 720 };
  wa.d[6]  = { wv_w,      wvT,     512,  512, 784 };
  wa.d[7]  = { wo_w,      woT,     512,  512, 848 };
  wa.d[8]  = { ffn_w1,    ffn1T,   512, 2048, 912 };
  wa.d[9]  = { ffn_w2,    ffn2T,  2048,  512, 1168 };
  wa.d[10] = { gate_w,    gateT,  1024,  512, 1424 };
  wt_k<<<1552, 256, 0, stream>>>(wa);
  pack3_k<<<6, 256, 0, stream>>>(wq_b, wk_b, wv_b, QKVB);

  // 1) xn1b = LN(x)
  ln_k<<<NROWS, 128, 0, stream>>>(x, nullptr, nullptr, norm1_g, norm1_b, nullptr, NB);
  // 2) xrb = xn1 @ in_proj (bf16)
  mm_k<7,0,128><<<dim3(16,64), 256, 0, stream>>>(NB,512, inprojT,512, XRb,2048,
        NROWS,2048,512, nulf,nulf,nulf,nulf,nulh,nulh);
  // 3) xc = silu(conv(xm)+cb) (bf16)
  conv_k<<<NROWS, 256, 0, stream>>>(XRb, conv_w, conv_b, XCb);
  // 4+5) BC (f32) | delta (bf16) fused: N=1056 over stacked [xprojT|dtT]
  mm_k<12,0,128><<<dim3(9,64), 256, 0, stream>>>(XCb,1024, xprojT,1024, BC,32,
        NROWS,1056,1024, dt_proj_b,nulf,nulf,nulf,nulh,DTb);
  // 6) chunked scan
  scan1_k<<<dim3(4,NSEG-1,8), 256, 0, stream>>>(DTb, XCb, BC, A_log, Pq);
  scan2_k<<<dim3(4,NSEG,8),   256, 0, stream>>>(DTb, XCb, BC, XRb, A_log, Dvec, Pq, Yb);
  // 7) mamba_out = y @ out_proj (f32 MB + bf16 MBb)  [TN=64 -> 512 blocks]
  mm_k<9,0,64><<<dim3(8,64), 256, 0, stream>>>(Yb,1024, outT,1024, MB,512,
        NROWS,512,1024, nulf,nulf,nulf,nulf,nulh,MBb);
  // 8) x1 = x + mamba_out ; xn2 = LN(x1)
  ln_k<<<NROWS, 128, 0, stream>>>(x, MB, X1, norm2_g, norm2_b, XN2, NB);
  // 9) QKV fused: N=1536 over stacked [wqT|wkT|wvT]
  mm_k<11,0,128><<<dim3(12,64), 256, 0, stream>>>(NB,512, wqT,512, Qb,512,
        NROWS,1536,512, QKVB,nulf,nulf,nulf,nulh,VTb);
  // 10-12) fused attention: AW (d_out) + Hbb
  attn_k<<<dim3(64,64), 256, 0, stream>>>(Qb, Kb, VTb, AW, Hbb);
  // 13) WOUT = Hb @ wo + b  [TN=64]
  mm_k<1,0,64><<<dim3(8,64), 256, 0, stream>>>(Hbb,512, woT,512, WOUT,512,
        NROWS,512,512, wo_b,nulf,nulf,nulf,nulh,nulh);
  // 14) attn_out = LN(WOUT + xn2)
  ln_k<<<NROWS, 128, 0, stream>>>(WOUT, XN2, nullptr, attn_ln_g, attn_ln_b, ATT, ATTb);
  // 15) gate fusion -> X1 (x3 in place)  [TN=64]
  mm_k<6,3,64><<<dim3(8,64), 256, 0, stream>>>(MBb,512, gateT,1024, X1,512,
        NROWS,512,1024, gate_b, MB, ATT, X1, ATTb, nulh);
  // 16) xn3b = LN(x3)
  ln_k<<<NROWS, 128, 0, stream>>>(X1, nullptr, nullptr, norm3_g, norm3_b, nullptr, NB);
  // 17) fh = gelu(xn3 @ ffn1 + b1) (bf16)
  mm_k<3,0,128><<<dim3(16,64), 256, 0, stream>>>(NB,512, ffn1T,512, FHb,2048,
        NROWS,2048,512, ffn_b1,nulf,nulf,nulf,nulh,nulh);
  // 18) out = x3 + fh @ ffn2 + b2 -> d_out  [TN=64]
  mm_k<5,0,64><<<dim3(8,64), 256, 0, stream>>>(FHb,2048, ffn2T,2048, XOUT,512,
        NROWS,512,2048, ffn_b2, X1,nulf,nulf,nulh,nulh);
}

// Round 7
// 613.684 us; speedup vs baseline: 4.6492x; 1.0241x over previous
//
#include <hip/hip_runtime.h>

#define SEQL 1024
#define DMODEL 512
#define DINNER 1024
#define NROWS 8192
#define SEG 64
#define NSEG 16
#define LOG2E 1.4426950408889634f

typedef unsigned short u16;
typedef unsigned int u32;
using bf16x8 = __attribute__((ext_vector_type(8))) short;
using f32x4  = __attribute__((ext_vector_type(4))) float;
using u16x4  = __attribute__((ext_vector_type(4))) unsigned short;

__device__ __forceinline__ float rcp_fast(float x){ return __builtin_amdgcn_rcpf(x); }
__device__ __forceinline__ float exp_fast(float x){ return __expf(x); }
#if __has_builtin(__builtin_amdgcn_exp2f)
__device__ __forceinline__ float exp2_fast(float x){ return __builtin_amdgcn_exp2f(x); }
#else
__device__ __forceinline__ float exp2_fast(float x){ return __expf(x*0.6931471805599453f); }
#endif
__device__ __forceinline__ float sigmoid_f(float x){ return rcp_fast(1.f+exp_fast(-x)); }
__device__ __forceinline__ float softplus_f(float x){ return fmaxf(x,0.f)+__logf(1.f+exp_fast(-fabsf(x))); }
__device__ __forceinline__ float gelu_f(float x){
  float u2 = 1.5957691216057308f*(x+0.044715f*x*x*x);
  float t = 1.f - 2.f*rcp_fast(1.f+exp_fast(u2));
  return 0.5f*x*(1.f+t);
}
__device__ __forceinline__ u16 f2bf(float f){
  u32 u = __builtin_bit_cast(u32, f);
  return (u16)((u + 0x7FFFu + ((u>>16)&1u)) >> 16);
}
__device__ __forceinline__ float bf2f(u16 h){
  return __builtin_bit_cast(float, (u32)h << 16);
}

// async global -> LDS, 16B per lane (LDS dest must be linear in lane order)
typedef __attribute__((address_space(1))) const void g_void;
typedef __attribute__((address_space(3))) void l_void;
__device__ __forceinline__ void gl_lds16(const void* g, void* l){
  __builtin_amdgcn_global_load_lds((g_void*)g, (l_void*)l, 16, 0, 0);
}

// ---------------- weight transpose+cvt: [K,N] fp32 -> [N,K] bf16 ---------------
struct WtDesc { const float* src; u16* dst; int K; int N; int t0; };
struct WtArgs { WtDesc d[11]; };

__global__ __launch_bounds__(256) void wt_k(WtArgs a)
{
  __shared__ float t[64][65];
  int bid = blockIdx.x;
  int i = 0;
  #pragma unroll
  for (int j=1;j<11;++j) if (bid >= a.d[j].t0) i = j;
  const float* src = a.d[i].src; u16* dst = a.d[i].dst;
  int K = a.d[i].K, N = a.d[i].N;
  int ntN = (N+63)>>6;
  int loc = bid - a.d[i].t0;
  int k0 = (loc / ntN)*64, n0 = (loc % ntN)*64;
  int tr = threadIdx.x>>4, tc = threadIdx.x&15;
  #pragma unroll
  for (int p=0;p<4;++p) {
    int r = p*16 + tr; int c = tc*4;
    if (n0 + c < N) {
      float4 v = *(const float4*)(src + (size_t)(k0+r)*N + n0 + c);
      t[r][c]=v.x; t[r][c+1]=v.y; t[r][c+2]=v.z; t[r][c+3]=v.w;
    }
  }
  __syncthreads();
  #pragma unroll
  for (int p=0;p<4;++p) {
    int n = p*16 + tr; int k = tc*4;
    if (n0 + n < N) {
      u16x4 o = { f2bf(t[k][n]), f2bf(t[k+1][n]), f2bf(t[k+2][n]), f2bf(t[k+3][n]) };
      *(u16x4*)(dst + (size_t)(n0+n)*K + k0 + k) = o;
    }
  }
}

// ---------------- bias concat for QKV -----------------------------------------
__global__ __launch_bounds__(256) void pack3_k(const float* a, const float* b,
                                               const float* c, float* o)
{
  int t = blockIdx.x*256 + threadIdx.x;
  if (t < 512) o[t] = a[t];
  else if (t < 1024) o[t] = b[t-512];
  else if (t < 1536) o[t] = c[t-1024];
}

// ---------------- LayerNorm (D=512) -------------------------------------------
// AM: 0 = a f32, no b ; 1 = a f32 + b bf16 ; 2 = a bf16 + b f32
template<int AM>
__global__ __launch_bounds__(128) void ln_k(const void* av, const void* bv, float* resid,
                                            const float* g, const float* beta,
                                            float* outf, u16* outb)
{
  int row = blockIdx.x;
  int t = threadIdx.x;
  size_t off = (size_t)row*DMODEL + t*4;
  float4 v;
  if (AM==2) {
    u16x4 va = *(const u16x4*)((const u16*)av + off);
    v.x = bf2f(va[0]); v.y = bf2f(va[1]); v.z = bf2f(va[2]); v.w = bf2f(va[3]);
  } else {
    v = *(const float4*)((const float*)av + off);
  }
  if (AM==1) {
    u16x4 wb = *(const u16x4*)((const u16*)bv + off);
    v.x += bf2f(wb[0]); v.y += bf2f(wb[1]); v.z += bf2f(wb[2]); v.w += bf2f(wb[3]);
  } else if (AM==2) {
    float4 wb = *(const float4*)((const float*)bv + off);
    v.x += wb.x; v.y += wb.y; v.z += wb.z; v.w += wb.w;
  }
  if (resid) *(float4*)(resid + off) = v;
  float s = v.x+v.y+v.z+v.w;
  float q = v.x*v.x+v.y*v.y+v.z*v.z+v.w*v.w;
  #pragma unroll
  for (int o=1;o<64;o<<=1){ s += __shfl_xor(s,o); q += __shfl_xor(q,o); }
  __shared__ float ss[2], qq[2];
  int w = t>>6;
  if ((t&63)==0){ ss[w]=s; qq[w]=q; }
  __syncthreads();
  s = ss[0]+ss[1]; q = qq[0]+qq[1];
  float mean = s*(1.f/512.f);
  float var  = q*(1.f/512.f) - mean*mean;
  float rstd = rsqrtf(var + 1e-5f);
  int c = t*4;
  float4 gg = *(const float4*)(g+c);
  float4 bb = *(const float4*)(beta+c);
  float4 o4;
  o4.x = (v.x-mean)*rstd*gg.x + bb.x;
  o4.y = (v.y-mean)*rstd*gg.y + bb.y;
  o4.z = (v.z-mean)*rstd*gg.z + bb.z;
  o4.w = (v.w-mean)*rstd*gg.w + bb.w;
  if (outf) *(float4*)(outf + off) = o4;
  if (outb) {
    u16x4 ob = { f2bf(o4.x), f2bf(o4.y), f2bf(o4.z), f2bf(o4.w) };
    *(u16x4*)(outb + off) = ob;
  }
}

// ---------------- bf16 MFMA GEMM, 128xTN tile, BK=32, global_load_lds staging ---
// EPI: 3 gelu(x+bias) bf16, 5 x+bias+p0 f32, 6 gate fusion (bf16 p0/p1, f32 p2) f32,
//      7 bf16, 8 bf16+bias,
//      11 QKV fused (cols 0-1023 -> Q/K bf16 + bias; 1024-1535 -> V transposed to aux),
//      12 BC|delta fused (cols 0-31 -> Cf raw f32; 32-1055 -> softplus+bias -> bf16 aux)
// BMODE: 0 plain, 3 stitched A|A2 (K=1024)
// TN: 128 or 64
template<int EPI, int BMODE, int TN>
__global__ __launch_bounds__(256) void mm_k(
    const u16* Ab, int lda, const u16* Bb, int ldb,
    void* Cv, int ldc, int M, int N, int K,
    const float* bias, const float* p0, const float* p1, const float* p2,
    const u16* A2b, u16* aux)
{
  constexpr int NJ = TN/32;
  __shared__ u16 As[128][32];
  __shared__ u16 Bs[TN][32];
  const int tid = threadIdx.x;
  const int bx = blockIdx.x, by = blockIdx.y;
  float* Cf = (float*)Cv;
  u16* Cb = (u16*)Cv;
  const int row0 = by*128, col0 = bx*TN;
  const int sr = tid>>2, sc = tid&3;
  const int wv = tid>>6, lane = tid&63;
  const int wr = wv>>1, wc = wv&1;
  const int lr = lane&15, lk = (lane>>4)*8;
  const int lq = lane>>4;

  f32x4 acc[4][NJ];
  #pragma unroll
  for (int i=0;i<4;++i)
    #pragma unroll
    for (int j=0;j<NJ;++j)
      acc[i][j] = (f32x4){0.f,0.f,0.f,0.f};

  for (int k0=0; k0<K; k0+=32) {
    #pragma unroll
    for (int h=0; h<2; ++h) {
      int row = sr + h*64;
      const u16* src;
      if (BMODE==3) {
        int kk = k0 + sc*8;
        src = (kk < 512) ? Ab + (size_t)(row0+row)*512 + kk
                         : A2b + (size_t)(row0+row)*512 + (kk-512);
      } else {
        src = Ab + (size_t)(row0+row)*lda + k0 + sc*8;
      }
      gl_lds16(src, &As[row][sc*8]);
    }
    #pragma unroll
    for (int h=0; h<TN/64; ++h) {
      int rowb = sr + h*64;
      gl_lds16(Bb + (size_t)(col0+rowb)*ldb + k0 + sc*8, &Bs[rowb][sc*8]);
    }
    __syncthreads();
    bf16x8 fa[4], fb[NJ];
    #pragma unroll
    for (int i=0;i<4;++i) fa[i] = *(const bf16x8*)&As[wr*64 + i*16 + lr][lk];
    #pragma unroll
    for (int j=0;j<NJ;++j) fb[j] = *(const bf16x8*)&Bs[wc*(TN/2) + j*16 + lr][lk];
    #pragma unroll
    for (int i=0;i<4;++i)
      #pragma unroll
      for (int j=0;j<NJ;++j)
        acc[i][j] = __builtin_amdgcn_mfma_f32_16x16x32_bf16(fa[i], fb[j], acc[i][j], 0,0,0);
    __syncthreads();
  }

  #pragma unroll
  for (int i=0;i<4;++i) {
    #pragma unroll
    for (int j=0;j<NJ;++j) {
      int col = col0 + wc*(TN/2) + j*16 + lr;
      if (col >= N) continue;
      int rowbase = row0 + wr*64 + i*16 + lq*4;
      f32x4 v4 = acc[i][j];
      if (EPI==11 && col >= 1024) {
        int c2 = col-1024;
        int b2 = rowbase >> 10;
        int l2 = rowbase & 1023;
        float bv = bias[col];
        u16x4 pk = { f2bf(v4[0]+bv), f2bf(v4[1]+bv), f2bf(v4[2]+bv), f2bf(v4[3]+bv) };
        *(u16x4*)(aux + (size_t)b2*DMODEL*SEQL + (size_t)c2*SEQL + l2) = pk;
        continue;
      }
      #pragma unroll
      for (int r=0;r<4;++r) {
        int row = rowbase + r;
        size_t idx = (size_t)row*ldc + col;
        float v = v4[r];
        if (EPI==3) Cb[idx] = f2bf(gelu_f(v + bias[col]));
        else if (EPI==5) Cf[idx] = v + bias[col] + p0[idx];
        else if (EPI==6) {
          float g = sigmoid_f(v + bias[col]);
          float m  = bf2f(((const u16*)p0)[idx]);
          float at = bf2f(((const u16*)p1)[idx]);
          Cf[idx] = p2[idx] + at + g*m + (1.f-g)*at;
        }
        else if (EPI==7) Cb[idx] = f2bf(v);
        else if (EPI==8) Cb[idx] = f2bf(v + bias[col]);
        else if (EPI==11) {
          size_t i2 = (size_t)(col>>9)*4194304 + (size_t)row*512 + (col&511);
          Cb[i2] = f2bf(v + bias[col]);
        }
        else if (EPI==12) {
          if (col < 32) Cf[(size_t)row*32 + col] = v;
          else aux[(size_t)row*1024 + (col-32)] = f2bf(softplus_f(v + bias[col-32]));
        }
      }
    }
  }
}

// ---------------- fused attention: 32-row q-tiles ------------------------------
// grid (qt=32, bh=64), 256 thr (4 waves). Scores: wave w covers k-cols w*256..+256
// for BOTH 16-row groups (K frags shared). PV: n-split, wave w owns d-cols w*16..+16.
__global__ __launch_bounds__(256) void attn_k(const u16* Qb, const u16* Kb,
                                              const u16* VTb, float* AW, u16* Hbb)
{
  __shared__ u16 Qs[32][72];
  __shared__ u16 Ps[32][1032];
  __shared__ float smax[4][32];
  __shared__ float ssum[4][32];

  const int tid = threadIdx.x;
  const int w = tid>>6, lane = tid&63;
  const int qt = blockIdx.x, bh = blockIdx.y;
  const int b = bh>>3, h = bh&7;
  const int q0 = qt*32;
  const int lr = lane&15, lg = lane>>4;
  const int rw = lg*4;

  {
    int r = tid>>3, c = (tid&7)*8;
    const u16* src = Qb + ((size_t)(b*1024 + q0 + r))*512 + h*64 + c;
    *(uint4*)&Qs[r][c] = *(const uint4*)src;
  }
  __syncthreads();

  f32x4 acc0[16], acc1[16];
  #pragma unroll
  for (int j=0;j<16;++j){ acc0[j]=(f32x4){0.f,0.f,0.f,0.f}; acc1[j]=(f32x4){0.f,0.f,0.f,0.f}; }
  bf16x8 fa00 = *(const bf16x8*)&Qs[lr][lg*8];
  bf16x8 fa01 = *(const bf16x8*)&Qs[lr][32+lg*8];
  bf16x8 fa10 = *(const bf16x8*)&Qs[16+lr][lg*8];
  bf16x8 fa11 = *(const bf16x8*)&Qs[16+lr][32+lg*8];
  const u16* Kbase = Kb + ((size_t)(b*1024 + w*256))*512 + h*64;
  #pragma unroll
  for (int j=0;j<16;++j){
    const u16* krow = Kbase + (size_t)(j*16 + lr)*512 + lg*8;
    bf16x8 fb0 = *(const bf16x8*)krow;
    bf16x8 fb1 = *(const bf16x8*)(krow+32);
    acc0[j] = __builtin_amdgcn_mfma_f32_16x16x32_bf16(fa00, fb0, acc0[j], 0,0,0);
    acc0[j] = __builtin_amdgcn_mfma_f32_16x16x32_bf16(fa01, fb1, acc0[j], 0,0,0);
    acc1[j] = __builtin_amdgcn_mfma_f32_16x16x32_bf16(fa10, fb0, acc1[j], 0,0,0);
    acc1[j] = __builtin_amdgcn_mfma_f32_16x16x32_bf16(fa11, fb1, acc1[j], 0,0,0);
  }

  float mg0[4] = {-1e30f,-1e30f,-1e30f,-1e30f};
  float mg1[4] = {-1e30f,-1e30f,-1e30f,-1e30f};
  #pragma unroll
  for (int j=0;j<16;++j)
    #pragma unroll
    for (int r=0;r<4;++r){
      mg0[r]=fmaxf(mg0[r],acc0[j][r]);
      mg1[r]=fmaxf(mg1[r],acc1[j][r]);
    }
  #pragma unroll
  for (int o=1;o<16;o<<=1)
    #pragma unroll
    for (int r=0;r<4;++r){
      mg0[r]=fmaxf(mg0[r],__shfl_xor(mg0[r],o));
      mg1[r]=fmaxf(mg1[r],__shfl_xor(mg1[r],o));
    }
  if (lr==0){
    #pragma unroll
    for (int r=0;r<4;++r){ smax[w][rw+r]=mg0[r]; smax[w][16+rw+r]=mg1[r]; }
  }
  __syncthreads();
  #pragma unroll
  for (int r=0;r<4;++r){
    mg0[r] = fmaxf(fmaxf(smax[0][rw+r],smax[1][rw+r]),fmaxf(smax[2][rw+r],smax[3][rw+r]));
    mg1[r] = fmaxf(fmaxf(smax[0][16+rw+r],smax[1][16+rw+r]),fmaxf(smax[2][16+rw+r],smax[3][16+rw+r]));
  }
  const float cs = 0.125f*LOG2E;
  float sg0[4]={0.f,0.f,0.f,0.f}, sg1[4]={0.f,0.f,0.f,0.f};
  #pragma unroll
  for (int j=0;j<16;++j)
    #pragma unroll
    for (int r=0;r<4;++r){
      acc0[j][r]=exp2_fast((acc0[j][r]-mg0[r])*cs); sg0[r]+=acc0[j][r];
      acc1[j][r]=exp2_fast((acc1[j][r]-mg1[r])*cs); sg1[r]+=acc1[j][r];
    }
  #pragma unroll
  for (int o=1;o<16;o<<=1)
    #pragma unroll
    for (int r=0;r<4;++r){
      sg0[r]+=__shfl_xor(sg0[r],o);
      sg1[r]+=__shfl_xor(sg1[r],o);
    }
  if (lr==0){
    #pragma unroll
    for (int r=0;r<4;++r){ ssum[w][rw+r]=sg0[r]; ssum[w][16+rw+r]=sg1[r]; }
  }
  __syncthreads();
  float ig0[4], ig1[4];
  #pragma unroll
  for (int r=0;r<4;++r){
    ig0[r] = rcp_fast(ssum[0][rw+r]+ssum[1][rw+r]+ssum[2][rw+r]+ssum[3][rw+r]);
    ig1[r] = rcp_fast(ssum[0][16+rw+r]+ssum[1][16+rw+r]+ssum[2][16+rw+r]+ssum[3][16+rw+r]);
  }

  float* awr = AW + (size_t)bh*1048576 + (size_t)q0*1024 + (size_t)w*256;
  #pragma unroll
  for (int j=0;j<16;++j){
    int col = j*16 + lr;
    #pragma unroll
    for (int r=0;r<4;++r){
      float v0 = acc0[j][r]*ig0[r];
      float v1 = acc1[j][r]*ig1[r];
      awr[(size_t)(rw+r)*1024 + col] = v0;
      awr[(size_t)(16+rw+r)*1024 + col] = v1;
      Ps[rw+r][w*256+col] = f2bf(v0);
      Ps[16+rw+r][w*256+col] = f2bf(v1);
    }
  }
  __syncthreads();

  // PV: wave w owns d-cols w*16..w*16+16, full k range
  f32x4 av0 = (f32x4){0.f,0.f,0.f,0.f};
  f32x4 av1 = (f32x4){0.f,0.f,0.f,0.f};
  const u16* Vbase = VTb + (size_t)b*524288 + (size_t)(h*64 + w*16 + lr)*1024;
  #pragma unroll
  for (int ks=0; ks<32; ++ks){
    bf16x8 fb  = *(const bf16x8*)(Vbase + ks*32 + lg*8);
    bf16x8 pa0 = *(const bf16x8*)&Ps[lr][ks*32 + lg*8];
    bf16x8 pa1 = *(const bf16x8*)&Ps[16+lr][ks*32 + lg*8];
    av0 = __builtin_amdgcn_mfma_f32_16x16x32_bf16(pa0, fb, av0, 0,0,0);
    av1 = __builtin_amdgcn_mfma_f32_16x16x32_bf16(pa1, fb, av1, 0,0,0);
  }
  u16* ob = Hbb + ((size_t)(b*1024 + q0))*512 + h*64 + w*16 + lr;
  #pragma unroll
  for (int r=0;r<4;++r){
    ob[(size_t)(rw+r)*512]    = f2bf(av0[r]);
    ob[(size_t)(16+rw+r)*512] = f2bf(av1[r]);
  }
}

// ---------------- causal depthwise conv (D_CONV=4) + SiLU, bf16 in/out ---------
__global__ __launch_bounds__(256) void conv_k(const u16* xrb, const float* cw,
                                              const float* cb, u16* xcb)
{
  int t = blockIdx.x*256 + threadIdx.x;
  int d = (t & 255)*4;
  int row = t >> 8;
  int l = row & (SEQL-1);
  const u16* xmb = xrb + (size_t)(row - l)*2048 + d;
  float wv[4][4];
  #pragma unroll
  for (int dd=0; dd<4; ++dd){
    float4 w = *(const float4*)(cw + (size_t)(d+dd)*4);
    wv[dd][0]=w.x; wv[dd][1]=w.y; wv[dd][2]=w.z; wv[dd][3]=w.w;
  }
  float4 acc = *(const float4*)(cb + d);
  #pragma unroll
  for (int k=0;k<4;++k){
    int ls = l + k - 3;
    if (ls >= 0) {
      u16x4 xv = *(const u16x4*)(xmb + (size_t)ls*2048);
      acc.x += wv[0][k]*bf2f(xv[0]);
      acc.y += wv[1][k]*bf2f(xv[1]);
      acc.z += wv[2][k]*bf2f(xv[2]);
      acc.w += wv[3][k]*bf2f(xv[3]);
    }
  }
  float sx = acc.x*rcp_fast(1.f+exp_fast(-acc.x));
  float sy = acc.y*rcp_fast(1.f+exp_fast(-acc.y));
  float sz = acc.z*rcp_fast(1.f+exp_fast(-acc.z));
  float sw = acc.w*rcp_fast(1.f+exp_fast(-acc.w));
  size_t off = (size_t)row*DINNER + d;
  u16x4 ob = { f2bf(sx), f2bf(sy), f2bf(sz), f2bf(sw) };
  *(u16x4*)(xcb + off) = ob;
}

// ---------------- selective scan, chunked two-pass -----------------------------
__global__ __launch_bounds__(256) void scan1_k(const u16* dtb, const u16* ub,
                                               const float* bc, const float* A_log,
                                               float* Pq)
{
  const int tid = threadIdx.x;
  const int d   = blockIdx.x*256 + tid;
  const int seg = blockIdx.y;
  const int b   = blockIdx.z;
  const int l0  = seg*SEG;

  __shared__ float BCs[SEG*32];
  {
    const float4* src = (const float4*)(bc + ((size_t)b*SEQL + l0)*32);
    float4* dst = (float4*)BCs;
    dst[tid]     = src[tid];
    dst[tid+256] = src[tid+256];
  }
  float As2[16];
  #pragma unroll
  for (int s=0;s<16;++s) As2[s] = -expf(A_log[s]) * LOG2E;
  __syncthreads();

  float h[16], P[16];
  #pragma unroll
  for (int s=0;s<16;++s){ h[s]=0.f; P[s]=1.f; }

  size_t base = ((size_t)b*SEQL + l0)*DINNER + d;
  const u16* pdt = dtb + base;
  const u16* pu  = ub  + base;

  u16 dpf[8], upf[8];
  #pragma unroll
  for (int j=0;j<8;++j){ dpf[j]=pdt[(size_t)j*DINNER]; upf[j]=pu[(size_t)j*DINNER]; }
  const u16* pdt_f = pdt + (size_t)8*DINNER;
  const u16* pu_f  = pu  + (size_t)8*DINNER;

  for (int l=0; l<SEG; l+=8) {
    bool pf = (l+8 < SEG);
    #pragma unroll
    for (int j=0;j<8;++j) {
      float dt = bf2f(dpf[j]), u = bf2f(upf[j]);
      if (pf) { dpf[j] = *pdt_f; upf[j] = *pu_f; }
      pdt_f += DINNER; pu_f += DINNER;
      float dtu = dt*u;
      const float* Bs = &BCs[(l+j)*32];
      #pragma unroll
      for (int s=0;s<16;++s) {
        float dA = exp2_fast(dt*As2[s]);
        P[s] *= dA;
        h[s] = fmaf(h[s], dA, dtu*Bs[s]);
      }
    }
  }
  float* out = Pq + (((size_t)b*NSEG + seg)*32)*1024 + d;
  #pragma unroll
  for (int s=0;s<16;++s) {
    out[(size_t)s*1024]      = P[s];
    out[(size_t)(16+s)*1024] = h[s];
  }
}

__global__ __launch_bounds__(256) void scan2_k(const u16* dtb, const u16* ub,
                                               const float* bc, const u16* xrb,
                                               const float* A_log, const float* Dp,
                                               const float* Pq, u16* yb)
{
  const int tid = threadIdx.x;
  const int d   = blockIdx.x*256 + tid;
  const int seg = blockIdx.y;
  const int b   = blockIdx.z;
  const int l0  = seg*SEG;

  __shared__ float BCs[SEG*32];
  {
    const float4* src = (const float4*)(bc + ((size_t)b*SEQL + l0)*32);
    float4* dst = (float4*)BCs;
    dst[tid]     = src[tid];
    dst[tid+256] = src[tid+256];
  }
  float As2[16];
  #pragma unroll
  for (int s=0;s<16;++s) As2[s] = -expf(A_log[s]) * LOG2E;
  float dcoef = Dp[d];
  __syncthreads();

  float h[16];
  #pragma unroll
  for (int s=0;s<16;++s) h[s]=0.f;

  const float* pp = Pq + ((size_t)b*NSEG)*32*1024 + d;
  for (int sg=0; sg<seg; ++sg) {
    const float* q = pp + (size_t)sg*32*1024;
    #pragma unroll
    for (int s=0;s<16;++s)
      h[s] = fmaf(h[s], q[(size_t)s*1024], q[(size_t)(16+s)*1024]);
  }

  size_t rbase = (size_t)b*SEQL + l0;
  const u16* pdt = dtb + rbase*DINNER + d;
  const u16* pu  = ub  + rbase*DINNER + d;
  const u16* pr  = xrb + rbase*2048 + 1024 + d;
  u16*       py  = yb  + rbase*DINNER + d;

  u16 dpf[8], upf[8], rpf[8];
  #pragma unroll
  for (int j=0;j<8;++j){
    dpf[j]=pdt[(size_t)j*DINNER]; upf[j]=pu[(size_t)j*DINNER]; rpf[j]=pr[(size_t)j*2048];
  }
  const u16* pdt_f = pdt + (size_t)8*DINNER;
  const u16* pu_f  = pu  + (size_t)8*DINNER;
  const u16* pr_f  = pr  + (size_t)8*2048;

  for (int l=0; l<SEG; l+=8) {
    bool pf = (l+8 < SEG);
    #pragma unroll
    for (int j=0;j<8;++j) {
      float dt = bf2f(dpf[j]), u = bf2f(upf[j]), rv = bf2f(rpf[j]);
      if (pf) { dpf[j] = *pdt_f; upf[j] = *pu_f; rpf[j] = *pr_f; }
      pdt_f += DINNER; pu_f += DINNER; pr_f += 2048;
      float dtu = dt*u;
      float acc = 0.f;
      const float* Bs = &BCs[(l+j)*32];
      #pragma unroll
      for (int s=0;s<16;++s) {
        float dA = exp2_fast(dt*As2[s]);
        h[s] = fmaf(h[s], dA, dtu*Bs[s]);
        acc  = fmaf(h[s], Bs[16+s], acc);
      }
      float y = fmaf(u, dcoef, acc);
      y *= rv * rcp_fast(1.f + exp2_fast(rv*(-LOG2E)));
      *py = f2bf(y);
      py += DINNER;
    }
  }
}

extern "C" void kernel_launch(void* const* d_in, const int* in_sizes, int n_in,
                              void* d_out, int out_size, void* d_ws, size_t ws_size,
                              hipStream_t stream)
{
  const float* x          = (const float*)d_in[0];
  const float* in_proj_w  = (const float*)d_in[1];
  const float* conv_w     = (const float*)d_in[2];
  const float* conv_b     = (const float*)d_in[3];
  const float* x_proj_w   = (const float*)d_in[4];
  const float* dt_proj_w  = (const float*)d_in[5];
  const float* dt_proj_b  = (const float*)d_in[6];
  const float* A_log      = (const float*)d_in[7];
  const float* Dvec       = (const float*)d_in[8];
  const float* out_proj_w = (const float*)d_in[9];
  const float* wq_w = (const float*)d_in[10]; const float* wq_b = (const float*)d_in[11];
  const float* wk_w = (const float*)d_in[12]; const float* wk_b = (const float*)d_in[13];
  const float* wv_w = (const float*)d_in[14]; const float* wv_b = (const float*)d_in[15];
  const float* wo_w = (const float*)d_in[16]; const float* wo_b = (const float*)d_in[17];
  const float* attn_ln_g = (const float*)d_in[18]; const float* attn_ln_b = (const float*)d_in[19];
  const float* ffn_w1 = (const float*)d_in[20]; const float* ffn_b1 = (const float*)d_in[21];
  const float* ffn_w2 = (const float*)d_in[22]; const float* ffn_b2 = (const float*)d_in[23];
  const float* norm1_g = (const float*)d_in[24]; const float* norm1_b = (const float*)d_in[25];
  const float* norm2_g = (const float*)d_in[26]; const float* norm2_b = (const float*)d_in[27];
  const float* norm3_g = (const float*)d_in[28]; const float* norm3_b = (const float*)d_in[29];
  const float* gate_w  = (const float*)d_in[30]; const float* gate_b  = (const float*)d_in[31];

  // ---- workspace layout ----
  float* ws  = (float*)d_ws;
  float* BC   = ws;                 // 262144 f32
  float* X1   = BC  + 262144;       // 4194304 f32 (x1 -> x3)
  float* XN2  = X1  + 4194304;      // 4194304 f32
  float* Pq   = XN2 + 4194304;      // 4194304 f32  [8][16][32][1024]
  u16* WT0 = (u16*)(Pq + 4194304);  // 6324224 u16 transposed weights
  u16* XRb = WT0 + 6324224;         // 16777216 u16 (xr); reused Q|K|VT|Hb; then FH
  u16* NB  = XRb + 16777216;        // 4194304 u16 (xn1b -> xn2b -> xn3b)
  u16* XCb = NB  + 4194304;         // 8388608 u16 (xc); reused MBb|ATTb
  u16* DTb = XCb + 8388608;         // 8388608 u16 (delta); reused WOUTb
  u16* Yb  = DTb + 8388608;         // 8388608 u16 (scan y)
  float* QKVB = (float*)(Yb + 8388608); // 1536 f32

  u16* Qb   = XRb;
  u16* Kb   = XRb + 4194304;
  u16* VTb  = XRb + 8388608;
  u16* Hbb  = XRb + 12582912;
  u16* FHb  = XRb;
  u16* MBb  = XCb;
  u16* ATTb = XCb + 4194304;
  u16* WOUTb= DTb;

  u16* inprojT = WT0;               // [2048,512]
  u16* xprojT  = inprojT + 1048576; // [32,1024]   (stacked with dtT -> 1056 rows)
  u16* dtT     = xprojT  + 32768;   // [1024,1024]
  u16* outT    = dtT     + 1048576; // [512,1024]
  u16* wqT     = outT    + 524288;  // [512,512]   (wq|wk|wv stacked -> 1536 rows)
  u16* wkT     = wqT     + 262144;
  u16* wvT     = wkT     + 262144;
  u16* woT     = wvT     + 262144;
  u16* ffn1T   = woT     + 262144;  // [2048,512]
  u16* ffn2T   = ffn1T   + 1048576; // [512,2048]
  u16* gateT   = ffn2T   + 1048576; // [512,1024]

  float* XOUT = (float*)d_out;
  float* AW   = (float*)d_out + 4194304;

  const float* nulf = nullptr;
  u16* nulh = nullptr;

  // 0) transpose + cvt weights; pack qkv bias
  WtArgs wa;
  wa.d[0]  = { in_proj_w, inprojT, 512, 2048, 0 };
  wa.d[1]  = { x_proj_w,  xprojT, 1024,   32, 256 };
  wa.d[2]  = { dt_proj_w, dtT,    1024, 1024, 272 };
  wa.d[3]  = { out_proj_w,outT,   1024,  512, 528 };
  wa.d[4]  = { wq_w,      wqT,     512,  512, 656 };
  wa.d[5]  = { wk_w,      wkT,     512,  512, 720 };
  wa.d[6]  = { wv_w,      wvT,     512,  512, 784 };
  wa.d[7]  = { wo_w,      woT,     512,  512, 848 };
  wa.d[8]  = { ffn_w1,    ffn1T,   512, 2048, 912 };
  wa.d[9]  = { ffn_w2,    ffn2T,  2048,  512, 1168 };
  wa.d[10] = { gate_w,    gateT,  1024,  512, 1424 };
  wt_k<<<1552, 256, 0, stream>>>(wa);
  pack3_k<<<6, 256, 0, stream>>>(wq_b, wk_b, wv_b, QKVB);

  // 1) xn1b = LN(x)
  ln_k<0><<<NROWS, 128, 0, stream>>>(x, nullptr, nullptr, norm1_g, norm1_b, nullptr, NB);
  // 2) xrb = xn1 @ in_proj (bf16)
  mm_k<7,0,128><<<dim3(16,64), 256, 0, stream>>>(NB,512, inprojT,512, XRb,2048,
        NROWS,2048,512, nulf,nulf,nulf,nulf,nulh,nulh);
  // 3) xc = silu(conv(xm)+cb) (bf16)
  conv_k<<<NROWS, 256, 0, stream>>>(XRb, conv_w, conv_b, XCb);
  // 4+5) BC (f32) | delta (bf16) fused: N=1056 over stacked [xprojT|dtT]
  mm_k<12,0,128><<<dim3(9,64), 256, 0, stream>>>(XCb,1024, xprojT,1024, BC,32,
        NROWS,1056,1024, dt_proj_b,nulf,nulf,nulf,nulh,DTb);
  // 6) chunked scan
  scan1_k<<<dim3(4,NSEG-1,8), 256, 0, stream>>>(DTb, XCb, BC, A_log, Pq);
  scan2_k<<<dim3(4,NSEG,8),   256, 0, stream>>>(DTb, XCb, BC, XRb, A_log, Dvec, Pq, Yb);
  // 7) mamba_out = y @ out_proj (bf16 only)  [TN=64]
  mm_k<7,0,64><<<dim3(8,64), 256, 0, stream>>>(Yb,1024, outT,1024, MBb,512,
        NROWS,512,1024, nulf,nulf,nulf,nulf,nulh,nulh);
  // 8) x1 = x + mamba_out(bf16) ; xn2 = LN(x1)
  ln_k<1><<<NROWS, 128, 0, stream>>>(x, MBb, X1, norm2_g, norm2_b, XN2, NB);
  // 9) QKV fused: N=1536 over stacked [wqT|wkT|wvT]
  mm_k<11,0,128><<<dim3(12,64), 256, 0, stream>>>(NB,512, wqT,512, Qb,512,
        NROWS,1536,512, QKVB,nulf,nulf,nulf,nulh,VTb);
  // 10-12) fused attention (32-row q-tiles): AW (d_out) + Hbb
  attn_k<<<dim3(32,64), 256, 0, stream>>>(Qb, Kb, VTb, AW, Hbb);
  // 13) wo_out = Hb @ wo + b (bf16)  [TN=64]
  mm_k<8,0,64><<<dim3(8,64), 256, 0, stream>>>(Hbb,512, woT,512, WOUTb,512,
        NROWS,512,512, wo_b,nulf,nulf,nulf,nulh,nulh);
  // 14) attn_out = LN(wo_out(bf16) + xn2(f32)) -> bf16 only
  ln_k<2><<<NROWS, 128, 0, stream>>>(WOUTb, XN2, nullptr, attn_ln_g, attn_ln_b, nullptr, ATTb);
  // 15) gate fusion -> X1 (x3 in place)  [TN=64, bf16 m/at]
  mm_k<6,3,64><<<dim3(8,64), 256, 0, stream>>>(MBb,512, gateT,1024, X1,512,
        NROWS,512,1024, gate_b, (const float*)MBb, (const float*)ATTb, X1, ATTb, nulh);
  // 16) xn3b = LN(x3)
  ln_k<0><<<NROWS, 128, 0, stream>>>(X1, nullptr, nullptr, norm3_g, norm3_b, nullptr, NB);
  // 17) fh = gelu(xn3 @ ffn1 + b1) (bf16)
  mm_k<3,0,128><<<dim3(16,64), 256, 0, stream>>>(NB,512, ffn1T,512, FHb,2048,
        NROWS,2048,512, ffn_b1,nulf,nulf,nulf,nulh,nulh);
  // 18) out = x3 + fh @ ffn2 + b2 -> d_out  [TN=64]
  mm_k<5,0,64><<<dim3(8,64), 256, 0, stream>>>(FHb,2048, ffn2T,2048, XOUT,512,
        NROWS,512,2048, ffn_b2, X1,nulf,nulf,nulh,nulh);
}